// Round 5
// baseline (1422.088 us; speedup 1.0000x reference)
//
#include <hip/hip_runtime.h>
#include <cmath>

// ---------------- constants ----------------
constexpr int BB    = 8;     // batch
constexpr int LS    = 57;    // spectra tokens
constexpr int LG    = 9;     // gaia tokens
constexpr int RS    = BB*LS; // 456
constexpr int RG    = BB*LG; // 72
constexpr int DM    = 512;   // d_model
constexpr int DPROJ = 2320;
constexpr int DIN   = 1024;
constexpr int NH    = 16;    // mamba heads
constexpr int HD    = 64;    // mamba headdim
constexpr int NLAY  = 10;

constexpr int SP_IN  = 4;    // split-K for in-proj  (K=512  -> 128/split)
constexpr int SP_OUT = 8;    // split-K for out-proj (K=1024 -> 128/split)
constexpr int SP_ATT = 4;    // split-K for attention gemms (K=512 -> 128/split)

__device__ __forceinline__ float siluf(float x){ return x / (1.f + expf(-x)); }

// ---------------- tokenize ----------------
__global__ __launch_bounds__(512) void tokenize_k(
    const float* __restrict__ x, const float* __restrict__ w, const float* __restrict__ bias,
    float* __restrict__ out, int in_dim, int tok_dim, int ntok)
{
    int t = blockIdx.x, b = blockIdx.y, d = threadIdx.x;
    __shared__ float xv[64];
    if (d < tok_dim) {
        int idx = t*tok_dim + d;
        xv[d] = (idx < in_dim) ? x[(size_t)b*in_dim + idx] : 0.f;
    }
    __syncthreads();
    float acc = bias[d];
    for (int k=0;k<tok_dim;k++) acc += xv[k]*w[(size_t)k*DM + d];
    out[(size_t)(b*ntok + t)*DM + d] = acc;
}

// ---------------- split-K f32 GEMM -> partials ----------------
struct GemmJob {
    const float* A; const float* B; float* part; int M;
};

template<int BN, int TN, bool TB, int NSPLIT>
__global__ __launch_bounds__(256) void gemm_ps(GemmJob j0, GemmJob j1, GemmJob j2, int N, int K)
{
    const int z = blockIdx.z;
    const int job = z / NSPLIT, split = z % NSPLIT;
    GemmJob jb = (job==0) ? j0 : (job==1 ? j1 : j2);
    const int bm = blockIdx.y*64, bn = blockIdx.x*BN;
    const int M = jb.M;
    if (bm >= M) return;
    __shared__ float As[2][16][68];
    __shared__ float Bs[2][16][BN+4];
    const int tid = threadIdx.x, tx = tid & 15, ty = tid >> 4;
    const float* __restrict__ A  = jb.A;
    const float* __restrict__ Bm = jb.B;
    float acc[4][TN] = {};

    const int arow = tid>>2, akb = (tid&3)*4;
    float4 ra, rb0, rb1;

    auto zero4 = [](){ float4 zz; zz.x=0.f; zz.y=0.f; zz.z=0.f; zz.w=0.f; return zz; };

    auto loadT = [&](int k0){
        ra = (bm+arow < M) ? *(const float4*)(A + (size_t)(bm+arow)*K + k0 + akb) : zero4();
        if constexpr (!TB) {
            const int kr = tid>>4, c4 = (tid&15)*4;
            rb0 = (bn+c4 < N) ? *(const float4*)(Bm + (size_t)(k0+kr)*N + bn + c4) : zero4();
            if constexpr (TN==8)
                rb1 = (bn+64+c4 < N) ? *(const float4*)(Bm + (size_t)(k0+kr)*N + bn + 64 + c4) : zero4();
        } else {
            const int nr = tid>>2, kb = (tid&3)*4;
            rb0 = (bn+nr < N) ? *(const float4*)(Bm + (size_t)(bn+nr)*K + k0 + kb) : zero4();
        }
    };
    auto storeT = [&](int buf){
        As[buf][akb+0][arow] = ra.x;
        As[buf][akb+1][arow] = ra.y;
        As[buf][akb+2][arow] = ra.z;
        As[buf][akb+3][arow] = ra.w;
        if constexpr (!TB) {
            const int kr = tid>>4, c4 = (tid&15)*4;
            *(float4*)&Bs[buf][kr][c4] = rb0;
            if constexpr (TN==8) *(float4*)&Bs[buf][kr][64+c4] = rb1;
        } else {
            const int nr = tid>>2, kb = (tid&3)*4;
            Bs[buf][kb+0][nr] = rb0.x;
            Bs[buf][kb+1][nr] = rb0.y;
            Bs[buf][kb+2][nr] = rb0.z;
            Bs[buf][kb+3][nr] = rb0.w;
        }
    };

    const int Kper = K/NSPLIT;
    const int koff = split*Kper;
    const int nk = Kper/16;
    loadT(koff);
    storeT(0);
    __syncthreads();
    for (int t=0; t<nk; ++t){
        const int cur = t & 1;
        if (t+1 < nk) loadT(koff + (t+1)*16);
        #pragma unroll
        for (int kk=0; kk<16; ++kk){
            float4 av = *(const float4*)&As[cur][kk][ty*4];
            float a[4] = {av.x, av.y, av.z, av.w};
            float b[TN];
            #pragma unroll
            for (int g=0; g<TN/4; ++g){
                float4 bv = *(const float4*)&Bs[cur][kk][tx*TN + g*4];
                b[g*4+0]=bv.x; b[g*4+1]=bv.y; b[g*4+2]=bv.z; b[g*4+3]=bv.w;
            }
            #pragma unroll
            for (int i=0;i<4;i++)
                #pragma unroll
                for (int j=0;j<TN;j++) acc[i][j] = fmaf(a[i], b[j], acc[i][j]);
        }
        if (t+1 < nk) storeT(cur^1);
        __syncthreads();
    }

    float* __restrict__ P = jb.part + (size_t)split*M*N;
    #pragma unroll
    for (int i=0;i<4;i++){
        int m = bm + ty*4 + i;
        if (m < M){
            #pragma unroll
            for (int j=0;j<TN;j++){
                int n = bn + tx*TN + j;
                if (n < N) P[(size_t)m*N + n] = acc[i][j];
            }
        }
    }
}

// ---------------- reduce partials (+bias, +res) ----------------
struct RJob { const float* part; const float* bias; const float* res; float* C; int M; };

template<int NS>
__global__ __launch_bounds__(256) void reduce_k(RJob j0, RJob j1, int N)
{
    RJob j = blockIdx.y ? j1 : j0;
    const size_t total = (size_t)j.M*N;
    const size_t i4 = ((size_t)blockIdx.x*256 + threadIdx.x)*4;
    if (i4 >= total) return;
    float4 s = *(const float4*)(j.part + i4);
    #pragma unroll
    for (int t=1;t<NS;t++){
        const float4 v = *(const float4*)(j.part + (size_t)t*total + i4);
        s.x+=v.x; s.y+=v.y; s.z+=v.z; s.w+=v.w;
    }
    const int n = (int)(i4 % (size_t)N);
    if (j.bias){ s.x+=j.bias[n]; s.y+=j.bias[n+1]; s.z+=j.bias[n+2]; s.w+=j.bias[n+3]; }
    if (j.res){ const float4 r = *(const float4*)(j.res + i4); s.x+=r.x; s.y+=r.y; s.z+=r.z; s.w+=r.w; }
    *(float4*)(j.C + i4) = s;
}

// ---------------- mamba mixer: conv+silu+softplus + CLOSED-FORM scan ----------------
// y[l,p] = sum_{m<=l} exp(A*(s_l - s_m)) * dt_m * (C_l . B_m) * x_m[p] + D*x[l,p]
// with s = inclusive prefix sum of softplus(dt). One block per (head,batch,stack).
// Phase 1: conv+silu -> LDS (X 57x64, B 57x128, C 57x128); wave0: dt softplus +
//          shfl prefix-scan. Phase 2: G = decay .* (C @ B^T) (57x57x128).
// Phase 3: Y = G @ X + D*X. All tiled 16x16 threads, no serial recurrence.
// Reads in-proj PARTIALS directly (SP_IN=4), avoiding the reduce kernel.
__global__ __launch_bounds__(256) void mamba_scan(
    const float* __restrict__ pS, const float* __restrict__ pG,
    const float* __restrict__ cw_s, const float* __restrict__ cw_g,
    const float* __restrict__ cb_s, const float* __restrict__ cb_g,
    const float* __restrict__ dtb_s, const float* __restrict__ dtb_g,
    const float* __restrict__ al_s, const float* __restrict__ al_g,
    const float* __restrict__ Dw_s, const float* __restrict__ Dw_g,
    float* __restrict__ y_s, float* __restrict__ y_g)
{
    const int h = blockIdx.x, b = blockIdx.y, st = blockIdx.z;
    const float* zp  = st ? pG : pS;
    const int   R    = st ? RG : RS;
    const size_t pstr = (size_t)R * DPROJ;
    const float* cw  = st ? cw_g  : cw_s;
    const float* cb  = st ? cb_g  : cb_s;
    const float* dtb = st ? dtb_g : dtb_s;
    const float* al  = st ? al_g  : al_s;
    const float* Dw  = st ? Dw_g  : Dw_s;
    float* y = st ? y_g : y_s;
    const int L = st ? LG : LS;

    const int t = threadIdx.x;
    constexpr int SB = 132;  // B/C row stride (mult of 4, 16B-aligned rows)
    constexpr int SX = 68;   // X row stride
    constexpr int SG = 60;   // G row stride
    __shared__ float Bm[64*SB];
    __shared__ float Cm[64*SB];
    __shared__ float Xm[64*SX];
    __shared__ float Gm[64*SG];
    __shared__ float dts[64], sps[64];

    // ---- conv channel mapping ----
    // t<64:        xh channel h*64+t  -> Xm[l][t];   2nd channel 1216+t -> Cm[l][64+t]
    // t in[64,192): B channel 960+t   -> Bm[l][t-64]
    // t in[192,256):C channel 960+t   -> Cm[l][t-192]
    const int chA = (t < 64) ? (h*HD + t) : (960 + t);
    float* baseA; int strA, colA;
    if (t < 64)       { baseA = Xm; strA = SX; colA = t; }
    else if (t < 192) { baseA = Bm; strA = SB; colA = t - 64; }
    else              { baseA = Cm; strA = SB; colA = t - 192; }
    float wA[4]; float cbA;
    #pragma unroll
    for (int k=0;k<4;k++) wA[k] = cw[chA*4 + k];
    cbA = cb[chA];
    const bool hasB = (t < 64);
    const int chB = 1216 + t;
    float wB[4] = {0,0,0,0}; float cbB = 0.f;
    if (hasB) {
        #pragma unroll
        for (int k=0;k<4;k++) wB[k] = cw[chB*4 + k];
        cbB = cb[chB];
    }

    const float Ah     = -expf(al[h]);
    const float dtbias = dtb[h];
    const float Dh     = Dw[h];

    // ---- phase 1: conv + silu for all steps (4-way partial sums inline) ----
    {
        const float* zA = zp + (size_t)b*L*DPROJ + 1024 + chA;
        const float* zB = zp + (size_t)b*L*DPROJ + 1024 + chB;
        float a0=0.f, a1=0.f, a2=0.f, b0=0.f, b1=0.f, b2=0.f;
        #pragma unroll 4
        for (int l=0; l<L; ++l){
            const size_t o = (size_t)l*DPROJ;
            const float rawA = zA[o] + zA[pstr+o] + zA[2*pstr+o] + zA[3*pstr+o];
            float acc = cbA + wA[0]*a0 + wA[1]*a1 + wA[2]*a2 + wA[3]*rawA;
            baseA[l*strA + colA] = siluf(acc);
            a0=a1; a1=a2; a2=rawA;
            if (hasB){
                const float rawB = zB[o] + zB[pstr+o] + zB[2*pstr+o] + zB[3*pstr+o];
                float accB = cbB + wB[0]*b0 + wB[1]*b1 + wB[2]*b2 + wB[3]*rawB;
                Cm[l*SB + 64 + t] = siluf(accB);
                b0=b1; b1=b2; b2=rawB;
            }
        }
    }
    // dt: softplus + inclusive prefix scan (wave 0)
    if (t < 64){
        float dtv = 0.f;
        if (t < L){
            const float* zD = zp + (size_t)(b*L + t)*DPROJ + 2304 + h;
            float raw = zD[0] + zD[pstr] + zD[2*pstr] + zD[3*pstr] + dtbias;
            dtv = (raw > 20.f) ? raw : log1pf(expf(raw));
        }
        float s = dtv;
        #pragma unroll
        for (int d=1; d<64; d<<=1){
            float o = __shfl_up(s, d, 64);
            if (t >= d) s += o;
        }
        dts[t] = dtv; sps[t] = s;
    }
    __syncthreads();

    // ---- phase 2: G = decay .* (C @ B^T) ----
    const int ti = t >> 4, tj = t & 15;
    int la[4], mb[4];
    #pragma unroll
    for (int a=0;a<4;a++){ la[a] = ti + 16*a; mb[a] = tj + 16*a; }
    {
        float accG[4][4] = {};
        for (int k0=0; k0<128; k0+=4){
            float4 cr[4], br[4];
            #pragma unroll
            for (int a=0;a<4;a++) cr[a] = *(const float4*)&Cm[la[a]*SB + k0];
            #pragma unroll
            for (int q=0;q<4;q++) br[q] = *(const float4*)&Bm[mb[q]*SB + k0];
            #pragma unroll
            for (int a=0;a<4;a++)
                #pragma unroll
                for (int q=0;q<4;q++)
                    accG[a][q] += cr[a].x*br[q].x + cr[a].y*br[q].y
                                + cr[a].z*br[q].z + cr[a].w*br[q].w;
        }
        #pragma unroll
        for (int a=0;a<4;a++){
            if (la[a] < L){
                const float sl = sps[la[a]];
                #pragma unroll
                for (int q=0;q<4;q++){
                    if (mb[q] < L){
                        float v = 0.f;
                        if (mb[q] <= la[a])
                            v = expf(Ah*(sl - sps[mb[q]])) * dts[mb[q]] * accG[a][q];
                        Gm[la[a]*SG + mb[q]] = v;
                    }
                }
            }
        }
    }
    __syncthreads();

    // ---- phase 3: Y = G @ X + D*X ----
    {
        float accY[4][4] = {};
        for (int m=0; m<L; ++m){
            float xr[4], gr[4];
            #pragma unroll
            for (int q=0;q<4;q++) xr[q] = Xm[m*SX + tj + 16*q];
            #pragma unroll
            for (int a=0;a<4;a++) gr[a] = (la[a] < L) ? Gm[la[a]*SG + m] : 0.f;
            #pragma unroll
            for (int a=0;a<4;a++)
                #pragma unroll
                for (int q=0;q<4;q++) accY[a][q] = fmaf(gr[a], xr[q], accY[a][q]);
        }
        #pragma unroll
        for (int a=0;a<4;a++){
            if (la[a] < L){
                float* yrow = y + (size_t)(b*L + la[a])*DIN + h*HD;
                #pragma unroll
                for (int q=0;q<4;q++){
                    int col = tj + 16*q;
                    yrow[col] = accY[a][q] + Dh * Xm[la[a]*SX + col];
                }
            }
        }
    }
}

// ---------------- gated RMSNorm (z read from in-proj partials) ----------------
__global__ __launch_bounds__(256) void gated_rmsnorm(
    const float* __restrict__ y_s, const float* __restrict__ pS, const float* __restrict__ nw_s, float* __restrict__ o_s,
    const float* __restrict__ y_g, const float* __restrict__ pG, const float* __restrict__ nw_g, float* __restrict__ o_g)
{
    int r = blockIdx.x, t = threadIdx.x;
    int st = (r >= RS);
    int row = st ? r - RS : r;
    const float* y   = (st ? y_g : y_s) + (size_t)row*DIN;
    const float* pin = st ? pG : pS;
    const size_t pstr = (size_t)(st ? RG : RS) * DPROJ;
    const size_t zoff = (size_t)row*DPROJ;
    const float* nw = st ? nw_g : nw_s;
    float* o = (st ? o_g : o_s) + (size_t)row*DIN;

    float g[4]; float s2 = 0.f;
    #pragma unroll
    for (int i=0;i<4;i++){
        int idx = t + i*256;
        float zv = pin[zoff+idx] + pin[pstr+zoff+idx] + pin[2*pstr+zoff+idx] + pin[3*pstr+zoff+idx];
        float gv = y[idx] * siluf(zv);
        g[i] = gv; s2 += gv*gv;
    }
    #pragma unroll
    for (int o2=32;o2;o2>>=1) s2 += __shfl_xor(s2, o2, 64);
    __shared__ float red[4];
    if ((t & 63) == 0) red[t>>6] = s2;
    __syncthreads();
    float S2 = red[0]+red[1]+red[2]+red[3];
    float scale = rsqrtf(S2*(1.f/DIN) + 1e-5f);
    #pragma unroll
    for (int i=0;i<4;i++){
        int idx = t + i*256;
        o[idx] = g[i]*scale*nw[idx];
    }
}

// ---------------- LayerNorm rows ----------------
__global__ __launch_bounds__(256) void ln_rows(
    const float* __restrict__ x, const float* __restrict__ w, const float* __restrict__ b,
    float* __restrict__ out, int D)
{
    int r = blockIdx.x, t = threadIdx.x;
    const float* xr = x + (size_t)r*D;
    float s = 0.f, s2 = 0.f;
    for (int i=t;i<D;i+=256){ float v = xr[i]; s += v; s2 += v*v; }
    #pragma unroll
    for (int o=32;o;o>>=1){ s += __shfl_xor(s,o,64); s2 += __shfl_xor(s2,o,64); }
    __shared__ float red[8];
    if ((t & 63) == 0){ red[t>>6] = s; red[4+(t>>6)] = s2; }
    __syncthreads();
    float S  = red[0]+red[1]+red[2]+red[3];
    float S2 = red[4]+red[5]+red[6]+red[7];
    float mean = S/D;
    float var  = S2/D - mean*mean;
    float inv  = rsqrtf(var + 1e-5f);
    for (int i=t;i<D;i+=256)
        out[(size_t)r*D + i] = (xr[i]-mean)*inv*w[i] + b[i];
}

// ---------------- cross-attention core (QKV from partials + bias) ----------------
template<int LQ, int LKV, int NS>
__global__ __launch_bounds__(64) void mha_attn(
    const float* __restrict__ pq, const float* __restrict__ pk, const float* __restrict__ pv,
    const float* __restrict__ qb, const float* __restrict__ kb, const float* __restrict__ vb,
    float* __restrict__ out, int Mq, int Mkv)
{
    const int hh = blockIdx.x, b = blockIdx.y, t = threadIdx.x;
    const size_t strQ = (size_t)Mq*DM, strKV = (size_t)Mkv*DM;
    __shared__ float ks[LKV*64], vs[LKV*64];
    const float kbv = kb[hh*64+t], vbv = vb[hh*64+t];
    for (int r=0;r<LKV;r++){
        const size_t off = (size_t)(b*LKV+r)*DM + hh*64 + t;
        float kv = kbv, vv = vbv;
        #pragma unroll
        for (int s=0;s<NS;s++){ kv += pk[s*strKV + off]; vv += pv[s*strKV + off]; }
        ks[r*64+t] = kv; vs[r*64+t] = vv;
    }
    __syncthreads();
    if (t < LQ) {
        float q[64];
        const size_t qoff = (size_t)(b*LQ+t)*DM + hh*64;
        #pragma unroll
        for (int d=0;d<64;d++){
            float qv = qb[hh*64+d];
            #pragma unroll
            for (int s=0;s<NS;s++) qv += pq[s*strQ + qoff + d];
            q[d] = qv;
        }
        float sc[LKV]; float mx = -1e30f;
        #pragma unroll
        for (int j=0;j<LKV;j++){
            float s = 0.f;
            #pragma unroll
            for (int d=0;d<64;d++) s += q[d]*ks[j*64+d];
            s *= 0.125f;
            sc[j] = s; mx = fmaxf(mx, s);
        }
        float se = 0.f;
        #pragma unroll
        for (int j=0;j<LKV;j++){ sc[j] = expf(sc[j]-mx); se += sc[j]; }
        float inv = 1.f/se;
        float* orow = out + (size_t)(b*LQ+t)*DM + hh*64;
        #pragma unroll
        for (int d=0;d<64;d++){
            float o = 0.f;
            #pragma unroll
            for (int j=0;j<LKV;j++) o += sc[j]*vs[j*64+d];
            orow[d] = o*inv;
        }
    }
}

// ---------------- mean pool (concat) ----------------
__global__ __launch_bounds__(512) void meanpool(
    const float* __restrict__ xs, const float* __restrict__ xg, float* __restrict__ fused)
{
    int b = blockIdx.x, d = threadIdx.x;
    float s = 0.f;
    for (int l=0;l<LS;l++) s += xs[(size_t)(b*LS+l)*DM + d];
    fused[b*1024 + d] = s*(1.f/LS);
    float g = 0.f;
    for (int l=0;l<LG;l++) g += xg[(size_t)(b*LG+l)*DM + d];
    fused[b*1024 + 512 + d] = g*(1.f/LG);
}

// ---------------- classifier head ----------------
__global__ __launch_bounds__(64) void cls_head(
    const float* __restrict__ lnf, const float* __restrict__ w,
    const float* __restrict__ bias, float* __restrict__ out)
{
    int b = blockIdx.x, t = threadIdx.x;
    __shared__ float xr[1024];
    for (int i=t;i<1024;i+=64) xr[i] = lnf[b*1024+i];
    __syncthreads();
    if (t < 55){
        float a = bias[t];
        const float* wr = w + (size_t)t*1024;
        for (int k=0;k<1024;k++) a += xr[k]*wr[k];
        out[b*55 + t] = a;
    }
}

// ---------------- launch ----------------
extern "C" void kernel_launch(void* const* d_in, const int* in_sizes, int n_in,
                              void* d_out, int out_size, void* d_ws, size_t ws_size,
                              hipStream_t stream)
{
    (void)in_sizes; (void)n_in; (void)out_size; (void)ws_size;
    const float* x_spectra = (const float*)d_in[0];
    const float* x_gaia    = (const float*)d_in[1];
    const float* tok_w_s   = (const float*)d_in[2];
    const float* tok_b_s   = (const float*)d_in[3];
    const float* tok_w_g   = (const float*)d_in[4];
    const float* tok_b_g   = (const float*)d_in[5];
    const float* ms_Win    = (const float*)d_in[6];
    const float* ms_conv_w = (const float*)d_in[7];
    const float* ms_conv_b = (const float*)d_in[8];
    const float* ms_dtb    = (const float*)d_in[9];
    const float* ms_Alog   = (const float*)d_in[10];
    const float* ms_D      = (const float*)d_in[11];
    const float* ms_nw     = (const float*)d_in[12];
    const float* ms_Wout   = (const float*)d_in[13];
    const float* mg_Win    = (const float*)d_in[14];
    const float* mg_conv_w = (const float*)d_in[15];
    const float* mg_conv_b = (const float*)d_in[16];
    const float* mg_dtb    = (const float*)d_in[17];
    const float* mg_Alog   = (const float*)d_in[18];
    const float* mg_D      = (const float*)d_in[19];
    const float* mg_nw     = (const float*)d_in[20];
    const float* mg_Wout   = (const float*)d_in[21];
    const float* cas_ln_w  = (const float*)d_in[22];
    const float* cas_ln_b  = (const float*)d_in[23];
    const float* cas_in_w  = (const float*)d_in[24];
    const float* cas_in_b  = (const float*)d_in[25];
    const float* cas_out_w = (const float*)d_in[26];
    const float* cas_out_b = (const float*)d_in[27];
    const float* cag_ln_w  = (const float*)d_in[28];
    const float* cag_ln_b  = (const float*)d_in[29];
    const float* cag_in_w  = (const float*)d_in[30];
    const float* cag_in_b  = (const float*)d_in[31];
    const float* cag_out_w = (const float*)d_in[32];
    const float* cag_out_b = (const float*)d_in[33];
    const float* cls_ln_w  = (const float*)d_in[34];
    const float* cls_ln_b  = (const float*)d_in[35];
    const float* cls_w     = (const float*)d_in[36];
    const float* cls_b     = (const float*)d_in[37];

    float* p = (float*)d_ws;
    auto alloc = [&](size_t n){ float* r = p; p += n; return r; };
    float* xs       = alloc((size_t)RS*DM);
    float* xg       = alloc((size_t)RG*DM);
    float* y_s      = alloc((size_t)RS*DIN);
    float* y_g      = alloc((size_t)RG*DIN);
    float* yn_s     = alloc((size_t)RS*DIN);
    float* yn_g     = alloc((size_t)RG*DIN);
    float* lnbuf    = alloc((size_t)RS*DM);
    float* attn_out = alloc((size_t)RS*DM);
    float* fused    = alloc((size_t)BB*1024);
    float* lnf      = alloc((size_t)BB*1024);
    float* part_inS  = alloc((size_t)SP_IN*RS*DPROJ);
    float* part_inG  = alloc((size_t)SP_IN*RG*DPROJ);
    float* part_outS = alloc((size_t)SP_OUT*RS*DM);
    float* part_outG = alloc((size_t)SP_OUT*RG*DM);
    float* part_q    = alloc((size_t)SP_ATT*RS*DM);
    float* part_k    = alloc((size_t)SP_ATT*RS*DM);
    float* part_v    = alloc((size_t)SP_ATT*RS*DM);

    // tokenize
    tokenize_k<<<dim3(LS,BB), 512, 0, stream>>>(x_spectra, tok_w_s, tok_b_s, xs, 3647, 64, LS);
    tokenize_k<<<dim3(LG,BB), 512, 0, stream>>>(x_gaia,    tok_w_g, tok_b_g, xg, 18,   2,  LG);

    const int rblkS = (RS*DM + 1023)/1024;   // out-proj reduce blocks

    // mamba stacks
    for (int i=0;i<NLAY;i++){
        const float* Win_s  = ms_Win  + (size_t)i*DM*DPROJ;
        const float* Win_g  = mg_Win  + (size_t)i*DM*DPROJ;
        const float* cw_s   = ms_conv_w + (size_t)i*1280*4;
        const float* cw_g   = mg_conv_w + (size_t)i*1280*4;
        const float* cbv_s  = ms_conv_b + (size_t)i*1280;
        const float* cbv_g  = mg_conv_b + (size_t)i*1280;
        const float* dtb_s  = ms_dtb  + (size_t)i*NH;
        const float* dtb_g  = mg_dtb  + (size_t)i*NH;
        const float* al_s   = ms_Alog + (size_t)i*NH;
        const float* al_g   = mg_Alog + (size_t)i*NH;
        const float* Dw_s   = ms_D    + (size_t)i*NH;
        const float* Dw_g   = mg_D    + (size_t)i*NH;
        const float* nw_s   = ms_nw   + (size_t)i*DIN;
        const float* nw_g   = mg_nw   + (size_t)i*DIN;
        const float* Wout_s = ms_Wout + (size_t)i*DIN*DM;
        const float* Wout_g = mg_Wout + (size_t)i*DIN*DM;

        GemmJob inS{xs, Win_s, part_inS, RS};
        GemmJob inG{xg, Win_g, part_inG, RG};
        gemm_ps<128,8,false,SP_IN><<<dim3((DPROJ+127)/128, 8, 2*SP_IN), 256, 0, stream>>>(
            inS, inG, inG, DPROJ, DM);

        mamba_scan<<<dim3(NH, BB, 2), 256, 0, stream>>>(
            part_inS, part_inG, cw_s, cw_g, cbv_s, cbv_g, dtb_s, dtb_g,
            al_s, al_g, Dw_s, Dw_g, y_s, y_g);

        gated_rmsnorm<<<dim3(RS+RG), 256, 0, stream>>>(
            y_s, part_inS, nw_s, yn_s,  y_g, part_inG, nw_g, yn_g);

        GemmJob outS{yn_s, Wout_s, part_outS, RS};
        GemmJob outG{yn_g, Wout_g, part_outG, RG};
        gemm_ps<64,4,false,SP_OUT><<<dim3(DM/64, 8, 2*SP_OUT), 256, 0, stream>>>(
            outS, outG, outG, DM, DIN);

        RJob roS{part_outS, nullptr, nullptr, xs, RS};
        RJob roG{part_outG, nullptr, nullptr, xg, RG};
        reduce_k<SP_OUT><<<dim3(rblkS, 2), 256, 0, stream>>>(roS, roG, DM);
    }

    // cross-attention: xs = xs + MHA(LN(xs), xg)
    {
        ln_rows<<<dim3(RS), 256, 0, stream>>>(xs, cas_ln_w, cas_ln_b, lnbuf, DM);
        GemmJob jq{lnbuf, cas_in_w,            part_q, RS};
        GemmJob jk{xg,    cas_in_w +  512*512, part_k, RG};
        GemmJob jv{xg,    cas_in_w + 1024*512, part_v, RG};
        gemm_ps<64,4,true,SP_ATT><<<dim3(DM/64, 8, 3*SP_ATT), 256, 0, stream>>>(jq, jk, jv, DM, DM);
        mha_attn<LS,LG,SP_ATT><<<dim3(8,BB), 64, 0, stream>>>(
            part_q, part_k, part_v, cas_in_b, cas_in_b+512, cas_in_b+1024, attn_out, RS, RG);
        GemmJob jo{attn_out, cas_out_w, part_outS, RS};
        gemm_ps<64,4,true,SP_ATT><<<dim3(DM/64, 8, SP_ATT), 256, 0, stream>>>(jo, jo, jo, DM, DM);
        RJob ro{part_outS, cas_out_b, xs, xs, RS};
        reduce_k<SP_ATT><<<dim3(rblkS, 1), 256, 0, stream>>>(ro, ro, DM);
    }

    // cross-attention: xg = xg + MHA(LN(xg), xs_updated)
    {
        ln_rows<<<dim3(RG), 256, 0, stream>>>(xg, cag_ln_w, cag_ln_b, lnbuf, DM);
        GemmJob jq{lnbuf, cag_in_w,            part_q, RG};
        GemmJob jk{xs,    cag_in_w +  512*512, part_k, RS};
        GemmJob jv{xs,    cag_in_w + 1024*512, part_v, RS};
        gemm_ps<64,4,true,SP_ATT><<<dim3(DM/64, 8, 3*SP_ATT), 256, 0, stream>>>(jq, jk, jv, DM, DM);
        mha_attn<LG,LS,SP_ATT><<<dim3(8,BB), 64, 0, stream>>>(
            part_q, part_k, part_v, cag_in_b, cag_in_b+512, cag_in_b+1024, attn_out, RG, RS);
        GemmJob jo{attn_out, cag_out_w, part_outS, RG};
        gemm_ps<64,4,true,SP_ATT><<<dim3(DM/64, 2, SP_ATT), 256, 0, stream>>>(jo, jo, jo, DM, DM);
        RJob ro{part_outS, cag_out_b, xg, xg, RG};
        reduce_k<SP_ATT><<<dim3((RG*DM+1023)/1024, 1), 256, 0, stream>>>(ro, ro, DM);
    }

    // head
    meanpool<<<dim3(BB), 512, 0, stream>>>(xs, xg, fused);
    ln_rows<<<dim3(BB), 256, 0, stream>>>(fused, cls_ln_w, cls_ln_b, lnf, 1024);
    cls_head<<<dim3(BB), 64, 0, stream>>>(lnf, cls_w, cls_b, (float*)d_out);
}

// Round 6
// 1126.157 us; speedup vs baseline: 1.2628x; 1.2628x over previous
//
#include <hip/hip_runtime.h>
#include <cmath>

// ---------------- constants ----------------
constexpr int BB    = 8;     // batch
constexpr int LS    = 57;    // spectra tokens
constexpr int LG    = 9;     // gaia tokens
constexpr int RS    = BB*LS; // 456
constexpr int RG    = BB*LG; // 72
constexpr int DM    = 512;   // d_model
constexpr int DPROJ = 2320;
constexpr int DIN   = 1024;
constexpr int NH    = 16;    // mamba heads
constexpr int HD    = 64;    // mamba headdim
constexpr int NLAY  = 10;

constexpr int SP_IN  = 4;    // split-K for in-proj  (K=512  -> 128/split)
constexpr int SP_OUT = 8;    // split-K for out-proj (K=1024 -> 128/split)
constexpr int SP_ATT = 4;    // split-K for attention gemms (K=512 -> 128/split)

__device__ __forceinline__ float siluf(float x){ return x / (1.f + expf(-x)); }

// ---------------- tokenize ----------------
__global__ __launch_bounds__(512) void tokenize_k(
    const float* __restrict__ x, const float* __restrict__ w, const float* __restrict__ bias,
    float* __restrict__ out, int in_dim, int tok_dim, int ntok)
{
    int t = blockIdx.x, b = blockIdx.y, d = threadIdx.x;
    __shared__ float xv[64];
    if (d < tok_dim) {
        int idx = t*tok_dim + d;
        xv[d] = (idx < in_dim) ? x[(size_t)b*in_dim + idx] : 0.f;
    }
    __syncthreads();
    float acc = bias[d];
    for (int k=0;k<tok_dim;k++) acc += xv[k]*w[(size_t)k*DM + d];
    out[(size_t)(b*ntok + t)*DM + d] = acc;
}

// ---------------- split-K f32 GEMM -> partials ----------------
struct GemmJob {
    const float* A; const float* B; float* part; int M;
};

template<int BN, int TN, bool TB, int NSPLIT>
__global__ __launch_bounds__(256) void gemm_ps(GemmJob j0, GemmJob j1, GemmJob j2, int N, int K)
{
    const int z = blockIdx.z;
    const int job = z / NSPLIT, split = z % NSPLIT;
    GemmJob jb = (job==0) ? j0 : (job==1 ? j1 : j2);
    const int bm = blockIdx.y*64, bn = blockIdx.x*BN;
    const int M = jb.M;
    if (bm >= M) return;
    __shared__ float As[2][16][68];
    __shared__ float Bs[2][16][BN+4];
    const int tid = threadIdx.x, tx = tid & 15, ty = tid >> 4;
    const float* __restrict__ A  = jb.A;
    const float* __restrict__ Bm = jb.B;
    float acc[4][TN] = {};

    const int arow = tid>>2, akb = (tid&3)*4;
    float4 ra, rb0, rb1;

    auto zero4 = [](){ float4 zz; zz.x=0.f; zz.y=0.f; zz.z=0.f; zz.w=0.f; return zz; };

    auto loadT = [&](int k0){
        ra = (bm+arow < M) ? *(const float4*)(A + (size_t)(bm+arow)*K + k0 + akb) : zero4();
        if constexpr (!TB) {
            const int kr = tid>>4, c4 = (tid&15)*4;
            rb0 = (bn+c4 < N) ? *(const float4*)(Bm + (size_t)(k0+kr)*N + bn + c4) : zero4();
            if constexpr (TN==8)
                rb1 = (bn+64+c4 < N) ? *(const float4*)(Bm + (size_t)(k0+kr)*N + bn + 64 + c4) : zero4();
        } else {
            const int nr = tid>>2, kb = (tid&3)*4;
            rb0 = (bn+nr < N) ? *(const float4*)(Bm + (size_t)(bn+nr)*K + k0 + kb) : zero4();
        }
    };
    auto storeT = [&](int buf){
        As[buf][akb+0][arow] = ra.x;
        As[buf][akb+1][arow] = ra.y;
        As[buf][akb+2][arow] = ra.z;
        As[buf][akb+3][arow] = ra.w;
        if constexpr (!TB) {
            const int kr = tid>>4, c4 = (tid&15)*4;
            *(float4*)&Bs[buf][kr][c4] = rb0;
            if constexpr (TN==8) *(float4*)&Bs[buf][kr][64+c4] = rb1;
        } else {
            const int nr = tid>>2, kb = (tid&3)*4;
            Bs[buf][kb+0][nr] = rb0.x;
            Bs[buf][kb+1][nr] = rb0.y;
            Bs[buf][kb+2][nr] = rb0.z;
            Bs[buf][kb+3][nr] = rb0.w;
        }
    };

    const int Kper = K/NSPLIT;
    const int koff = split*Kper;
    const int nk = Kper/16;
    loadT(koff);
    storeT(0);
    __syncthreads();
    for (int t=0; t<nk; ++t){
        const int cur = t & 1;
        if (t+1 < nk) loadT(koff + (t+1)*16);
        #pragma unroll
        for (int kk=0; kk<16; ++kk){
            float4 av = *(const float4*)&As[cur][kk][ty*4];
            float a[4] = {av.x, av.y, av.z, av.w};
            float b[TN];
            #pragma unroll
            for (int g=0; g<TN/4; ++g){
                float4 bv = *(const float4*)&Bs[cur][kk][tx*TN + g*4];
                b[g*4+0]=bv.x; b[g*4+1]=bv.y; b[g*4+2]=bv.z; b[g*4+3]=bv.w;
            }
            #pragma unroll
            for (int i=0;i<4;i++)
                #pragma unroll
                for (int j=0;j<TN;j++) acc[i][j] = fmaf(a[i], b[j], acc[i][j]);
        }
        if (t+1 < nk) storeT(cur^1);
        __syncthreads();
    }

    float* __restrict__ P = jb.part + (size_t)split*M*N;
    #pragma unroll
    for (int i=0;i<4;i++){
        int m = bm + ty*4 + i;
        if (m < M){
            #pragma unroll
            for (int j=0;j<TN;j++){
                int n = bn + tx*TN + j;
                if (n < N) P[(size_t)m*N + n] = acc[i][j];
            }
        }
    }
}

// ---------------- reduce partials (+bias, +res) ----------------
struct RJob { const float* part; const float* bias; const float* res; float* C; int M; };

template<int NS>
__global__ __launch_bounds__(256) void reduce_k(RJob j0, RJob j1, int N)
{
    RJob j = blockIdx.y ? j1 : j0;
    const size_t total = (size_t)j.M*N;
    const size_t i4 = ((size_t)blockIdx.x*256 + threadIdx.x)*4;
    if (i4 >= total) return;
    float4 s = *(const float4*)(j.part + i4);
    #pragma unroll
    for (int t=1;t<NS;t++){
        const float4 v = *(const float4*)(j.part + (size_t)t*total + i4);
        s.x+=v.x; s.y+=v.y; s.z+=v.z; s.w+=v.w;
    }
    const int n = (int)(i4 % (size_t)N);
    if (j.bias){ s.x+=j.bias[n]; s.y+=j.bias[n+1]; s.z+=j.bias[n+2]; s.w+=j.bias[n+3]; }
    if (j.res){ const float4 r = *(const float4*)(j.res + i4); s.x+=r.x; s.y+=r.y; s.z+=r.z; s.w+=r.w; }
    *(float4*)(j.C + i4) = s;
}

// ---------------- mamba prep: reduce partials + conv + silu + softplus ----------------
// Fully parallel over (row, quad-of-channels). Outputs:
//   zsilu [R][1024] = silu(z)            (consumed by gated_rmsnorm)
//   xh    [R][1024] = silu(conv(xBC[:1024]))
//   Bc    [R][128], Cc [R][128] = silu(conv(B/C channels))
//   dtw   [R][16]  = softplus(dt_raw + dt_bias)
struct PrepJob {
    const float* part;     // [SP_IN][R][DPROJ]
    float* zsilu; float* xh; float* Bc; float* Cc; float* dtw;
    const float* cw; const float* cb; const float* dtb;
    int R, L;
};

__device__ __forceinline__ float4 psum4(const float* p, size_t pstr){
    float4 a = *(const float4*)p;
    const float4 b = *(const float4*)(p + pstr);
    const float4 c = *(const float4*)(p + 2*pstr);
    const float4 d = *(const float4*)(p + 3*pstr);
    a.x += b.x + c.x + d.x;
    a.y += b.y + c.y + d.y;
    a.z += b.z + c.z + d.z;
    a.w += b.w + c.w + d.w;
    return a;
}

__global__ __launch_bounds__(256) void mamba_prep(PrepJob js, PrepJob jg)
{
    PrepJob j = blockIdx.y ? jg : js;
    const int R = j.R, L = j.L;
    constexpr int QPR = 580;   // 256 (z) + 320 (conv) + 4 (dt) quads per row
    const int q = blockIdx.x*256 + threadIdx.x;
    if (q >= R*QPR) return;
    const int r = q / QPR, qi = q % QPR;
    const int l = r % L;
    const size_t pstr = (size_t)R*DPROJ;
    const float* base = j.part + (size_t)r*DPROJ;

    if (qi < 256) {                 // ---- z region -> silu(z)
        const int c = qi*4;
        float4 s = psum4(base + c, pstr);
        s.x = siluf(s.x); s.y = siluf(s.y); s.z = siluf(s.z); s.w = siluf(s.w);
        *(float4*)(j.zsilu + (size_t)r*1024 + c) = s;
    } else if (qi < 576) {          // ---- conv region
        const int cc = (qi-256)*4;  // 0..1276
        float tk[4][4];
        #pragma unroll
        for (int k=0;k<4;k++){
            const int lr = l - 3 + k;
            if (lr >= 0){
                float4 v = psum4(j.part + (size_t)(r-3+k)*DPROJ + 1024 + cc, pstr);
                tk[k][0]=v.x; tk[k][1]=v.y; tk[k][2]=v.z; tk[k][3]=v.w;
            } else {
                tk[k][0]=0.f; tk[k][1]=0.f; tk[k][2]=0.f; tk[k][3]=0.f;
            }
        }
        const float4 cb4 = *(const float4*)(j.cb + cc);
        const float cba[4] = {cb4.x, cb4.y, cb4.z, cb4.w};
        float out[4];
        #pragma unroll
        for (int jj=0;jj<4;jj++){
            const float4 wv = *(const float4*)(j.cw + (size_t)(cc+jj)*4);
            float v = cba[jj] + wv.x*tk[0][jj] + wv.y*tk[1][jj]
                              + wv.z*tk[2][jj] + wv.w*tk[3][jj];
            out[jj] = siluf(v);
        }
        float4 o4; o4.x=out[0]; o4.y=out[1]; o4.z=out[2]; o4.w=out[3];
        if (cc < 1024)       *(float4*)(j.xh + (size_t)r*1024 + cc)        = o4;
        else if (cc < 1152)  *(float4*)(j.Bc + (size_t)r*128 + (cc-1024))  = o4;
        else                 *(float4*)(j.Cc + (size_t)r*128 + (cc-1152))  = o4;
    } else {                        // ---- dt region
        const int hd = (qi-576)*4;  // 0,4,8,12
        float4 s = psum4(base + 2304 + hd, pstr);
        const float4 b4 = *(const float4*)(j.dtb + hd);
        float raw[4] = {s.x+b4.x, s.y+b4.y, s.z+b4.z, s.w+b4.w};
        float4 o4;
        float* op = &o4.x;
        #pragma unroll
        for (int jj=0;jj<4;jj++)
            op[jj] = (raw[jj] > 20.f) ? raw[jj] : log1pf(expf(raw[jj]));
        *(float4*)(j.dtw + (size_t)r*16 + hd) = o4;
    }
}

// ---------------- CBT = C @ B^T per (batch, stack) — head-independent ----------------
__global__ __launch_bounds__(256) void mamba_cbt(
    const float* __restrict__ Bc_s, const float* __restrict__ Cc_s, float* __restrict__ cbt_s,
    const float* __restrict__ Bc_g, const float* __restrict__ Cc_g, float* __restrict__ cbt_g)
{
    const int b = blockIdx.x, st = blockIdx.y;
    const float* Bc = st ? Bc_g : Bc_s;
    const float* Cc = st ? Cc_g : Cc_s;
    float* cbt = st ? cbt_g : cbt_s;
    const int L = st ? LG : LS;
    constexpr int SB = 132;
    __shared__ float Bm[64*SB], Cm[64*SB];
    const int t = threadIdx.x;
    for (int idx = t; idx < L*32; idx += 256){
        const int l = idx >> 5, c4 = (idx & 31)*4;
        *(float4*)&Bm[l*SB + c4] = *(const float4*)(Bc + (size_t)(b*L+l)*128 + c4);
        *(float4*)&Cm[l*SB + c4] = *(const float4*)(Cc + (size_t)(b*L+l)*128 + c4);
    }
    __syncthreads();
    const int ti = t >> 4, tj = t & 15;
    float acc[4][4] = {};
    for (int k0=0;k0<128;k0+=4){
        float4 cr[4], br[4];
        #pragma unroll
        for (int a=0;a<4;a++) cr[a] = *(const float4*)&Cm[(ti+16*a)*SB + k0];
        #pragma unroll
        for (int qq=0;qq<4;qq++) br[qq] = *(const float4*)&Bm[(tj+16*qq)*SB + k0];
        #pragma unroll
        for (int a=0;a<4;a++)
            #pragma unroll
            for (int qq=0;qq<4;qq++)
                acc[a][qq] += cr[a].x*br[qq].x + cr[a].y*br[qq].y
                            + cr[a].z*br[qq].z + cr[a].w*br[qq].w;
    }
    #pragma unroll
    for (int a=0;a<4;a++){
        const int i = ti + 16*a;
        if (i < L){
            #pragma unroll
            for (int qq=0;qq<4;qq++){
                const int jj = tj + 16*qq;
                if (jj < L) cbt[(size_t)b*3840 + i*60 + jj] = acc[a][qq];
            }
        }
    }
}

// ---------------- Y = (decay .* CBT) @ X + D*X per (head, batch, stack) ----------------
__global__ __launch_bounds__(256) void mamba_y(
    const float* __restrict__ cbt_s, const float* __restrict__ xh_s, const float* __restrict__ dtw_s,
    const float* __restrict__ al_s, const float* __restrict__ Dw_s, float* __restrict__ y_s,
    const float* __restrict__ cbt_g, const float* __restrict__ xh_g, const float* __restrict__ dtw_g,
    const float* __restrict__ al_g, const float* __restrict__ Dw_g, float* __restrict__ y_g)
{
    const int h = blockIdx.x, b = blockIdx.y, st = blockIdx.z;
    const float* cbt = st ? cbt_g : cbt_s;
    const float* xh  = st ? xh_g  : xh_s;
    const float* dtw = st ? dtw_g : dtw_s;
    const float* al  = st ? al_g  : al_s;
    const float* Dw  = st ? Dw_g  : Dw_s;
    float* y = st ? y_g : y_s;
    const int L = st ? LG : LS;

    const int t = threadIdx.x;
    constexpr int SG = 60, SX = 68;
    __shared__ float Gm[64*SG], Xm[64*SX];
    __shared__ float dts[64], sps[64];

    const float Ah = -expf(al[h]);
    const float Dh = Dw[h];

    // dt + prefix scan (wave 0)
    if (t < 64){
        float dtv = (t < L) ? dtw[(size_t)(b*L+t)*16 + h] : 0.f;
        float s = dtv;
        #pragma unroll
        for (int d=1; d<64; d<<=1){
            float o = __shfl_up(s, d, 64);
            if (t >= d) s += o;
        }
        dts[t] = dtv; sps[t] = s;
    }
    // load X tile
    for (int idx = t; idx < L*16; idx += 256){
        const int l = idx >> 4, c4 = (idx & 15)*4;
        *(float4*)&Xm[l*SX + c4] = *(const float4*)(xh + (size_t)(b*L+l)*1024 + h*64 + c4);
    }
    __syncthreads();

    // G = decay .* CBT
    for (int idx = t; idx < L*15; idx += 256){
        const int i = idx/15, j4 = (idx%15)*4;
        const float4 v = *(const float4*)(cbt + (size_t)b*3840 + i*60 + j4);
        const float va[4] = {v.x, v.y, v.z, v.w};
        float g[4];
        const float si = sps[i];
        #pragma unroll
        for (int jj=0;jj<4;jj++){
            const int jc = j4 + jj;
            float gg = 0.f;
            if (jc <= i && jc < L)
                gg = expf(Ah*(si - sps[jc])) * dts[jc] * va[jj];
            g[jj] = gg;
        }
        float4 g4; g4.x=g[0]; g4.y=g[1]; g4.z=g[2]; g4.w=g[3];
        *(float4*)&Gm[i*SG + j4] = g4;
    }
    __syncthreads();

    // Y = G @ X + D*X
    const int ti = t >> 4, tj = t & 15;
    int la[4];
    #pragma unroll
    for (int a=0;a<4;a++) la[a] = ti + 16*a;
    float accY[4][4] = {};
    for (int m=0; m<L; ++m){
        float xr[4], gr[4];
        #pragma unroll
        for (int qq=0;qq<4;qq++) xr[qq] = Xm[m*SX + tj + 16*qq];
        #pragma unroll
        for (int a=0;a<4;a++) gr[a] = (la[a] < L) ? Gm[la[a]*SG + m] : 0.f;
        #pragma unroll
        for (int a=0;a<4;a++)
            #pragma unroll
            for (int qq=0;qq<4;qq++) accY[a][qq] = fmaf(gr[a], xr[qq], accY[a][qq]);
    }
    #pragma unroll
    for (int a=0;a<4;a++){
        if (la[a] < L){
            float* yrow = y + (size_t)(b*L + la[a])*DIN + h*HD;
            #pragma unroll
            for (int qq=0;qq<4;qq++){
                const int col = tj + 16*qq;
                yrow[col] = accY[a][qq] + Dh * Xm[la[a]*SX + col];
            }
        }
    }
}

// ---------------- gated RMSNorm (z pre-silu'd by prep) ----------------
__global__ __launch_bounds__(256) void gated_rmsnorm(
    const float* __restrict__ y_s, const float* __restrict__ zs_s, const float* __restrict__ nw_s, float* __restrict__ o_s,
    const float* __restrict__ y_g, const float* __restrict__ zs_g, const float* __restrict__ nw_g, float* __restrict__ o_g)
{
    int r = blockIdx.x, t = threadIdx.x;
    int st = (r >= RS);
    int row = st ? r - RS : r;
    const float* y  = (st ? y_g  : y_s) + (size_t)row*DIN;
    const float* zs = (st ? zs_g : zs_s) + (size_t)row*DIN;
    const float* nw = st ? nw_g : nw_s;
    float* o = (st ? o_g : o_s) + (size_t)row*DIN;

    float g[4]; float s2 = 0.f;
    #pragma unroll
    for (int i=0;i<4;i++){
        int idx = t + i*256;
        float gv = y[idx] * zs[idx];
        g[i] = gv; s2 += gv*gv;
    }
    #pragma unroll
    for (int o2=32;o2;o2>>=1) s2 += __shfl_xor(s2, o2, 64);
    __shared__ float red[4];
    if ((t & 63) == 0) red[t>>6] = s2;
    __syncthreads();
    float S2 = red[0]+red[1]+red[2]+red[3];
    float scale = rsqrtf(S2*(1.f/DIN) + 1e-5f);
    #pragma unroll
    for (int i=0;i<4;i++){
        int idx = t + i*256;
        o[idx] = g[i]*scale*nw[idx];
    }
}

// ---------------- LayerNorm rows ----------------
__global__ __launch_bounds__(256) void ln_rows(
    const float* __restrict__ x, const float* __restrict__ w, const float* __restrict__ b,
    float* __restrict__ out, int D)
{
    int r = blockIdx.x, t = threadIdx.x;
    const float* xr = x + (size_t)r*D;
    float s = 0.f, s2 = 0.f;
    for (int i=t;i<D;i+=256){ float v = xr[i]; s += v; s2 += v*v; }
    #pragma unroll
    for (int o=32;o;o>>=1){ s += __shfl_xor(s,o,64); s2 += __shfl_xor(s2,o,64); }
    __shared__ float red[8];
    if ((t & 63) == 0){ red[t>>6] = s; red[4+(t>>6)] = s2; }
    __syncthreads();
    float S  = red[0]+red[1]+red[2]+red[3];
    float S2 = red[4]+red[5]+red[6]+red[7];
    float mean = S/D;
    float var  = S2/D - mean*mean;
    float inv  = rsqrtf(var + 1e-5f);
    for (int i=t;i<D;i+=256)
        out[(size_t)r*D + i] = (xr[i]-mean)*inv*w[i] + b[i];
}

// ---------------- cross-attention core (QKV from partials + bias) ----------------
template<int LQ, int LKV, int NS>
__global__ __launch_bounds__(64) void mha_attn(
    const float* __restrict__ pq, const float* __restrict__ pk, const float* __restrict__ pv,
    const float* __restrict__ qb, const float* __restrict__ kb, const float* __restrict__ vb,
    float* __restrict__ out, int Mq, int Mkv)
{
    const int hh = blockIdx.x, b = blockIdx.y, t = threadIdx.x;
    const size_t strQ = (size_t)Mq*DM, strKV = (size_t)Mkv*DM;
    __shared__ float ks[LKV*64], vs[LKV*64];
    const float kbv = kb[hh*64+t], vbv = vb[hh*64+t];
    for (int r=0;r<LKV;r++){
        const size_t off = (size_t)(b*LKV+r)*DM + hh*64 + t;
        float kv = kbv, vv = vbv;
        #pragma unroll
        for (int s=0;s<NS;s++){ kv += pk[s*strKV + off]; vv += pv[s*strKV + off]; }
        ks[r*64+t] = kv; vs[r*64+t] = vv;
    }
    __syncthreads();
    if (t < LQ) {
        float q[64];
        const size_t qoff = (size_t)(b*LQ+t)*DM + hh*64;
        #pragma unroll
        for (int d=0;d<64;d++){
            float qv = qb[hh*64+d];
            #pragma unroll
            for (int s=0;s<NS;s++) qv += pq[s*strQ + qoff + d];
            q[d] = qv;
        }
        float sc[LKV]; float mx = -1e30f;
        #pragma unroll
        for (int j=0;j<LKV;j++){
            float s = 0.f;
            #pragma unroll
            for (int d=0;d<64;d++) s += q[d]*ks[j*64+d];
            s *= 0.125f;
            sc[j] = s; mx = fmaxf(mx, s);
        }
        float se = 0.f;
        #pragma unroll
        for (int j=0;j<LKV;j++){ sc[j] = expf(sc[j]-mx); se += sc[j]; }
        float inv = 1.f/se;
        float* orow = out + (size_t)(b*LQ+t)*DM + hh*64;
        #pragma unroll
        for (int d=0;d<64;d++){
            float o = 0.f;
            #pragma unroll
            for (int j=0;j<LKV;j++) o += sc[j]*vs[j*64+d];
            orow[d] = o*inv;
        }
    }
}

// ---------------- mean pool (concat) ----------------
__global__ __launch_bounds__(512) void meanpool(
    const float* __restrict__ xs, const float* __restrict__ xg, float* __restrict__ fused)
{
    int b = blockIdx.x, d = threadIdx.x;
    float s = 0.f;
    for (int l=0;l<LS;l++) s += xs[(size_t)(b*LS+l)*DM + d];
    fused[b*1024 + d] = s*(1.f/LS);
    float g = 0.f;
    for (int l=0;l<LG;l++) g += xg[(size_t)(b*LG+l)*DM + d];
    fused[b*1024 + 512 + d] = g*(1.f/LG);
}

// ---------------- classifier head ----------------
__global__ __launch_bounds__(64) void cls_head(
    const float* __restrict__ lnf, const float* __restrict__ w,
    const float* __restrict__ bias, float* __restrict__ out)
{
    int b = blockIdx.x, t = threadIdx.x;
    __shared__ float xr[1024];
    for (int i=t;i<1024;i+=64) xr[i] = lnf[b*1024+i];
    __syncthreads();
    if (t < 55){
        float a = bias[t];
        const float* wr = w + (size_t)t*1024;
        for (int k=0;k<1024;k++) a += xr[k]*wr[k];
        out[b*55 + t] = a;
    }
}

// ---------------- launch ----------------
extern "C" void kernel_launch(void* const* d_in, const int* in_sizes, int n_in,
                              void* d_out, int out_size, void* d_ws, size_t ws_size,
                              hipStream_t stream)
{
    (void)in_sizes; (void)n_in; (void)out_size; (void)ws_size;
    const float* x_spectra = (const float*)d_in[0];
    const float* x_gaia    = (const float*)d_in[1];
    const float* tok_w_s   = (const float*)d_in[2];
    const float* tok_b_s   = (const float*)d_in[3];
    const float* tok_w_g   = (const float*)d_in[4];
    const float* tok_b_g   = (const float*)d_in[5];
    const float* ms_Win    = (const float*)d_in[6];
    const float* ms_conv_w = (const float*)d_in[7];
    const float* ms_conv_b = (const float*)d_in[8];
    const float* ms_dtb    = (const float*)d_in[9];
    const float* ms_Alog   = (const float*)d_in[10];
    const float* ms_D      = (const float*)d_in[11];
    const float* ms_nw     = (const float*)d_in[12];
    const float* ms_Wout   = (const float*)d_in[13];
    const float* mg_Win    = (const float*)d_in[14];
    const float* mg_conv_w = (const float*)d_in[15];
    const float* mg_conv_b = (const float*)d_in[16];
    const float* mg_dtb    = (const float*)d_in[17];
    const float* mg_Alog   = (const float*)d_in[18];
    const float* mg_D      = (const float*)d_in[19];
    const float* mg_nw     = (const float*)d_in[20];
    const float* mg_Wout   = (const float*)d_in[21];
    const float* cas_ln_w  = (const float*)d_in[22];
    const float* cas_ln_b  = (const float*)d_in[23];
    const float* cas_in_w  = (const float*)d_in[24];
    const float* cas_in_b  = (const float*)d_in[25];
    const float* cas_out_w = (const float*)d_in[26];
    const float* cas_out_b = (const float*)d_in[27];
    const float* cag_ln_w  = (const float*)d_in[28];
    const float* cag_ln_b  = (const float*)d_in[29];
    const float* cag_in_w  = (const float*)d_in[30];
    const float* cag_in_b  = (const float*)d_in[31];
    const float* cag_out_w = (const float*)d_in[32];
    const float* cag_out_b = (const float*)d_in[33];
    const float* cls_ln_w  = (const float*)d_in[34];
    const float* cls_ln_b  = (const float*)d_in[35];
    const float* cls_w     = (const float*)d_in[36];
    const float* cls_b     = (const float*)d_in[37];

    float* p = (float*)d_ws;
    auto alloc = [&](size_t n){ float* r = p; p += n; return r; };
    float* xs       = alloc((size_t)RS*DM);
    float* xg       = alloc((size_t)RG*DM);
    float* y_s      = alloc((size_t)RS*DIN);
    float* y_g      = alloc((size_t)RG*DIN);
    float* yn_s     = alloc((size_t)RS*DIN);
    float* yn_g     = alloc((size_t)RG*DIN);
    float* lnbuf    = alloc((size_t)RS*DM);
    float* attn_out = alloc((size_t)RS*DM);
    float* fused    = alloc((size_t)BB*1024);
    float* lnf      = alloc((size_t)BB*1024);
    float* part_inS  = alloc((size_t)SP_IN*RS*DPROJ);
    float* part_inG  = alloc((size_t)SP_IN*RG*DPROJ);
    float* part_outS = alloc((size_t)SP_OUT*RS*DM);
    float* part_outG = alloc((size_t)SP_OUT*RG*DM);
    // union region: mamba mixer buffers during layers; attn partials afterwards
    float* uni       = alloc((size_t)3*SP_ATT*RS*DM);
    float* zsilu_s = uni;
    float* zsilu_g = zsilu_s + (size_t)RS*1024;
    float* xh_s    = zsilu_g + (size_t)RG*1024;
    float* xh_g    = xh_s    + (size_t)RS*1024;
    float* Bc_s    = xh_g    + (size_t)RG*1024;
    float* Bc_g    = Bc_s    + (size_t)RS*128;
    float* Cc_s    = Bc_g    + (size_t)RG*128;
    float* Cc_g    = Cc_s    + (size_t)RS*128;
    float* dtw_s   = Cc_g    + (size_t)RG*128;
    float* dtw_g   = dtw_s   + (size_t)RS*16;
    float* cbt_s   = dtw_g   + (size_t)RG*16;
    float* cbt_g   = cbt_s   + (size_t)BB*3840;
    float* part_q = uni;
    float* part_k = uni + (size_t)SP_ATT*RS*DM;
    float* part_v = uni + (size_t)2*SP_ATT*RS*DM;

    // tokenize
    tokenize_k<<<dim3(LS,BB), 512, 0, stream>>>(x_spectra, tok_w_s, tok_b_s, xs, 3647, 64, LS);
    tokenize_k<<<dim3(LG,BB), 512, 0, stream>>>(x_gaia,    tok_w_g, tok_b_g, xg, 18,   2,  LG);

    const int rblkS = (RS*DM + 1023)/1024;   // out-proj reduce blocks
    const int prepBlk = (RS*580 + 255)/256;  // 1034

    // mamba stacks
    for (int i=0;i<NLAY;i++){
        const float* Win_s  = ms_Win  + (size_t)i*DM*DPROJ;
        const float* Win_g  = mg_Win  + (size_t)i*DM*DPROJ;
        const float* cw_s   = ms_conv_w + (size_t)i*1280*4;
        const float* cw_g   = mg_conv_w + (size_t)i*1280*4;
        const float* cbv_s  = ms_conv_b + (size_t)i*1280;
        const float* cbv_g  = mg_conv_b + (size_t)i*1280;
        const float* dtb_s  = ms_dtb  + (size_t)i*NH;
        const float* dtb_g  = mg_dtb  + (size_t)i*NH;
        const float* al_s   = ms_Alog + (size_t)i*NH;
        const float* al_g   = mg_Alog + (size_t)i*NH;
        const float* Dw_s   = ms_D    + (size_t)i*NH;
        const float* Dw_g   = mg_D    + (size_t)i*NH;
        const float* nw_s   = ms_nw   + (size_t)i*DIN;
        const float* nw_g   = mg_nw   + (size_t)i*DIN;
        const float* Wout_s = ms_Wout + (size_t)i*DIN*DM;
        const float* Wout_g = mg_Wout + (size_t)i*DIN*DM;

        GemmJob inS{xs, Win_s, part_inS, RS};
        GemmJob inG{xg, Win_g, part_inG, RG};
        gemm_ps<128,8,false,SP_IN><<<dim3((DPROJ+127)/128, 8, 2*SP_IN), 256, 0, stream>>>(
            inS, inG, inG, DPROJ, DM);

        PrepJob pjS{part_inS, zsilu_s, xh_s, Bc_s, Cc_s, dtw_s, cw_s, cbv_s, dtb_s, RS, LS};
        PrepJob pjG{part_inG, zsilu_g, xh_g, Bc_g, Cc_g, dtw_g, cw_g, cbv_g, dtb_g, RG, LG};
        mamba_prep<<<dim3(prepBlk, 2), 256, 0, stream>>>(pjS, pjG);

        mamba_cbt<<<dim3(BB, 2), 256, 0, stream>>>(Bc_s, Cc_s, cbt_s, Bc_g, Cc_g, cbt_g);

        mamba_y<<<dim3(NH, BB, 2), 256, 0, stream>>>(
            cbt_s, xh_s, dtw_s, al_s, Dw_s, y_s,
            cbt_g, xh_g, dtw_g, al_g, Dw_g, y_g);

        gated_rmsnorm<<<dim3(RS+RG), 256, 0, stream>>>(
            y_s, zsilu_s, nw_s, yn_s,  y_g, zsilu_g, nw_g, yn_g);

        GemmJob outS{yn_s, Wout_s, part_outS, RS};
        GemmJob outG{yn_g, Wout_g, part_outG, RG};
        gemm_ps<64,4,false,SP_OUT><<<dim3(DM/64, 8, 2*SP_OUT), 256, 0, stream>>>(
            outS, outG, outG, DM, DIN);

        RJob roS{part_outS, nullptr, nullptr, xs, RS};
        RJob roG{part_outG, nullptr, nullptr, xg, RG};
        reduce_k<SP_OUT><<<dim3(rblkS, 2), 256, 0, stream>>>(roS, roG, DM);
    }

    // cross-attention: xs = xs + MHA(LN(xs), xg)
    {
        ln_rows<<<dim3(RS), 256, 0, stream>>>(xs, cas_ln_w, cas_ln_b, lnbuf, DM);
        GemmJob jq{lnbuf, cas_in_w,            part_q, RS};
        GemmJob jk{xg,    cas_in_w +  512*512, part_k, RG};
        GemmJob jv{xg,    cas_in_w + 1024*512, part_v, RG};
        gemm_ps<64,4,true,SP_ATT><<<dim3(DM/64, 8, 3*SP_ATT), 256, 0, stream>>>(jq, jk, jv, DM, DM);
        mha_attn<LS,LG,SP_ATT><<<dim3(8,BB), 64, 0, stream>>>(
            part_q, part_k, part_v, cas_in_b, cas_in_b+512, cas_in_b+1024, attn_out, RS, RG);
        GemmJob jo{attn_out, cas_out_w, part_outS, RS};
        gemm_ps<64,4,true,SP_ATT><<<dim3(DM/64, 8, SP_ATT), 256, 0, stream>>>(jo, jo, jo, DM, DM);
        RJob ro{part_outS, cas_out_b, xs, xs, RS};
        reduce_k<SP_ATT><<<dim3(rblkS, 1), 256, 0, stream>>>(ro, ro, DM);
    }

    // cross-attention: xg = xg + MHA(LN(xg), xs_updated)
    {
        ln_rows<<<dim3(RG), 256, 0, stream>>>(xg, cag_ln_w, cag_ln_b, lnbuf, DM);
        GemmJob jq{lnbuf, cag_in_w,            part_q, RG};
        GemmJob jk{xs,    cag_in_w +  512*512, part_k, RS};
        GemmJob jv{xs,    cag_in_w + 1024*512, part_v, RS};
        gemm_ps<64,4,true,SP_ATT><<<dim3(DM/64, 8, 3*SP_ATT), 256, 0, stream>>>(jq, jk, jv, DM, DM);
        mha_attn<LG,LS,SP_ATT><<<dim3(8,BB), 64, 0, stream>>>(
            part_q, part_k, part_v, cag_in_b, cag_in_b+512, cag_in_b+1024, attn_out, RG, RS);
        GemmJob jo{attn_out, cag_out_w, part_outS, RG};
        gemm_ps<64,4,true,SP_ATT><<<dim3(DM/64, 2, SP_ATT), 256, 0, stream>>>(jo, jo, jo, DM, DM);
        RJob ro{part_outS, cag_out_b, xg, xg, RG};
        reduce_k<SP_ATT><<<dim3((RG*DM+1023)/1024, 1), 256, 0, stream>>>(ro, ro, DM);
    }

    // head
    meanpool<<<dim3(BB), 512, 0, stream>>>(xs, xg, fused);
    ln_rows<<<dim3(BB), 256, 0, stream>>>(fused, cls_ln_w, cls_ln_b, lnf, 1024);
    cls_head<<<dim3(BB), 64, 0, stream>>>(lnf, cls_w, cls_b, (float*)d_out);
}

// Round 7
// 1074.290 us; speedup vs baseline: 1.3237x; 1.0483x over previous
//
#include <hip/hip_runtime.h>
#include <cmath>

// ---------------- constants ----------------
constexpr int BB    = 8;     // batch
constexpr int LS    = 57;    // spectra tokens
constexpr int LG    = 9;     // gaia tokens
constexpr int RS    = BB*LS; // 456
constexpr int RG    = BB*LG; // 72
constexpr int DM    = 512;   // d_model
constexpr int DPROJ = 2320;
constexpr int DIN   = 1024;
constexpr int NH    = 16;    // mamba heads
constexpr int HD    = 64;    // mamba headdim
constexpr int NLAY  = 10;

constexpr int SP_IN  = 4;    // split-K for in-proj  (K=512  -> 128/split)
constexpr int SP_OUT = 8;    // split-K for out-proj (K=1024 -> 128/split)
constexpr int SP_ATT = 4;    // split-K for attention gemms (K=512 -> 128/split)

__device__ __forceinline__ float siluf(float x){ return x / (1.f + expf(-x)); }

// ---------------- tokenize ----------------
__global__ __launch_bounds__(512) void tokenize_k(
    const float* __restrict__ x, const float* __restrict__ w, const float* __restrict__ bias,
    float* __restrict__ out, int in_dim, int tok_dim, int ntok)
{
    int t = blockIdx.x, b = blockIdx.y, d = threadIdx.x;
    __shared__ float xv[64];
    if (d < tok_dim) {
        int idx = t*tok_dim + d;
        xv[d] = (idx < in_dim) ? x[(size_t)b*in_dim + idx] : 0.f;
    }
    __syncthreads();
    float acc = bias[d];
    for (int k=0;k<tok_dim;k++) acc += xv[k]*w[(size_t)k*DM + d];
    out[(size_t)(b*ntok + t)*DM + d] = acc;
}

// ---------------- split-K f32 GEMM -> partials ----------------
struct GemmJob {
    const float* A; const float* B; float* part; int M;
};

template<int BN, int TN, bool TB, int NSPLIT>
__global__ __launch_bounds__(256) void gemm_ps(GemmJob j0, GemmJob j1, GemmJob j2, int N, int K)
{
    const int z = blockIdx.z;
    const int job = z / NSPLIT, split = z % NSPLIT;
    GemmJob jb = (job==0) ? j0 : (job==1 ? j1 : j2);
    const int bm = blockIdx.y*64, bn = blockIdx.x*BN;
    const int M = jb.M;
    if (bm >= M) return;
    __shared__ float As[2][16][68];
    __shared__ float Bs[2][16][BN+4];
    const int tid = threadIdx.x, tx = tid & 15, ty = tid >> 4;
    const float* __restrict__ A  = jb.A;
    const float* __restrict__ Bm = jb.B;
    float acc[4][TN] = {};

    const int arow = tid>>2, akb = (tid&3)*4;
    float4 ra, rb0, rb1;

    auto zero4 = [](){ float4 zz; zz.x=0.f; zz.y=0.f; zz.z=0.f; zz.w=0.f; return zz; };

    auto loadT = [&](int k0){
        ra = (bm+arow < M) ? *(const float4*)(A + (size_t)(bm+arow)*K + k0 + akb) : zero4();
        if constexpr (!TB) {
            const int kr = tid>>4, c4 = (tid&15)*4;
            rb0 = (bn+c4 < N) ? *(const float4*)(Bm + (size_t)(k0+kr)*N + bn + c4) : zero4();
            if constexpr (TN==8)
                rb1 = (bn+64+c4 < N) ? *(const float4*)(Bm + (size_t)(k0+kr)*N + bn + 64 + c4) : zero4();
        } else {
            const int nr = tid>>2, kb = (tid&3)*4;
            rb0 = (bn+nr < N) ? *(const float4*)(Bm + (size_t)(bn+nr)*K + k0 + kb) : zero4();
        }
    };
    auto storeT = [&](int buf){
        As[buf][akb+0][arow] = ra.x;
        As[buf][akb+1][arow] = ra.y;
        As[buf][akb+2][arow] = ra.z;
        As[buf][akb+3][arow] = ra.w;
        if constexpr (!TB) {
            const int kr = tid>>4, c4 = (tid&15)*4;
            *(float4*)&Bs[buf][kr][c4] = rb0;
            if constexpr (TN==8) *(float4*)&Bs[buf][kr][64+c4] = rb1;
        } else {
            const int nr = tid>>2, kb = (tid&3)*4;
            Bs[buf][kb+0][nr] = rb0.x;
            Bs[buf][kb+1][nr] = rb0.y;
            Bs[buf][kb+2][nr] = rb0.z;
            Bs[buf][kb+3][nr] = rb0.w;
        }
    };

    const int Kper = K/NSPLIT;
    const int koff = split*Kper;
    const int nk = Kper/16;
    loadT(koff);
    storeT(0);
    __syncthreads();
    for (int t=0; t<nk; ++t){
        const int cur = t & 1;
        if (t+1 < nk) loadT(koff + (t+1)*16);
        #pragma unroll
        for (int kk=0; kk<16; ++kk){
            float4 av = *(const float4*)&As[cur][kk][ty*4];
            float a[4] = {av.x, av.y, av.z, av.w};
            float b[TN];
            #pragma unroll
            for (int g=0; g<TN/4; ++g){
                float4 bv = *(const float4*)&Bs[cur][kk][tx*TN + g*4];
                b[g*4+0]=bv.x; b[g*4+1]=bv.y; b[g*4+2]=bv.z; b[g*4+3]=bv.w;
            }
            #pragma unroll
            for (int i=0;i<4;i++)
                #pragma unroll
                for (int j=0;j<TN;j++) acc[i][j] = fmaf(a[i], b[j], acc[i][j]);
        }
        if (t+1 < nk) storeT(cur^1);
        __syncthreads();
    }

    float* __restrict__ P = jb.part + (size_t)split*M*N;
    #pragma unroll
    for (int i=0;i<4;i++){
        int m = bm + ty*4 + i;
        if (m < M){
            #pragma unroll
            for (int j=0;j<TN;j++){
                int n = bn + tx*TN + j;
                if (n < N) P[(size_t)m*N + n] = acc[i][j];
            }
        }
    }
}

// ---------------- reduce partials (+bias, +res) ----------------
struct RJob { const float* part; const float* bias; const float* res; float* C; int M; };

template<int NS>
__global__ __launch_bounds__(256) void reduce_k(RJob j0, RJob j1, int N)
{
    RJob j = blockIdx.y ? j1 : j0;
    const size_t total = (size_t)j.M*N;
    const size_t i4 = ((size_t)blockIdx.x*256 + threadIdx.x)*4;
    if (i4 >= total) return;
    float4 s = *(const float4*)(j.part + i4);
    #pragma unroll
    for (int t=1;t<NS;t++){
        const float4 v = *(const float4*)(j.part + (size_t)t*total + i4);
        s.x+=v.x; s.y+=v.y; s.z+=v.z; s.w+=v.w;
    }
    const int n = (int)(i4 % (size_t)N);
    if (j.bias){ s.x+=j.bias[n]; s.y+=j.bias[n+1]; s.z+=j.bias[n+2]; s.w+=j.bias[n+3]; }
    if (j.res){ const float4 r = *(const float4*)(j.res + i4); s.x+=r.x; s.y+=r.y; s.z+=r.z; s.w+=r.w; }
    *(float4*)(j.C + i4) = s;
}

template<int NS>
__global__ __launch_bounds__(256) void reduce_k3(RJob j0, RJob j1, RJob j2, int N)
{
    RJob j = (blockIdx.y==0) ? j0 : (blockIdx.y==1 ? j1 : j2);
    const size_t total = (size_t)j.M*N;
    const size_t i4 = ((size_t)blockIdx.x*256 + threadIdx.x)*4;
    if (i4 >= total) return;
    float4 s = *(const float4*)(j.part + i4);
    #pragma unroll
    for (int t=1;t<NS;t++){
        const float4 v = *(const float4*)(j.part + (size_t)t*total + i4);
        s.x+=v.x; s.y+=v.y; s.z+=v.z; s.w+=v.w;
    }
    const int n = (int)(i4 % (size_t)N);
    if (j.bias){ s.x+=j.bias[n]; s.y+=j.bias[n+1]; s.z+=j.bias[n+2]; s.w+=j.bias[n+3]; }
    if (j.res){ const float4 r = *(const float4*)(j.res + i4); s.x+=r.x; s.y+=r.y; s.z+=r.z; s.w+=r.w; }
    *(float4*)(j.C + i4) = s;
}

// ---------------- mamba prep: reduce partials + conv + silu + softplus ----------------
struct PrepJob {
    const float* part;     // [SP_IN][R][DPROJ]
    float* zsilu; float* xh; float* Bc; float* Cc; float* dtw;
    const float* cw; const float* cb; const float* dtb;
    int R, L;
};

__device__ __forceinline__ float4 psum4(const float* p, size_t pstr){
    float4 a = *(const float4*)p;
    const float4 b = *(const float4*)(p + pstr);
    const float4 c = *(const float4*)(p + 2*pstr);
    const float4 d = *(const float4*)(p + 3*pstr);
    a.x += b.x + c.x + d.x;
    a.y += b.y + c.y + d.y;
    a.z += b.z + c.z + d.z;
    a.w += b.w + c.w + d.w;
    return a;
}

__global__ __launch_bounds__(256) void mamba_prep(PrepJob js, PrepJob jg)
{
    PrepJob j = blockIdx.y ? jg : js;
    const int R = j.R, L = j.L;
    constexpr int QPR = 580;   // 256 (z) + 320 (conv) + 4 (dt) quads per row
    const int q = blockIdx.x*256 + threadIdx.x;
    if (q >= R*QPR) return;
    const int r = q / QPR, qi = q % QPR;
    const int l = r % L;
    const size_t pstr = (size_t)R*DPROJ;
    const float* base = j.part + (size_t)r*DPROJ;

    if (qi < 256) {                 // ---- z region -> silu(z)
        const int c = qi*4;
        float4 s = psum4(base + c, pstr);
        s.x = siluf(s.x); s.y = siluf(s.y); s.z = siluf(s.z); s.w = siluf(s.w);
        *(float4*)(j.zsilu + (size_t)r*1024 + c) = s;
    } else if (qi < 576) {          // ---- conv region
        const int cc = (qi-256)*4;  // 0..1276
        float tk[4][4];
        #pragma unroll
        for (int k=0;k<4;k++){
            const int lr = l - 3 + k;
            if (lr >= 0){
                float4 v = psum4(j.part + (size_t)(r-3+k)*DPROJ + 1024 + cc, pstr);
                tk[k][0]=v.x; tk[k][1]=v.y; tk[k][2]=v.z; tk[k][3]=v.w;
            } else {
                tk[k][0]=0.f; tk[k][1]=0.f; tk[k][2]=0.f; tk[k][3]=0.f;
            }
        }
        const float4 cb4 = *(const float4*)(j.cb + cc);
        const float cba[4] = {cb4.x, cb4.y, cb4.z, cb4.w};
        float out[4];
        #pragma unroll
        for (int jj=0;jj<4;jj++){
            const float4 wv = *(const float4*)(j.cw + (size_t)(cc+jj)*4);
            float v = cba[jj] + wv.x*tk[0][jj] + wv.y*tk[1][jj]
                              + wv.z*tk[2][jj] + wv.w*tk[3][jj];
            out[jj] = siluf(v);
        }
        float4 o4; o4.x=out[0]; o4.y=out[1]; o4.z=out[2]; o4.w=out[3];
        if (cc < 1024)       *(float4*)(j.xh + (size_t)r*1024 + cc)        = o4;
        else if (cc < 1152)  *(float4*)(j.Bc + (size_t)r*128 + (cc-1024))  = o4;
        else                 *(float4*)(j.Cc + (size_t)r*128 + (cc-1152))  = o4;
    } else {                        // ---- dt region
        const int hd = (qi-576)*4;  // 0,4,8,12
        float4 s = psum4(base + 2304 + hd, pstr);
        const float4 b4 = *(const float4*)(j.dtb + hd);
        float raw[4] = {s.x+b4.x, s.y+b4.y, s.z+b4.z, s.w+b4.w};
        float4 o4;
        float* op = &o4.x;
        #pragma unroll
        for (int jj=0;jj<4;jj++)
            op[jj] = (raw[jj] > 20.f) ? raw[jj] : log1pf(expf(raw[jj]));
        *(float4*)(j.dtw + (size_t)r*16 + hd) = o4;
    }
}

// ---------------- CBT = C @ B^T per (batch, stack) — head-independent ----------------
__global__ __launch_bounds__(256) void mamba_cbt(
    const float* __restrict__ Bc_s, const float* __restrict__ Cc_s, float* __restrict__ cbt_s,
    const float* __restrict__ Bc_g, const float* __restrict__ Cc_g, float* __restrict__ cbt_g)
{
    const int b = blockIdx.x, st = blockIdx.y;
    const float* Bc = st ? Bc_g : Bc_s;
    const float* Cc = st ? Cc_g : Cc_s;
    float* cbt = st ? cbt_g : cbt_s;
    const int L = st ? LG : LS;
    constexpr int SB = 132;
    __shared__ float Bm[64*SB], Cm[64*SB];
    const int t = threadIdx.x;
    for (int idx = t; idx < L*32; idx += 256){
        const int l = idx >> 5, c4 = (idx & 31)*4;
        *(float4*)&Bm[l*SB + c4] = *(const float4*)(Bc + (size_t)(b*L+l)*128 + c4);
        *(float4*)&Cm[l*SB + c4] = *(const float4*)(Cc + (size_t)(b*L+l)*128 + c4);
    }
    __syncthreads();
    const int ti = t >> 4, tj = t & 15;
    float acc[4][4] = {};
    for (int k0=0;k0<128;k0+=4){
        float4 cr[4], br[4];
        #pragma unroll
        for (int a=0;a<4;a++) cr[a] = *(const float4*)&Cm[(ti+16*a)*SB + k0];
        #pragma unroll
        for (int qq=0;qq<4;qq++) br[qq] = *(const float4*)&Bm[(tj+16*qq)*SB + k0];
        #pragma unroll
        for (int a=0;a<4;a++)
            #pragma unroll
            for (int qq=0;qq<4;qq++)
                acc[a][qq] += cr[a].x*br[qq].x + cr[a].y*br[qq].y
                            + cr[a].z*br[qq].z + cr[a].w*br[qq].w;
    }
    #pragma unroll
    for (int a=0;a<4;a++){
        const int i = ti + 16*a;
        if (i < L){
            #pragma unroll
            for (int qq=0;qq<4;qq++){
                const int jj = tj + 16*qq;
                if (jj < L) cbt[(size_t)b*3840 + i*60 + jj] = acc[a][qq];
            }
        }
    }
}

// ---------------- Y = (decay .* CBT) @ X + D*X per (head, batch, stack) ----------------
__global__ __launch_bounds__(256) void mamba_y(
    const float* __restrict__ cbt_s, const float* __restrict__ xh_s, const float* __restrict__ dtw_s,
    const float* __restrict__ al_s, const float* __restrict__ Dw_s, float* __restrict__ y_s,
    const float* __restrict__ cbt_g, const float* __restrict__ xh_g, const float* __restrict__ dtw_g,
    const float* __restrict__ al_g, const float* __restrict__ Dw_g, float* __restrict__ y_g)
{
    const int h = blockIdx.x, b = blockIdx.y, st = blockIdx.z;
    const float* cbt = st ? cbt_g : cbt_s;
    const float* xh  = st ? xh_g  : xh_s;
    const float* dtw = st ? dtw_g : dtw_s;
    const float* al  = st ? al_g  : al_s;
    const float* Dw  = st ? Dw_g  : Dw_s;
    float* y = st ? y_g : y_s;
    const int L = st ? LG : LS;

    const int t = threadIdx.x;
    constexpr int SG = 60, SX = 68;
    __shared__ float Gm[64*SG], Xm[64*SX];
    __shared__ float dts[64], sps[64];

    const float Ah = -expf(al[h]);
    const float Dh = Dw[h];

    // dt + prefix scan (wave 0)
    if (t < 64){
        float dtv = (t < L) ? dtw[(size_t)(b*L+t)*16 + h] : 0.f;
        float s = dtv;
        #pragma unroll
        for (int d=1; d<64; d<<=1){
            float o = __shfl_up(s, d, 64);
            if (t >= d) s += o;
        }
        dts[t] = dtv; sps[t] = s;
    }
    // load X tile
    for (int idx = t; idx < L*16; idx += 256){
        const int l = idx >> 4, c4 = (idx & 15)*4;
        *(float4*)&Xm[l*SX + c4] = *(const float4*)(xh + (size_t)(b*L+l)*1024 + h*64 + c4);
    }
    __syncthreads();

    // G = decay .* CBT
    for (int idx = t; idx < L*15; idx += 256){
        const int i = idx/15, j4 = (idx%15)*4;
        const float4 v = *(const float4*)(cbt + (size_t)b*3840 + i*60 + j4);
        const float va[4] = {v.x, v.y, v.z, v.w};
        float g[4];
        const float si = sps[i];
        #pragma unroll
        for (int jj=0;jj<4;jj++){
            const int jc = j4 + jj;
            float gg = 0.f;
            if (jc <= i && jc < L)
                gg = expf(Ah*(si - sps[jc])) * dts[jc] * va[jj];
            g[jj] = gg;
        }
        float4 g4; g4.x=g[0]; g4.y=g[1]; g4.z=g[2]; g4.w=g[3];
        *(float4*)&Gm[i*SG + j4] = g4;
    }
    __syncthreads();

    // Y = G @ X + D*X
    const int ti = t >> 4, tj = t & 15;
    int la[4];
    #pragma unroll
    for (int a=0;a<4;a++) la[a] = ti + 16*a;
    float accY[4][4] = {};
    for (int m=0; m<L; ++m){
        float xr[4], gr[4];
        #pragma unroll
        for (int qq=0;qq<4;qq++) xr[qq] = Xm[m*SX + tj + 16*qq];
        #pragma unroll
        for (int a=0;a<4;a++) gr[a] = (la[a] < L) ? Gm[la[a]*SG + m] : 0.f;
        #pragma unroll
        for (int a=0;a<4;a++)
            #pragma unroll
            for (int qq=0;qq<4;qq++) accY[a][qq] = fmaf(gr[a], xr[qq], accY[a][qq]);
    }
    #pragma unroll
    for (int a=0;a<4;a++){
        if (la[a] < L){
            float* yrow = y + (size_t)(b*L + la[a])*DIN + h*HD;
            #pragma unroll
            for (int qq=0;qq<4;qq++){
                const int col = tj + 16*qq;
                yrow[col] = accY[a][qq] + Dh * Xm[la[a]*SX + col];
            }
        }
    }
}

// ---------------- gated RMSNorm (z pre-silu'd by prep) ----------------
__global__ __launch_bounds__(256) void gated_rmsnorm(
    const float* __restrict__ y_s, const float* __restrict__ zs_s, const float* __restrict__ nw_s, float* __restrict__ o_s,
    const float* __restrict__ y_g, const float* __restrict__ zs_g, const float* __restrict__ nw_g, float* __restrict__ o_g)
{
    int r = blockIdx.x, t = threadIdx.x;
    int st = (r >= RS);
    int row = st ? r - RS : r;
    const float* y  = (st ? y_g  : y_s) + (size_t)row*DIN;
    const float* zs = (st ? zs_g : zs_s) + (size_t)row*DIN;
    const float* nw = st ? nw_g : nw_s;
    float* o = (st ? o_g : o_s) + (size_t)row*DIN;

    float g[4]; float s2 = 0.f;
    #pragma unroll
    for (int i=0;i<4;i++){
        int idx = t + i*256;
        float gv = y[idx] * zs[idx];
        g[i] = gv; s2 += gv*gv;
    }
    #pragma unroll
    for (int o2=32;o2;o2>>=1) s2 += __shfl_xor(s2, o2, 64);
    __shared__ float red[4];
    if ((t & 63) == 0) red[t>>6] = s2;
    __syncthreads();
    float S2 = red[0]+red[1]+red[2]+red[3];
    float scale = rsqrtf(S2*(1.f/DIN) + 1e-5f);
    #pragma unroll
    for (int i=0;i<4;i++){
        int idx = t + i*256;
        o[idx] = g[i]*scale*nw[idx];
    }
}

// ---------------- LayerNorm rows ----------------
__global__ __launch_bounds__(256) void ln_rows(
    const float* __restrict__ x, const float* __restrict__ w, const float* __restrict__ b,
    float* __restrict__ out, int D)
{
    int r = blockIdx.x, t = threadIdx.x;
    const float* xr = x + (size_t)r*D;
    float s = 0.f, s2 = 0.f;
    for (int i=t;i<D;i+=256){ float v = xr[i]; s += v; s2 += v*v; }
    #pragma unroll
    for (int o=32;o;o>>=1){ s += __shfl_xor(s,o,64); s2 += __shfl_xor(s2,o,64); }
    __shared__ float red[8];
    if ((t & 63) == 0){ red[t>>6] = s; red[4+(t>>6)] = s2; }
    __syncthreads();
    float S  = red[0]+red[1]+red[2]+red[3];
    float S2 = red[4]+red[5]+red[6]+red[7];
    float mean = S/D;
    float var  = S2/D - mean*mean;
    float inv  = rsqrtf(var + 1e-5f);
    for (int i=t;i<D;i+=256)
        out[(size_t)r*D + i] = (xr[i]-mean)*inv*w[i] + b[i];
}

// ---------------- cross-attention core v2: dense Q/K/V, 256 threads ----------------
template<int LQ, int LKV>
__global__ __launch_bounds__(256) void mha_attn2(
    const float* __restrict__ qh, const float* __restrict__ kh,
    const float* __restrict__ vh, float* __restrict__ out)
{
    const int hh = blockIdx.x, b = blockIdx.y, t = threadIdx.x;
    constexpr int SD = 68;            // 64-dim row stride (pad)
    constexpr int SS = 60;            // score row stride
    constexpr int QT = (LQ +15)/16;
    constexpr int KT = (LKV+15)/16;
    __shared__ float Qs[LQ*SD];
    __shared__ float Ks[LKV*SD];
    __shared__ float Vs[LKV*SD];
    __shared__ float Ps[LQ*SS];

    for (int idx = t; idx < LQ*16; idx += 256){
        const int r = idx>>4, c4 = (idx&15)*4;
        *(float4*)&Qs[r*SD+c4] = *(const float4*)(qh + (size_t)(b*LQ+r)*DM + hh*64 + c4);
    }
    for (int idx = t; idx < LKV*16; idx += 256){
        const int r = idx>>4, c4 = (idx&15)*4;
        *(float4*)&Ks[r*SD+c4] = *(const float4*)(kh + (size_t)(b*LKV+r)*DM + hh*64 + c4);
        *(float4*)&Vs[r*SD+c4] = *(const float4*)(vh + (size_t)(b*LKV+r)*DM + hh*64 + c4);
    }
    __syncthreads();

    const int ti = t>>4, tj = t&15;

    // scores S = 0.125 * Q @ K^T
    {
        float acc[QT][KT];
        #pragma unroll
        for (int a=0;a<QT;a++)
            #pragma unroll
            for (int q=0;q<KT;q++) acc[a][q] = 0.f;
        for (int k0=0;k0<64;k0+=4){
            float4 qr[QT], kr[KT];
            #pragma unroll
            for (int a=0;a<QT;a++){
                int rr = ti+16*a; if (rr >= LQ) rr = LQ-1;
                qr[a] = *(const float4*)&Qs[rr*SD+k0];
            }
            #pragma unroll
            for (int q=0;q<KT;q++){
                int rr = tj+16*q; if (rr >= LKV) rr = LKV-1;
                kr[q] = *(const float4*)&Ks[rr*SD+k0];
            }
            #pragma unroll
            for (int a=0;a<QT;a++)
                #pragma unroll
                for (int q=0;q<KT;q++)
                    acc[a][q] += qr[a].x*kr[q].x + qr[a].y*kr[q].y
                               + qr[a].z*kr[q].z + qr[a].w*kr[q].w;
        }
        #pragma unroll
        for (int a=0;a<QT;a++){
            const int i = ti+16*a;
            if (i < LQ){
                #pragma unroll
                for (int q=0;q<KT;q++){
                    const int jj = tj+16*q;
                    if (jj < LKV) Ps[i*SS+jj] = acc[a][q]*0.125f;
                }
            }
        }
    }
    __syncthreads();

    // row softmax (thread t handles row t)
    if (t < LQ){
        float mx = -1e30f;
        for (int j=0;j<LKV;j++) mx = fmaxf(mx, Ps[t*SS+j]);
        float se = 0.f;
        for (int j=0;j<LKV;j++){ float e = expf(Ps[t*SS+j]-mx); Ps[t*SS+j] = e; se += e; }
        const float inv = 1.f/se;
        for (int j=0;j<LKV;j++) Ps[t*SS+j] *= inv;
    }
    __syncthreads();

    // O = P @ V : thread (ti: query group, tj: 4-dim group)
    {
        float o[QT][4];
        #pragma unroll
        for (int a=0;a<QT;a++){ o[a][0]=0.f; o[a][1]=0.f; o[a][2]=0.f; o[a][3]=0.f; }
        for (int m=0;m<LKV;m++){
            const float4 vv = *(const float4*)&Vs[m*SD + tj*4];
            #pragma unroll
            for (int a=0;a<QT;a++){
                const int rr = ti+16*a;
                const float pv = (rr < LQ) ? Ps[rr*SS+m] : 0.f;
                o[a][0] = fmaf(pv, vv.x, o[a][0]);
                o[a][1] = fmaf(pv, vv.y, o[a][1]);
                o[a][2] = fmaf(pv, vv.z, o[a][2]);
                o[a][3] = fmaf(pv, vv.w, o[a][3]);
            }
        }
        #pragma unroll
        for (int a=0;a<QT;a++){
            const int rr = ti+16*a;
            if (rr < LQ){
                float4 o4; o4.x=o[a][0]; o4.y=o[a][1]; o4.z=o[a][2]; o4.w=o[a][3];
                *(float4*)(out + (size_t)(b*LQ+rr)*DM + hh*64 + tj*4) = o4;
            }
        }
    }
}

// ---------------- fused head: meanpool + LN + classifier ----------------
__global__ __launch_bounds__(512) void head_fused(
    const float* __restrict__ xs, const float* __restrict__ xg,
    const float* __restrict__ lw, const float* __restrict__ lb,
    const float* __restrict__ cw, const float* __restrict__ cb,
    float* __restrict__ out)
{
    const int b = blockIdx.x, t = threadIdx.x;
    __shared__ float fr[1024];
    __shared__ float red[16];
    __shared__ float pr[55*8];
    {
        float s = 0.f;
        for (int l=0;l<LS;l++) s += xs[(size_t)(b*LS+l)*DM + t];
        fr[t] = s*(1.f/LS);
        float g = 0.f;
        for (int l=0;l<LG;l++) g += xg[(size_t)(b*LG+l)*DM + t];
        fr[512+t] = g*(1.f/LG);
    }
    __syncthreads();
    float v0 = fr[t], v1 = fr[512+t];
    float sm = v0+v1, sq = v0*v0 + v1*v1;
    #pragma unroll
    for (int o=32;o;o>>=1){ sm += __shfl_xor(sm,o,64); sq += __shfl_xor(sq,o,64); }
    if ((t&63)==0){ red[t>>6] = sm; red[8+(t>>6)] = sq; }
    __syncthreads();
    float S=0.f, Q=0.f;
    #pragma unroll
    for (int i=0;i<8;i++){ S += red[i]; Q += red[8+i]; }
    const float mean = S*(1.f/1024.f);
    const float var  = Q*(1.f/1024.f) - mean*mean;
    const float inv  = rsqrtf(var + 1e-5f);
    fr[t]     = (v0-mean)*inv*lw[t]     + lb[t];
    fr[512+t] = (v1-mean)*inv*lw[512+t] + lb[512+t];
    __syncthreads();
    {
        const int c = t & 63, pp = t >> 6;   // 8 parts of 128
        if (c < 55){
            float a = 0.f;
            const float* wr = cw + (size_t)c*1024 + pp*128;
            const float* xr = fr + pp*128;
            #pragma unroll 4
            for (int k=0;k<128;k++) a = fmaf(xr[k], wr[k], a);
            pr[c*8+pp] = a;
        }
    }
    __syncthreads();
    if (t < 55){
        float a = cb[t];
        #pragma unroll
        for (int p2=0;p2<8;p2++) a += pr[t*8+p2];
        out[b*55 + t] = a;
    }
}

// ---------------- launch ----------------
extern "C" void kernel_launch(void* const* d_in, const int* in_sizes, int n_in,
                              void* d_out, int out_size, void* d_ws, size_t ws_size,
                              hipStream_t stream)
{
    (void)in_sizes; (void)n_in; (void)out_size; (void)ws_size;
    const float* x_spectra = (const float*)d_in[0];
    const float* x_gaia    = (const float*)d_in[1];
    const float* tok_w_s   = (const float*)d_in[2];
    const float* tok_b_s   = (const float*)d_in[3];
    const float* tok_w_g   = (const float*)d_in[4];
    const float* tok_b_g   = (const float*)d_in[5];
    const float* ms_Win    = (const float*)d_in[6];
    const float* ms_conv_w = (const float*)d_in[7];
    const float* ms_conv_b = (const float*)d_in[8];
    const float* ms_dtb    = (const float*)d_in[9];
    const float* ms_Alog   = (const float*)d_in[10];
    const float* ms_D      = (const float*)d_in[11];
    const float* ms_nw     = (const float*)d_in[12];
    const float* ms_Wout   = (const float*)d_in[13];
    const float* mg_Win    = (const float*)d_in[14];
    const float* mg_conv_w = (const float*)d_in[15];
    const float* mg_conv_b = (const float*)d_in[16];
    const float* mg_dtb    = (const float*)d_in[17];
    const float* mg_Alog   = (const float*)d_in[18];
    const float* mg_D      = (const float*)d_in[19];
    const float* mg_nw     = (const float*)d_in[20];
    const float* mg_Wout   = (const float*)d_in[21];
    const float* cas_ln_w  = (const float*)d_in[22];
    const float* cas_ln_b  = (const float*)d_in[23];
    const float* cas_in_w  = (const float*)d_in[24];
    const float* cas_in_b  = (const float*)d_in[25];
    const float* cas_out_w = (const float*)d_in[26];
    const float* cas_out_b = (const float*)d_in[27];
    const float* cag_ln_w  = (const float*)d_in[28];
    const float* cag_ln_b  = (const float*)d_in[29];
    const float* cag_in_w  = (const float*)d_in[30];
    const float* cag_in_b  = (const float*)d_in[31];
    const float* cag_out_w = (const float*)d_in[32];
    const float* cag_out_b = (const float*)d_in[33];
    const float* cls_ln_w  = (const float*)d_in[34];
    const float* cls_ln_b  = (const float*)d_in[35];
    const float* cls_w     = (const float*)d_in[36];
    const float* cls_b     = (const float*)d_in[37];

    float* p = (float*)d_ws;
    auto alloc = [&](size_t n){ float* r = p; p += n; return r; };
    float* xs       = alloc((size_t)RS*DM);
    float* xg       = alloc((size_t)RG*DM);
    float* y_s      = alloc((size_t)RS*DIN);
    float* y_g      = alloc((size_t)RG*DIN);
    float* yn_s     = alloc((size_t)RS*DIN);
    float* yn_g     = alloc((size_t)RG*DIN);
    float* lnbuf    = alloc((size_t)RS*DM);
    float* attn_out = alloc((size_t)RS*DM);
    float* part_inS  = alloc((size_t)SP_IN*RS*DPROJ);
    float* part_inG  = alloc((size_t)SP_IN*RG*DPROJ);
    float* part_outS = alloc((size_t)SP_OUT*RS*DM);
    float* part_outG = alloc((size_t)SP_OUT*RG*DM);
    // union region: mamba mixer buffers during layers; attn partials afterwards
    float* uni       = alloc((size_t)3*SP_ATT*RS*DM);
    float* zsilu_s = uni;
    float* zsilu_g = zsilu_s + (size_t)RS*1024;
    float* xh_s    = zsilu_g + (size_t)RG*1024;
    float* xh_g    = xh_s    + (size_t)RS*1024;
    float* Bc_s    = xh_g    + (size_t)RG*1024;
    float* Bc_g    = Bc_s    + (size_t)RS*128;
    float* Cc_s    = Bc_g    + (size_t)RG*128;
    float* Cc_g    = Cc_s    + (size_t)RS*128;
    float* dtw_s   = Cc_g    + (size_t)RG*128;
    float* dtw_g   = dtw_s   + (size_t)RS*16;
    float* cbt_s   = dtw_g   + (size_t)RG*16;
    float* cbt_g   = cbt_s   + (size_t)BB*3840;
    float* part_q = uni;
    float* part_k = uni + (size_t)SP_ATT*RS*DM;
    float* part_v = uni + (size_t)2*SP_ATT*RS*DM;
    // dense q/k/v aliased onto dead mixer buffers (RS*DIN == 2*RS*DM exactly)
    float* qh = y_s;
    float* vh = y_s + (size_t)RS*DM;
    float* kh = yn_s;

    // tokenize
    tokenize_k<<<dim3(LS,BB), 512, 0, stream>>>(x_spectra, tok_w_s, tok_b_s, xs, 3647, 64, LS);
    tokenize_k<<<dim3(LG,BB), 512, 0, stream>>>(x_gaia,    tok_w_g, tok_b_g, xg, 18,   2,  LG);

    const int rblkS = (RS*DM + 1023)/1024;   // 228
    const int prepBlk = (RS*580 + 255)/256;  // 1034

    // mamba stacks
    for (int i=0;i<NLAY;i++){
        const float* Win_s  = ms_Win  + (size_t)i*DM*DPROJ;
        const float* Win_g  = mg_Win  + (size_t)i*DM*DPROJ;
        const float* cw_s   = ms_conv_w + (size_t)i*1280*4;
        const float* cw_g   = mg_conv_w + (size_t)i*1280*4;
        const float* cbv_s  = ms_conv_b + (size_t)i*1280;
        const float* cbv_g  = mg_conv_b + (size_t)i*1280;
        const float* dtb_s  = ms_dtb  + (size_t)i*NH;
        const float* dtb_g  = mg_dtb  + (size_t)i*NH;
        const float* al_s   = ms_Alog + (size_t)i*NH;
        const float* al_g   = mg_Alog + (size_t)i*NH;
        const float* Dw_s   = ms_D    + (size_t)i*NH;
        const float* Dw_g   = mg_D    + (size_t)i*NH;
        const float* nw_s   = ms_nw   + (size_t)i*DIN;
        const float* nw_g   = mg_nw   + (size_t)i*DIN;
        const float* Wout_s = ms_Wout + (size_t)i*DIN*DM;
        const float* Wout_g = mg_Wout + (size_t)i*DIN*DM;

        GemmJob inS{xs, Win_s, part_inS, RS};
        GemmJob inG{xg, Win_g, part_inG, RG};
        gemm_ps<128,8,false,SP_IN><<<dim3((DPROJ+127)/128, 8, 2*SP_IN), 256, 0, stream>>>(
            inS, inG, inG, DPROJ, DM);

        PrepJob pjS{part_inS, zsilu_s, xh_s, Bc_s, Cc_s, dtw_s, cw_s, cbv_s, dtb_s, RS, LS};
        PrepJob pjG{part_inG, zsilu_g, xh_g, Bc_g, Cc_g, dtw_g, cw_g, cbv_g, dtb_g, RG, LG};
        mamba_prep<<<dim3(prepBlk, 2), 256, 0, stream>>>(pjS, pjG);

        mamba_cbt<<<dim3(BB, 2), 256, 0, stream>>>(Bc_s, Cc_s, cbt_s, Bc_g, Cc_g, cbt_g);

        mamba_y<<<dim3(NH, BB, 2), 256, 0, stream>>>(
            cbt_s, xh_s, dtw_s, al_s, Dw_s, y_s,
            cbt_g, xh_g, dtw_g, al_g, Dw_g, y_g);

        gated_rmsnorm<<<dim3(RS+RG), 256, 0, stream>>>(
            y_s, zsilu_s, nw_s, yn_s,  y_g, zsilu_g, nw_g, yn_g);

        GemmJob outS{yn_s, Wout_s, part_outS, RS};
        GemmJob outG{yn_g, Wout_g, part_outG, RG};
        gemm_ps<64,4,false,SP_OUT><<<dim3(DM/64, 8, 2*SP_OUT), 256, 0, stream>>>(
            outS, outG, outG, DM, DIN);

        RJob roS{part_outS, nullptr, nullptr, xs, RS};
        RJob roG{part_outG, nullptr, nullptr, xg, RG};
        reduce_k<SP_OUT><<<dim3(rblkS, 2), 256, 0, stream>>>(roS, roG, DM);
    }

    // cross-attention: xs = xs + MHA(LN(xs), xg)
    {
        ln_rows<<<dim3(RS), 256, 0, stream>>>(xs, cas_ln_w, cas_ln_b, lnbuf, DM);
        GemmJob jq{lnbuf, cas_in_w,            part_q, RS};
        GemmJob jk{xg,    cas_in_w +  512*512, part_k, RG};
        GemmJob jv{xg,    cas_in_w + 1024*512, part_v, RG};
        gemm_ps<64,4,true,SP_ATT><<<dim3(DM/64, 8, 3*SP_ATT), 256, 0, stream>>>(jq, jk, jv, DM, DM);
        RJob rq{part_q, cas_in_b,      nullptr, qh, RS};
        RJob rk{part_k, cas_in_b+512,  nullptr, kh, RG};
        RJob rv{part_v, cas_in_b+1024, nullptr, vh, RG};
        reduce_k3<SP_ATT><<<dim3(rblkS, 3), 256, 0, stream>>>(rq, rk, rv, DM);
        mha_attn2<LS,LG><<<dim3(8,BB), 256, 0, stream>>>(qh, kh, vh, attn_out);
        GemmJob jo{attn_out, cas_out_w, part_outS, RS};
        gemm_ps<64,4,true,SP_ATT><<<dim3(DM/64, 8, SP_ATT), 256, 0, stream>>>(jo, jo, jo, DM, DM);
        RJob ro{part_outS, cas_out_b, xs, xs, RS};
        reduce_k<SP_ATT><<<dim3(rblkS, 1), 256, 0, stream>>>(ro, ro, DM);
    }

    // cross-attention: xg = xg + MHA(LN(xg), xs_updated)
    {
        ln_rows<<<dim3(RG), 256, 0, stream>>>(xg, cag_ln_w, cag_ln_b, lnbuf, DM);
        GemmJob jq{lnbuf, cag_in_w,            part_q, RG};
        GemmJob jk{xs,    cag_in_w +  512*512, part_k, RS};
        GemmJob jv{xs,    cag_in_w + 1024*512, part_v, RS};
        gemm_ps<64,4,true,SP_ATT><<<dim3(DM/64, 8, 3*SP_ATT), 256, 0, stream>>>(jq, jk, jv, DM, DM);
        RJob rq{part_q, cag_in_b,      nullptr, qh, RG};
        RJob rk{part_k, cag_in_b+512,  nullptr, kh, RS};
        RJob rv{part_v, cag_in_b+1024, nullptr, vh, RS};
        reduce_k3<SP_ATT><<<dim3(rblkS, 3), 256, 0, stream>>>(rq, rk, rv, DM);
        mha_attn2<LG,LS><<<dim3(8,BB), 256, 0, stream>>>(qh, kh, vh, attn_out);
        GemmJob jo{attn_out, cag_out_w, part_outS, RG};
        gemm_ps<64,4,true,SP_ATT><<<dim3(DM/64, 2, SP_ATT), 256, 0, stream>>>(jo, jo, jo, DM, DM);
        RJob ro{part_outS, cag_out_b, xg, xg, RG};
        reduce_k<SP_ATT><<<dim3((RG*DM+1023)/1024, 1), 256, 0, stream>>>(ro, ro, DM);
    }

    // fused head
    head_fused<<<dim3(BB), 512, 0, stream>>>(xs, xg, cls_ln_w, cls_ln_b, cls_w, cls_b, (float*)d_out);
}

// Round 8
// 839.001 us; speedup vs baseline: 1.6950x; 1.2804x over previous
//
#include <hip/hip_runtime.h>
#include <cmath>

// ---------------- constants ----------------
constexpr int BB    = 8;     // batch
constexpr int LS    = 57;    // spectra tokens
constexpr int LG    = 9;     // gaia tokens
constexpr int RS    = BB*LS; // 456
constexpr int RG    = BB*LG; // 72
constexpr int DM    = 512;   // d_model
constexpr int DPROJ = 2320;
constexpr int DIN   = 1024;
constexpr int NH    = 16;    // mamba heads
constexpr int HD    = 64;    // mamba headdim
constexpr int NLAY  = 10;

constexpr int SP_IN  = 4;    // split-K for in-proj  (K=512  -> 128/split)
constexpr int SP_OUT = 8;    // split-K for out-proj (K=1024 -> 128/split)
constexpr int SP_ATT = 4;    // split-K for attention gemms (K=512 -> 128/split)

__device__ __forceinline__ float siluf(float x){ return x / (1.f + expf(-x)); }

// ---------------- bf16 split helpers ----------------
typedef short  short8 __attribute__((ext_vector_type(8)));
typedef float  f32x4  __attribute__((ext_vector_type(4)));

__device__ __forceinline__ unsigned short f2bh(float f){
    unsigned int u = __float_as_uint(f);
    u = u + 0x7FFFu + ((u >> 16) & 1u);
    return (unsigned short)(u >> 16);
}
__device__ __forceinline__ float bh2f(unsigned short h){
    return __uint_as_float(((unsigned int)h) << 16);
}

// ---------------- tokenize ----------------
__global__ __launch_bounds__(512) void tokenize_k(
    const float* __restrict__ x, const float* __restrict__ w, const float* __restrict__ bias,
    float* __restrict__ out, int in_dim, int tok_dim, int ntok)
{
    int t = blockIdx.x, b = blockIdx.y, d = threadIdx.x;
    __shared__ float xv[64];
    if (d < tok_dim) {
        int idx = t*tok_dim + d;
        xv[d] = (idx < in_dim) ? x[(size_t)b*in_dim + idx] : 0.f;
    }
    __syncthreads();
    float acc = bias[d];
    for (int k=0;k<tok_dim;k++) acc += xv[k]*w[(size_t)k*DM + d];
    out[(size_t)(b*ntok + t)*DM + d] = acc;
}

// ---------------- split-K MFMA GEMM (split-bf16 3-term) -> f32 partials ----------------
// C_part[split][M][N] = A[M][Kslice] @ B ; TB=false: B=[K][N]; TB=true: B=[N][K].
// BM=BN=64, BK=32, 256 threads = 4 waves; wave w owns rows [w*16,w*16+16).
// Each f32 operand is split hi/lo bf16; D += Ah*Wh + Ah*Wl + Al*Wh (err ~2^-17).
struct GemmJob {
    const float* A; const float* B; float* part; int M;
};

template<bool TB, int NSPLIT>
__global__ __launch_bounds__(256) void gemm_mfma(GemmJob j0, GemmJob j1, GemmJob j2, int N, int K)
{
    const int z = blockIdx.z;
    const int job = z / NSPLIT, split = z % NSPLIT;
    GemmJob jb = (job==0) ? j0 : (job==1 ? j1 : j2);
    const int bm = blockIdx.y*64, bn = blockIdx.x*64;
    const int M = jb.M;
    if (bm >= M) return;

    constexpr int SR = 40;            // row stride in ushorts (80B: conflict-light)
    __shared__ unsigned short Ah[64*SR], Al[64*SR];
    __shared__ unsigned short Bh[64*SR], Bl[64*SR];

    const int tid = threadIdx.x;
    const float* __restrict__ A  = jb.A;
    const float* __restrict__ Bm = jb.B;

    // staging coords
    const int ar = tid >> 2, ac0 = (tid & 3) * 8;     // A: row 0..63, col0 {0,8,16,24}
    const int wkN = tid >> 3, wcN0 = (tid & 7) * 8;   // W(NN): k 0..31, col0 {0..56}
    const int wnT = tid >> 2, wkT0 = (tid & 3) * 8;   // W(NT): n 0..63, k0 {0,8,16,24}

    float a_reg[8];
    float w_reg[8];

    auto loadA = [&](int k0){
        if (bm + ar < M){
            const float* src = A + (size_t)(bm+ar)*K + k0 + ac0;
            float4 v0 = *(const float4*)(src);
            float4 v1 = *(const float4*)(src+4);
            a_reg[0]=v0.x; a_reg[1]=v0.y; a_reg[2]=v0.z; a_reg[3]=v0.w;
            a_reg[4]=v1.x; a_reg[5]=v1.y; a_reg[6]=v1.z; a_reg[7]=v1.w;
        } else {
            #pragma unroll
            for (int j=0;j<8;j++) a_reg[j]=0.f;
        }
    };
    auto loadW = [&](int k0){
        if constexpr (!TB){
            const float* src = Bm + (size_t)(k0+wkN)*N + bn + wcN0;
            if (bn + wcN0 + 4 <= N){
                float4 v0 = *(const float4*)(src);
                float4 v1 = *(const float4*)(src+4);
                w_reg[0]=v0.x; w_reg[1]=v0.y; w_reg[2]=v0.z; w_reg[3]=v0.w;
                w_reg[4]=v1.x; w_reg[5]=v1.y; w_reg[6]=v1.z; w_reg[7]=v1.w;
            } else if (bn + wcN0 < N){
                float4 v0 = *(const float4*)(src);
                w_reg[0]=v0.x; w_reg[1]=v0.y; w_reg[2]=v0.z; w_reg[3]=v0.w;
                w_reg[4]=0.f; w_reg[5]=0.f; w_reg[6]=0.f; w_reg[7]=0.f;
            } else {
                #pragma unroll
                for (int j=0;j<8;j++) w_reg[j]=0.f;
            }
        } else {
            if (bn + wnT < N){
                const float* src = Bm + (size_t)(bn+wnT)*K + k0 + wkT0;
                float4 v0 = *(const float4*)(src);
                float4 v1 = *(const float4*)(src+4);
                w_reg[0]=v0.x; w_reg[1]=v0.y; w_reg[2]=v0.z; w_reg[3]=v0.w;
                w_reg[4]=v1.x; w_reg[5]=v1.y; w_reg[6]=v1.z; w_reg[7]=v1.w;
            } else {
                #pragma unroll
                for (int j=0;j<8;j++) w_reg[j]=0.f;
            }
        }
    };
    auto storeT = [&](){
        #pragma unroll
        for (int j=0;j<8;j++){
            const unsigned short h = f2bh(a_reg[j]);
            const unsigned short lo = f2bh(a_reg[j] - bh2f(h));
            Ah[ar*SR + ac0 + j] = h;
            Al[ar*SR + ac0 + j] = lo;
        }
        if constexpr (!TB){
            #pragma unroll
            for (int j=0;j<8;j++){
                const unsigned short h = f2bh(w_reg[j]);
                const unsigned short lo = f2bh(w_reg[j] - bh2f(h));
                Bh[(wcN0+j)*SR + wkN] = h;      // transpose to [n][k]
                Bl[(wcN0+j)*SR + wkN] = lo;
            }
        } else {
            #pragma unroll
            for (int j=0;j<8;j++){
                const unsigned short h = f2bh(w_reg[j]);
                const unsigned short lo = f2bh(w_reg[j] - bh2f(h));
                Bh[wnT*SR + wkT0 + j] = h;      // already [n][k]
                Bl[wnT*SR + wkT0 + j] = lo;
            }
        }
    };

    const int Kper = K / NSPLIT;
    const int koff = split * Kper;
    const int nk   = Kper / 32;

    const int l  = tid & 63, w = tid >> 6;
    const int fr = l & 15, kg = (l >> 4) * 8;

    f32x4 acc0 = {0.f,0.f,0.f,0.f};
    f32x4 acc1 = {0.f,0.f,0.f,0.f};
    f32x4 acc2 = {0.f,0.f,0.f,0.f};
    f32x4 acc3 = {0.f,0.f,0.f,0.f};

    loadA(koff); loadW(koff);
    for (int t=0; t<nk; ++t){
        storeT();
        __syncthreads();
        if (t+1 < nk){ loadA(koff+(t+1)*32); loadW(koff+(t+1)*32); }

        const short8 ah = *(const short8*)&Ah[(w*16+fr)*SR + kg];
        const short8 al = *(const short8*)&Al[(w*16+fr)*SR + kg];
        {
            const short8 bh = *(const short8*)&Bh[(fr)*SR + kg];
            const short8 bl = *(const short8*)&Bl[(fr)*SR + kg];
            acc0 = __builtin_amdgcn_mfma_f32_16x16x32_bf16(ah, bh, acc0, 0,0,0);
            acc0 = __builtin_amdgcn_mfma_f32_16x16x32_bf16(ah, bl, acc0, 0,0,0);
            acc0 = __builtin_amdgcn_mfma_f32_16x16x32_bf16(al, bh, acc0, 0,0,0);
        }
        {
            const short8 bh = *(const short8*)&Bh[(16+fr)*SR + kg];
            const short8 bl = *(const short8*)&Bl[(16+fr)*SR + kg];
            acc1 = __builtin_amdgcn_mfma_f32_16x16x32_bf16(ah, bh, acc1, 0,0,0);
            acc1 = __builtin_amdgcn_mfma_f32_16x16x32_bf16(ah, bl, acc1, 0,0,0);
            acc1 = __builtin_amdgcn_mfma_f32_16x16x32_bf16(al, bh, acc1, 0,0,0);
        }
        {
            const short8 bh = *(const short8*)&Bh[(32+fr)*SR + kg];
            const short8 bl = *(const short8*)&Bl[(32+fr)*SR + kg];
            acc2 = __builtin_amdgcn_mfma_f32_16x16x32_bf16(ah, bh, acc2, 0,0,0);
            acc2 = __builtin_amdgcn_mfma_f32_16x16x32_bf16(ah, bl, acc2, 0,0,0);
            acc2 = __builtin_amdgcn_mfma_f32_16x16x32_bf16(al, bh, acc2, 0,0,0);
        }
        {
            const short8 bh = *(const short8*)&Bh[(48+fr)*SR + kg];
            const short8 bl = *(const short8*)&Bl[(48+fr)*SR + kg];
            acc3 = __builtin_amdgcn_mfma_f32_16x16x32_bf16(ah, bh, acc3, 0,0,0);
            acc3 = __builtin_amdgcn_mfma_f32_16x16x32_bf16(ah, bl, acc3, 0,0,0);
            acc3 = __builtin_amdgcn_mfma_f32_16x16x32_bf16(al, bh, acc3, 0,0,0);
        }
        __syncthreads();
    }

    // C/D layout (m89-verified): col = lane&15, row = (lane>>4)*4 + reg
    float* __restrict__ P = jb.part + (size_t)split*M*N;
    const int rbase = bm + w*16 + (l>>4)*4;
    #pragma unroll
    for (int nt=0; nt<4; ++nt){
        const f32x4 a = (nt==0)?acc0 : (nt==1)?acc1 : (nt==2)?acc2 : acc3;
        const int n = bn + nt*16 + fr;
        if (n < N){
            #pragma unroll
            for (int j=0;j<4;j++){
                const int m = rbase + j;
                if (m < M) P[(size_t)m*N + n] = a[j];
            }
        }
    }
}

// ---------------- reduce partials (+bias, +res) ----------------
struct RJob { const float* part; const float* bias; const float* res; float* C; int M; };

template<int NS>
__global__ __launch_bounds__(256) void reduce_k(RJob j0, RJob j1, int N)
{
    RJob j = blockIdx.y ? j1 : j0;
    const size_t total = (size_t)j.M*N;
    const size_t i4 = ((size_t)blockIdx.x*256 + threadIdx.x)*4;
    if (i4 >= total) return;
    float4 s = *(const float4*)(j.part + i4);
    #pragma unroll
    for (int t=1;t<NS;t++){
        const float4 v = *(const float4*)(j.part + (size_t)t*total + i4);
        s.x+=v.x; s.y+=v.y; s.z+=v.z; s.w+=v.w;
    }
    const int n = (int)(i4 % (size_t)N);
    if (j.bias){ s.x+=j.bias[n]; s.y+=j.bias[n+1]; s.z+=j.bias[n+2]; s.w+=j.bias[n+3]; }
    if (j.res){ const float4 r = *(const float4*)(j.res + i4); s.x+=r.x; s.y+=r.y; s.z+=r.z; s.w+=r.w; }
    *(float4*)(j.C + i4) = s;
}

template<int NS>
__global__ __launch_bounds__(256) void reduce_k3(RJob j0, RJob j1, RJob j2, int N)
{
    RJob j = (blockIdx.y==0) ? j0 : (blockIdx.y==1 ? j1 : j2);
    const size_t total = (size_t)j.M*N;
    const size_t i4 = ((size_t)blockIdx.x*256 + threadIdx.x)*4;
    if (i4 >= total) return;
    float4 s = *(const float4*)(j.part + i4);
    #pragma unroll
    for (int t=1;t<NS;t++){
        const float4 v = *(const float4*)(j.part + (size_t)t*total + i4);
        s.x+=v.x; s.y+=v.y; s.z+=v.z; s.w+=v.w;
    }
    const int n = (int)(i4 % (size_t)N);
    if (j.bias){ s.x+=j.bias[n]; s.y+=j.bias[n+1]; s.z+=j.bias[n+2]; s.w+=j.bias[n+3]; }
    if (j.res){ const float4 r = *(const float4*)(j.res + i4); s.x+=r.x; s.y+=r.y; s.z+=r.z; s.w+=r.w; }
    *(float4*)(j.C + i4) = s;
}

// ---------------- mamba prep: reduce partials + conv + silu + softplus ----------------
struct PrepJob {
    const float* part;     // [SP_IN][R][DPROJ]
    float* zsilu; float* xh; float* Bc; float* Cc; float* dtw;
    const float* cw; const float* cb; const float* dtb;
    int R, L;
};

__device__ __forceinline__ float4 psum4(const float* p, size_t pstr){
    float4 a = *(const float4*)p;
    const float4 b = *(const float4*)(p + pstr);
    const float4 c = *(const float4*)(p + 2*pstr);
    const float4 d = *(const float4*)(p + 3*pstr);
    a.x += b.x + c.x + d.x;
    a.y += b.y + c.y + d.y;
    a.z += b.z + c.z + d.z;
    a.w += b.w + c.w + d.w;
    return a;
}

__global__ __launch_bounds__(256) void mamba_prep(PrepJob js, PrepJob jg)
{
    PrepJob j = blockIdx.y ? jg : js;
    const int R = j.R, L = j.L;
    constexpr int QPR = 580;   // 256 (z) + 320 (conv) + 4 (dt) quads per row
    const int q = blockIdx.x*256 + threadIdx.x;
    if (q >= R*QPR) return;
    const int r = q / QPR, qi = q % QPR;
    const int l = r % L;
    const size_t pstr = (size_t)R*DPROJ;
    const float* base = j.part + (size_t)r*DPROJ;

    if (qi < 256) {                 // ---- z region -> silu(z)
        const int c = qi*4;
        float4 s = psum4(base + c, pstr);
        s.x = siluf(s.x); s.y = siluf(s.y); s.z = siluf(s.z); s.w = siluf(s.w);
        *(float4*)(j.zsilu + (size_t)r*1024 + c) = s;
    } else if (qi < 576) {          // ---- conv region
        const int cc = (qi-256)*4;  // 0..1276
        float tk[4][4];
        #pragma unroll
        for (int k=0;k<4;k++){
            const int lr = l - 3 + k;
            if (lr >= 0){
                float4 v = psum4(j.part + (size_t)(r-3+k)*DPROJ + 1024 + cc, pstr);
                tk[k][0]=v.x; tk[k][1]=v.y; tk[k][2]=v.z; tk[k][3]=v.w;
            } else {
                tk[k][0]=0.f; tk[k][1]=0.f; tk[k][2]=0.f; tk[k][3]=0.f;
            }
        }
        const float4 cb4 = *(const float4*)(j.cb + cc);
        const float cba[4] = {cb4.x, cb4.y, cb4.z, cb4.w};
        float out[4];
        #pragma unroll
        for (int jj=0;jj<4;jj++){
            const float4 wv = *(const float4*)(j.cw + (size_t)(cc+jj)*4);
            float v = cba[jj] + wv.x*tk[0][jj] + wv.y*tk[1][jj]
                              + wv.z*tk[2][jj] + wv.w*tk[3][jj];
            out[jj] = siluf(v);
        }
        float4 o4; o4.x=out[0]; o4.y=out[1]; o4.z=out[2]; o4.w=out[3];
        if (cc < 1024)       *(float4*)(j.xh + (size_t)r*1024 + cc)        = o4;
        else if (cc < 1152)  *(float4*)(j.Bc + (size_t)r*128 + (cc-1024))  = o4;
        else                 *(float4*)(j.Cc + (size_t)r*128 + (cc-1152))  = o4;
    } else {                        // ---- dt region
        const int hd = (qi-576)*4;  // 0,4,8,12
        float4 s = psum4(base + 2304 + hd, pstr);
        const float4 b4 = *(const float4*)(j.dtb + hd);
        float raw[4] = {s.x+b4.x, s.y+b4.y, s.z+b4.z, s.w+b4.w};
        float4 o4;
        float* op = &o4.x;
        #pragma unroll
        for (int jj=0;jj<4;jj++)
            op[jj] = (raw[jj] > 20.f) ? raw[jj] : log1pf(expf(raw[jj]));
        *(float4*)(j.dtw + (size_t)r*16 + hd) = o4;
    }
}

// ---------------- CBT = C @ B^T per (batch, stack) — head-independent ----------------
__global__ __launch_bounds__(256) void mamba_cbt(
    const float* __restrict__ Bc_s, const float* __restrict__ Cc_s, float* __restrict__ cbt_s,
    const float* __restrict__ Bc_g, const float* __restrict__ Cc_g, float* __restrict__ cbt_g)
{
    const int b = blockIdx.x, st = blockIdx.y;
    const float* Bc = st ? Bc_g : Bc_s;
    const float* Cc = st ? Cc_g : Cc_s;
    float* cbt = st ? cbt_g : cbt_s;
    const int L = st ? LG : LS;
    constexpr int SB = 132;
    __shared__ float Bm[64*SB], Cm[64*SB];
    const int t = threadIdx.x;
    for (int idx = t; idx < L*32; idx += 256){
        const int l = idx >> 5, c4 = (idx & 31)*4;
        *(float4*)&Bm[l*SB + c4] = *(const float4*)(Bc + (size_t)(b*L+l)*128 + c4);
        *(float4*)&Cm[l*SB + c4] = *(const float4*)(Cc + (size_t)(b*L+l)*128 + c4);
    }
    __syncthreads();
    const int ti = t >> 4, tj = t & 15;
    float acc[4][4] = {};
    for (int k0=0;k0<128;k0+=4){
        float4 cr[4], br[4];
        #pragma unroll
        for (int a=0;a<4;a++) cr[a] = *(const float4*)&Cm[(ti+16*a)*SB + k0];
        #pragma unroll
        for (int qq=0;qq<4;qq++) br[qq] = *(const float4*)&Bm[(tj+16*qq)*SB + k0];
        #pragma unroll
        for (int a=0;a<4;a++)
            #pragma unroll
            for (int qq=0;qq<4;qq++)
                acc[a][qq] += cr[a].x*br[qq].x + cr[a].y*br[qq].y
                            + cr[a].z*br[qq].z + cr[a].w*br[qq].w;
    }
    #pragma unroll
    for (int a=0;a<4;a++){
        const int i = ti + 16*a;
        if (i < L){
            #pragma unroll
            for (int qq=0;qq<4;qq++){
                const int jj = tj + 16*qq;
                if (jj < L) cbt[(size_t)b*3840 + i*60 + jj] = acc[a][qq];
            }
        }
    }
}

// ---------------- Y = (decay .* CBT) @ X + D*X per (head, batch, stack) ----------------
__global__ __launch_bounds__(256) void mamba_y(
    const float* __restrict__ cbt_s, const float* __restrict__ xh_s, const float* __restrict__ dtw_s,
    const float* __restrict__ al_s, const float* __restrict__ Dw_s, float* __restrict__ y_s,
    const float* __restrict__ cbt_g, const float* __restrict__ xh_g, const float* __restrict__ dtw_g,
    const float* __restrict__ al_g, const float* __restrict__ Dw_g, float* __restrict__ y_g)
{
    const int h = blockIdx.x, b = blockIdx.y, st = blockIdx.z;
    const float* cbt = st ? cbt_g : cbt_s;
    const float* xh  = st ? xh_g  : xh_s;
    const float* dtw = st ? dtw_g : dtw_s;
    const float* al  = st ? al_g  : al_s;
    const float* Dw  = st ? Dw_g  : Dw_s;
    float* y = st ? y_g : y_s;
    const int L = st ? LG : LS;

    const int t = threadIdx.x;
    constexpr int SG = 60, SX = 68;
    __shared__ float Gm[64*SG], Xm[64*SX];
    __shared__ float dts[64], sps[64];

    const float Ah = -expf(al[h]);
    const float Dh = Dw[h];

    // dt + prefix scan (wave 0)
    if (t < 64){
        float dtv = (t < L) ? dtw[(size_t)(b*L+t)*16 + h] : 0.f;
        float s = dtv;
        #pragma unroll
        for (int d=1; d<64; d<<=1){
            float o = __shfl_up(s, d, 64);
            if (t >= d) s += o;
        }
        dts[t] = dtv; sps[t] = s;
    }
    // load X tile
    for (int idx = t; idx < L*16; idx += 256){
        const int l = idx >> 4, c4 = (idx & 15)*4;
        *(float4*)&Xm[l*SX + c4] = *(const float4*)(xh + (size_t)(b*L+l)*1024 + h*64 + c4);
    }
    __syncthreads();

    // G = decay .* CBT
    for (int idx = t; idx < L*15; idx += 256){
        const int i = idx/15, j4 = (idx%15)*4;
        const float4 v = *(const float4*)(cbt + (size_t)b*3840 + i*60 + j4);
        const float va[4] = {v.x, v.y, v.z, v.w};
        float g[4];
        const float si = sps[i];
        #pragma unroll
        for (int jj=0;jj<4;jj++){
            const int jc = j4 + jj;
            float gg = 0.f;
            if (jc <= i && jc < L)
                gg = expf(Ah*(si - sps[jc])) * dts[jc] * va[jj];
            g[jj] = gg;
        }
        float4 g4; g4.x=g[0]; g4.y=g[1]; g4.z=g[2]; g4.w=g[3];
        *(float4*)&Gm[i*SG + j4] = g4;
    }
    __syncthreads();

    // Y = G @ X + D*X
    const int ti = t >> 4, tj = t & 15;
    int la[4];
    #pragma unroll
    for (int a=0;a<4;a++) la[a] = ti + 16*a;
    float accY[4][4] = {};
    for (int m=0; m<L; ++m){
        float xr[4], gr[4];
        #pragma unroll
        for (int qq=0;qq<4;qq++) xr[qq] = Xm[m*SX + tj + 16*qq];
        #pragma unroll
        for (int a=0;a<4;a++) gr[a] = (la[a] < L) ? Gm[la[a]*SG + m] : 0.f;
        #pragma unroll
        for (int a=0;a<4;a++)
            #pragma unroll
            for (int qq=0;qq<4;qq++) accY[a][qq] = fmaf(gr[a], xr[qq], accY[a][qq]);
    }
    #pragma unroll
    for (int a=0;a<4;a++){
        if (la[a] < L){
            float* yrow = y + (size_t)(b*L + la[a])*DIN + h*HD;
            #pragma unroll
            for (int qq=0;qq<4;qq++){
                const int col = tj + 16*qq;
                yrow[col] = accY[a][qq] + Dh * Xm[la[a]*SX + col];
            }
        }
    }
}

// ---------------- gated RMSNorm (z pre-silu'd by prep) ----------------
__global__ __launch_bounds__(256) void gated_rmsnorm(
    const float* __restrict__ y_s, const float* __restrict__ zs_s, const float* __restrict__ nw_s, float* __restrict__ o_s,
    const float* __restrict__ y_g, const float* __restrict__ zs_g, const float* __restrict__ nw_g, float* __restrict__ o_g)
{
    int r = blockIdx.x, t = threadIdx.x;
    int st = (r >= RS);
    int row = st ? r - RS : r;
    const float* y  = (st ? y_g  : y_s) + (size_t)row*DIN;
    const float* zs = (st ? zs_g : zs_s) + (size_t)row*DIN;
    const float* nw = st ? nw_g : nw_s;
    float* o = (st ? o_g : o_s) + (size_t)row*DIN;

    float g[4]; float s2 = 0.f;
    #pragma unroll
    for (int i=0;i<4;i++){
        int idx = t + i*256;
        float gv = y[idx] * zs[idx];
        g[i] = gv; s2 += gv*gv;
    }
    #pragma unroll
    for (int o2=32;o2;o2>>=1) s2 += __shfl_xor(s2, o2, 64);
    __shared__ float red[4];
    if ((t & 63) == 0) red[t>>6] = s2;
    __syncthreads();
    float S2 = red[0]+red[1]+red[2]+red[3];
    float scale = rsqrtf(S2*(1.f/DIN) + 1e-5f);
    #pragma unroll
    for (int i=0;i<4;i++){
        int idx = t + i*256;
        o[idx] = g[i]*scale*nw[idx];
    }
}

// ---------------- LayerNorm rows ----------------
__global__ __launch_bounds__(256) void ln_rows(
    const float* __restrict__ x, const float* __restrict__ w, const float* __restrict__ b,
    float* __restrict__ out, int D)
{
    int r = blockIdx.x, t = threadIdx.x;
    const float* xr = x + (size_t)r*D;
    float s = 0.f, s2 = 0.f;
    for (int i=t;i<D;i+=256){ float v = xr[i]; s += v; s2 += v*v; }
    #pragma unroll
    for (int o=32;o;o>>=1){ s += __shfl_xor(s,o,64); s2 += __shfl_xor(s2,o,64); }
    __shared__ float red[8];
    if ((t & 63) == 0){ red[t>>6] = s; red[4+(t>>6)] = s2; }
    __syncthreads();
    float S  = red[0]+red[1]+red[2]+red[3];
    float S2 = red[4]+red[5]+red[6]+red[7];
    float mean = S/D;
    float var  = S2/D - mean*mean;
    float inv  = rsqrtf(var + 1e-5f);
    for (int i=t;i<D;i+=256)
        out[(size_t)r*D + i] = (xr[i]-mean)*inv*w[i] + b[i];
}

// ---------------- cross-attention core v2: dense Q/K/V, 256 threads ----------------
template<int LQ, int LKV>
__global__ __launch_bounds__(256) void mha_attn2(
    const float* __restrict__ qh, const float* __restrict__ kh,
    const float* __restrict__ vh, float* __restrict__ out)
{
    const int hh = blockIdx.x, b = blockIdx.y, t = threadIdx.x;
    constexpr int SD = 68;            // 64-dim row stride (pad)
    constexpr int SS = 60;            // score row stride
    constexpr int QT = (LQ +15)/16;
    constexpr int KT = (LKV+15)/16;
    __shared__ float Qs[LQ*SD];
    __shared__ float Ks[LKV*SD];
    __shared__ float Vs[LKV*SD];
    __shared__ float Ps[LQ*SS];

    for (int idx = t; idx < LQ*16; idx += 256){
        const int r = idx>>4, c4 = (idx&15)*4;
        *(float4*)&Qs[r*SD+c4] = *(const float4*)(qh + (size_t)(b*LQ+r)*DM + hh*64 + c4);
    }
    for (int idx = t; idx < LKV*16; idx += 256){
        const int r = idx>>4, c4 = (idx&15)*4;
        *(float4*)&Ks[r*SD+c4] = *(const float4*)(kh + (size_t)(b*LKV+r)*DM + hh*64 + c4);
        *(float4*)&Vs[r*SD+c4] = *(const float4*)(vh + (size_t)(b*LKV+r)*DM + hh*64 + c4);
    }
    __syncthreads();

    const int ti = t>>4, tj = t&15;

    // scores S = 0.125 * Q @ K^T
    {
        float acc[QT][KT];
        #pragma unroll
        for (int a=0;a<QT;a++)
            #pragma unroll
            for (int q=0;q<KT;q++) acc[a][q] = 0.f;
        for (int k0=0;k0<64;k0+=4){
            float4 qr[QT], kr[KT];
            #pragma unroll
            for (int a=0;a<QT;a++){
                int rr = ti+16*a; if (rr >= LQ) rr = LQ-1;
                qr[a] = *(const float4*)&Qs[rr*SD+k0];
            }
            #pragma unroll
            for (int q=0;q<KT;q++){
                int rr = tj+16*q; if (rr >= LKV) rr = LKV-1;
                kr[q] = *(const float4*)&Ks[rr*SD+k0];
            }
            #pragma unroll
            for (int a=0;a<QT;a++)
                #pragma unroll
                for (int q=0;q<KT;q++)
                    acc[a][q] += qr[a].x*kr[q].x + qr[a].y*kr[q].y
                               + qr[a].z*kr[q].z + qr[a].w*kr[q].w;
        }
        #pragma unroll
        for (int a=0;a<QT;a++){
            const int i = ti+16*a;
            if (i < LQ){
                #pragma unroll
                for (int q=0;q<KT;q++){
                    const int jj = tj+16*q;
                    if (jj < LKV) Ps[i*SS+jj] = acc[a][q]*0.125f;
                }
            }
        }
    }
    __syncthreads();

    // row softmax (thread t handles row t)
    if (t < LQ){
        float mx = -1e30f;
        for (int j=0;j<LKV;j++) mx = fmaxf(mx, Ps[t*SS+j]);
        float se = 0.f;
        for (int j=0;j<LKV;j++){ float e = expf(Ps[t*SS+j]-mx); Ps[t*SS+j] = e; se += e; }
        const float inv = 1.f/se;
        for (int j=0;j<LKV;j++) Ps[t*SS+j] *= inv;
    }
    __syncthreads();

    // O = P @ V : thread (ti: query group, tj: 4-dim group)
    {
        float o[QT][4];
        #pragma unroll
        for (int a=0;a<QT;a++){ o[a][0]=0.f; o[a][1]=0.f; o[a][2]=0.f; o[a][3]=0.f; }
        for (int m=0;m<LKV;m++){
            const float4 vv = *(const float4*)&Vs[m*SD + tj*4];
            #pragma unroll
            for (int a=0;a<QT;a++){
                const int rr = ti+16*a;
                const float pv = (rr < LQ) ? Ps[rr*SS+m] : 0.f;
                o[a][0] = fmaf(pv, vv.x, o[a][0]);
                o[a][1] = fmaf(pv, vv.y, o[a][1]);
                o[a][2] = fmaf(pv, vv.z, o[a][2]);
                o[a][3] = fmaf(pv, vv.w, o[a][3]);
            }
        }
        #pragma unroll
        for (int a=0;a<QT;a++){
            const int rr = ti+16*a;
            if (rr < LQ){
                float4 o4; o4.x=o[a][0]; o4.y=o[a][1]; o4.z=o[a][2]; o4.w=o[a][3];
                *(float4*)(out + (size_t)(b*LQ+rr)*DM + hh*64 + tj*4) = o4;
            }
        }
    }
}

// ---------------- fused head: meanpool + LN + classifier ----------------
__global__ __launch_bounds__(512) void head_fused(
    const float* __restrict__ xs, const float* __restrict__ xg,
    const float* __restrict__ lw, const float* __restrict__ lb,
    const float* __restrict__ cw, const float* __restrict__ cb,
    float* __restrict__ out)
{
    const int b = blockIdx.x, t = threadIdx.x;
    __shared__ float fr[1024];
    __shared__ float red[16];
    __shared__ float pr[55*8];
    {
        float s = 0.f;
        for (int l=0;l<LS;l++) s += xs[(size_t)(b*LS+l)*DM + t];
        fr[t] = s*(1.f/LS);
        float g = 0.f;
        for (int l=0;l<LG;l++) g += xg[(size_t)(b*LG+l)*DM + t];
        fr[512+t] = g*(1.f/LG);
    }
    __syncthreads();
    float v0 = fr[t], v1 = fr[512+t];
    float sm = v0+v1, sq = v0*v0 + v1*v1;
    #pragma unroll
    for (int o=32;o;o>>=1){ sm += __shfl_xor(sm,o,64); sq += __shfl_xor(sq,o,64); }
    if ((t&63)==0){ red[t>>6] = sm; red[8+(t>>6)] = sq; }
    __syncthreads();
    float S=0.f, Q=0.f;
    #pragma unroll
    for (int i=0;i<8;i++){ S += red[i]; Q += red[8+i]; }
    const float mean = S*(1.f/1024.f);
    const float var  = Q*(1.f/1024.f) - mean*mean;
    const float inv  = rsqrtf(var + 1e-5f);
    fr[t]     = (v0-mean)*inv*lw[t]     + lb[t];
    fr[512+t] = (v1-mean)*inv*lw[512+t] + lb[512+t];
    __syncthreads();
    {
        const int c = t & 63, pp = t >> 6;   // 8 parts of 128
        if (c < 55){
            float a = 0.f;
            const float* wr = cw + (size_t)c*1024 + pp*128;
            const float* xr = fr + pp*128;
            #pragma unroll 4
            for (int k=0;k<128;k++) a = fmaf(xr[k], wr[k], a);
            pr[c*8+pp] = a;
        }
    }
    __syncthreads();
    if (t < 55){
        float a = cb[t];
        #pragma unroll
        for (int p2=0;p2<8;p2++) a += pr[t*8+p2];
        out[b*55 + t] = a;
    }
}

// ---------------- launch ----------------
extern "C" void kernel_launch(void* const* d_in, const int* in_sizes, int n_in,
                              void* d_out, int out_size, void* d_ws, size_t ws_size,
                              hipStream_t stream)
{
    (void)in_sizes; (void)n_in; (void)out_size; (void)ws_size;
    const float* x_spectra = (const float*)d_in[0];
    const float* x_gaia    = (const float*)d_in[1];
    const float* tok_w_s   = (const float*)d_in[2];
    const float* tok_b_s   = (const float*)d_in[3];
    const float* tok_w_g   = (const float*)d_in[4];
    const float* tok_b_g   = (const float*)d_in[5];
    const float* ms_Win    = (const float*)d_in[6];
    const float* ms_conv_w = (const float*)d_in[7];
    const float* ms_conv_b = (const float*)d_in[8];
    const float* ms_dtb    = (const float*)d_in[9];
    const float* ms_Alog   = (const float*)d_in[10];
    const float* ms_D      = (const float*)d_in[11];
    const float* ms_nw     = (const float*)d_in[12];
    const float* ms_Wout   = (const float*)d_in[13];
    const float* mg_Win    = (const float*)d_in[14];
    const float* mg_conv_w = (const float*)d_in[15];
    const float* mg_conv_b = (const float*)d_in[16];
    const float* mg_dtb    = (const float*)d_in[17];
    const float* mg_Alog   = (const float*)d_in[18];
    const float* mg_D      = (const float*)d_in[19];
    const float* mg_nw     = (const float*)d_in[20];
    const float* mg_Wout   = (const float*)d_in[21];
    const float* cas_ln_w  = (const float*)d_in[22];
    const float* cas_ln_b  = (const float*)d_in[23];
    const float* cas_in_w  = (const float*)d_in[24];
    const float* cas_in_b  = (const float*)d_in[25];
    const float* cas_out_w = (const float*)d_in[26];
    const float* cas_out_b = (const float*)d_in[27];
    const float* cag_ln_w  = (const float*)d_in[28];
    const float* cag_ln_b  = (const float*)d_in[29];
    const float* cag_in_w  = (const float*)d_in[30];
    const float* cag_in_b  = (const float*)d_in[31];
    const float* cag_out_w = (const float*)d_in[32];
    const float* cag_out_b = (const float*)d_in[33];
    const float* cls_ln_w  = (const float*)d_in[34];
    const float* cls_ln_b  = (const float*)d_in[35];
    const float* cls_w     = (const float*)d_in[36];
    const float* cls_b     = (const float*)d_in[37];

    float* p = (float*)d_ws;
    auto alloc = [&](size_t n){ float* r = p; p += n; return r; };
    float* xs       = alloc((size_t)RS*DM);
    float* xg       = alloc((size_t)RG*DM);
    float* y_s      = alloc((size_t)RS*DIN);
    float* y_g      = alloc((size_t)RG*DIN);
    float* yn_s     = alloc((size_t)RS*DIN);
    float* yn_g     = alloc((size_t)RG*DIN);
    float* lnbuf    = alloc((size_t)RS*DM);
    float* attn_out = alloc((size_t)RS*DM);
    float* part_inS  = alloc((size_t)SP_IN*RS*DPROJ);
    float* part_inG  = alloc((size_t)SP_IN*RG*DPROJ);
    float* part_outS = alloc((size_t)SP_OUT*RS*DM);
    float* part_outG = alloc((size_t)SP_OUT*RG*DM);
    // union region: mamba mixer buffers during layers; attn partials afterwards
    float* uni       = alloc((size_t)3*SP_ATT*RS*DM);
    float* zsilu_s = uni;
    float* zsilu_g = zsilu_s + (size_t)RS*1024;
    float* xh_s    = zsilu_g + (size_t)RG*1024;
    float* xh_g    = xh_s    + (size_t)RS*1024;
    float* Bc_s    = xh_g    + (size_t)RG*1024;
    float* Bc_g    = Bc_s    + (size_t)RS*128;
    float* Cc_s    = Bc_g    + (size_t)RG*128;
    float* Cc_g    = Cc_s    + (size_t)RS*128;
    float* dtw_s   = Cc_g    + (size_t)RG*128;
    float* dtw_g   = dtw_s   + (size_t)RS*16;
    float* cbt_s   = dtw_g   + (size_t)RG*16;
    float* cbt_g   = cbt_s   + (size_t)BB*3840;
    float* part_q = uni;
    float* part_k = uni + (size_t)SP_ATT*RS*DM;
    float* part_v = uni + (size_t)2*SP_ATT*RS*DM;
    // dense q/k/v aliased onto dead mixer buffers (RS*DIN == 2*RS*DM exactly)
    float* qh = y_s;
    float* vh = y_s + (size_t)RS*DM;
    float* kh = yn_s;

    // tokenize
    tokenize_k<<<dim3(LS,BB), 512, 0, stream>>>(x_spectra, tok_w_s, tok_b_s, xs, 3647, 64, LS);
    tokenize_k<<<dim3(LG,BB), 512, 0, stream>>>(x_gaia,    tok_w_g, tok_b_g, xg, 18,   2,  LG);

    const int rblkS = (RS*DM + 1023)/1024;   // 228
    const int prepBlk = (RS*580 + 255)/256;  // 1034
    const int NTI = (DPROJ + 63)/64;         // 37 N-tiles for in-proj

    // mamba stacks
    for (int i=0;i<NLAY;i++){
        const float* Win_s  = ms_Win  + (size_t)i*DM*DPROJ;
        const float* Win_g  = mg_Win  + (size_t)i*DM*DPROJ;
        const float* cw_s   = ms_conv_w + (size_t)i*1280*4;
        const float* cw_g   = mg_conv_w + (size_t)i*1280*4;
        const float* cbv_s  = ms_conv_b + (size_t)i*1280;
        const float* cbv_g  = mg_conv_b + (size_t)i*1280;
        const float* dtb_s  = ms_dtb  + (size_t)i*NH;
        const float* dtb_g  = mg_dtb  + (size_t)i*NH;
        const float* al_s   = ms_Alog + (size_t)i*NH;
        const float* al_g   = mg_Alog + (size_t)i*NH;
        const float* Dw_s   = ms_D    + (size_t)i*NH;
        const float* Dw_g   = mg_D    + (size_t)i*NH;
        const float* nw_s   = ms_nw   + (size_t)i*DIN;
        const float* nw_g   = mg_nw   + (size_t)i*DIN;
        const float* Wout_s = ms_Wout + (size_t)i*DIN*DM;
        const float* Wout_g = mg_Wout + (size_t)i*DIN*DM;

        GemmJob inS{xs, Win_s, part_inS, RS};
        GemmJob inG{xg, Win_g, part_inG, RG};
        gemm_mfma<false,SP_IN><<<dim3(NTI, 8, 2*SP_IN), 256, 0, stream>>>(
            inS, inG, inG, DPROJ, DM);

        PrepJob pjS{part_inS, zsilu_s, xh_s, Bc_s, Cc_s, dtw_s, cw_s, cbv_s, dtb_s, RS, LS};
        PrepJob pjG{part_inG, zsilu_g, xh_g, Bc_g, Cc_g, dtw_g, cw_g, cbv_g, dtb_g, RG, LG};
        mamba_prep<<<dim3(prepBlk, 2), 256, 0, stream>>>(pjS, pjG);

        mamba_cbt<<<dim3(BB, 2), 256, 0, stream>>>(Bc_s, Cc_s, cbt_s, Bc_g, Cc_g, cbt_g);

        mamba_y<<<dim3(NH, BB, 2), 256, 0, stream>>>(
            cbt_s, xh_s, dtw_s, al_s, Dw_s, y_s,
            cbt_g, xh_g, dtw_g, al_g, Dw_g, y_g);

        gated_rmsnorm<<<dim3(RS+RG), 256, 0, stream>>>(
            y_s, zsilu_s, nw_s, yn_s,  y_g, zsilu_g, nw_g, yn_g);

        GemmJob outS{yn_s, Wout_s, part_outS, RS};
        GemmJob outG{yn_g, Wout_g, part_outG, RG};
        gemm_mfma<false,SP_OUT><<<dim3(DM/64, 8, 2*SP_OUT), 256, 0, stream>>>(
            outS, outG, outG, DM, DIN);

        RJob roS{part_outS, nullptr, nullptr, xs, RS};
        RJob roG{part_outG, nullptr, nullptr, xg, RG};
        reduce_k<SP_OUT><<<dim3(rblkS, 2), 256, 0, stream>>>(roS, roG, DM);
    }

    // cross-attention: xs = xs + MHA(LN(xs), xg)
    {
        ln_rows<<<dim3(RS), 256, 0, stream>>>(xs, cas_ln_w, cas_ln_b, lnbuf, DM);
        GemmJob jq{lnbuf, cas_in_w,            part_q, RS};
        GemmJob jk{xg,    cas_in_w +  512*512, part_k, RG};
        GemmJob jv{xg,    cas_in_w + 1024*512, part_v, RG};
        gemm_mfma<true,SP_ATT><<<dim3(DM/64, 8, 3*SP_ATT), 256, 0, stream>>>(jq, jk, jv, DM, DM);
        RJob rq{part_q, cas_in_b,      nullptr, qh, RS};
        RJob rk{part_k, cas_in_b+512,  nullptr, kh, RG};
        RJob rv{part_v, cas_in_b+1024, nullptr, vh, RG};
        reduce_k3<SP_ATT><<<dim3(rblkS, 3), 256, 0, stream>>>(rq, rk, rv, DM);
        mha_attn2<LS,LG><<<dim3(8,BB), 256, 0, stream>>>(qh, kh, vh, attn_out);
        GemmJob jo{attn_out, cas_out_w, part_outS, RS};
        gemm_mfma<true,SP_ATT><<<dim3(DM/64, 8, SP_ATT), 256, 0, stream>>>(jo, jo, jo, DM, DM);
        RJob ro{part_outS, cas_out_b, xs, xs, RS};
        reduce_k<SP_ATT><<<dim3(rblkS, 1), 256, 0, stream>>>(ro, ro, DM);
    }

    // cross-attention: xg = xg + MHA(LN(xg), xs_updated)
    {
        ln_rows<<<dim3(RG), 256, 0, stream>>>(xg, cag_ln_w, cag_ln_b, lnbuf, DM);
        GemmJob jq{lnbuf, cag_in_w,            part_q, RG};
        GemmJob jk{xs,    cag_in_w +  512*512, part_k, RS};
        GemmJob jv{xs,    cag_in_w + 1024*512, part_v, RS};
        gemm_mfma<true,SP_ATT><<<dim3(DM/64, 8, 3*SP_ATT), 256, 0, stream>>>(jq, jk, jv, DM, DM);
        RJob rq{part_q, cag_in_b,      nullptr, qh, RG};
        RJob rk{part_k, cag_in_b+512,  nullptr, kh, RS};
        RJob rv{part_v, cag_in_b+1024, nullptr, vh, RS};
        reduce_k3<SP_ATT><<<dim3(rblkS, 3), 256, 0, stream>>>(rq, rk, rv, DM);
        mha_attn2<LG,LS><<<dim3(8,BB), 256, 0, stream>>>(qh, kh, vh, attn_out);
        GemmJob jo{attn_out, cag_out_w, part_outS, RG};
        gemm_mfma<true,SP_ATT><<<dim3(DM/64, 2, SP_ATT), 256, 0, stream>>>(jo, jo, jo, DM, DM);
        RJob ro{part_outS, cag_out_b, xg, xg, RG};
        reduce_k<SP_ATT><<<dim3((RG*DM+1023)/1024, 1), 256, 0, stream>>>(ro, ro, DM);
    }

    // fused head
    head_fused<<<dim3(BB), 512, 0, stream>>>(xs, xg, cls_ln_w, cls_ln_b, cls_w, cls_b, (float*)d_out);
}

// Round 9
// 765.262 us; speedup vs baseline: 1.8583x; 1.0964x over previous
//
#include <hip/hip_runtime.h>
#include <cmath>

// ---------------- constants ----------------
constexpr int BB    = 8;     // batch
constexpr int LS    = 57;    // spectra tokens
constexpr int LG    = 9;     // gaia tokens
constexpr int RS    = BB*LS; // 456
constexpr int RG    = BB*LG; // 72
constexpr int DM    = 512;   // d_model
constexpr int DPROJ = 2320;
constexpr int DIN   = 1024;
constexpr int NH    = 16;    // mamba heads
constexpr int HD    = 64;    // mamba headdim
constexpr int NLAY  = 10;

constexpr int SP_IN  = 2;    // split-K for in-proj  (K=512  -> 256/split)
constexpr int SP_OUT = 8;    // split-K for out-proj (K=1024 -> 128/split)
constexpr int SP_ATT = 4;    // split-K for attention gemms (K=512 -> 128/split)

__device__ __forceinline__ float siluf(float x){ return x / (1.f + expf(-x)); }

// ---------------- bf16 split helpers ----------------
typedef short  short8  __attribute__((ext_vector_type(8)));
typedef short  short4_ __attribute__((ext_vector_type(4)));
typedef float  f32x4   __attribute__((ext_vector_type(4)));

__device__ __forceinline__ unsigned short f2bh(float f){
    unsigned int u = __float_as_uint(f);
    u = u + 0x7FFFu + ((u >> 16) & 1u);
    return (unsigned short)(u >> 16);
}
__device__ __forceinline__ float bh2f(unsigned short h){
    return __uint_as_float(((unsigned int)h) << 16);
}

// ---------------- tokenize (+bf16 planes) ----------------
__global__ __launch_bounds__(512) void tokenize_k(
    const float* __restrict__ x, const float* __restrict__ w, const float* __restrict__ bias,
    float* __restrict__ out, unsigned short* __restrict__ outh, unsigned short* __restrict__ outl,
    int in_dim, int tok_dim, int ntok)
{
    int t = blockIdx.x, b = blockIdx.y, d = threadIdx.x;
    __shared__ float xv[64];
    if (d < tok_dim) {
        int idx = t*tok_dim + d;
        xv[d] = (idx < in_dim) ? x[(size_t)b*in_dim + idx] : 0.f;
    }
    __syncthreads();
    float acc = bias[d];
    for (int k=0;k<tok_dim;k++) acc += xv[k]*w[(size_t)k*DM + d];
    const size_t o = (size_t)(b*ntok + t)*DM + d;
    out[o] = acc;
    const unsigned short h = f2bh(acc);
    outh[o] = h;
    outl[o] = f2bh(acc - bh2f(h));
}

// ---------------- one-time weight conversion: [K][N] f32 -> [N][K] bf16 hi/lo ----------------
// z in [0,20): Win (layer=z>>1, stack=z&1), K=512, N=2320
// z in [20,40): Wout (i=z-20),            K=1024, N=512
__global__ __launch_bounds__(256) void convert_all_w(
    const float* __restrict__ winS, const float* __restrict__ winG,
    const float* __restrict__ woutS, const float* __restrict__ woutG,
    unsigned short* __restrict__ winh, unsigned short* __restrict__ winl,
    unsigned short* __restrict__ wouth, unsigned short* __restrict__ woutl)
{
    const int z = blockIdx.z;
    const float* src; unsigned short *dh, *dl; int K, N;
    if (z < 20){
        const int layer = z >> 1, s = z & 1;
        src = (s ? winG : winS) + (size_t)layer*DM*DPROJ;
        K = DM; N = DPROJ;
        dh = winh + (size_t)z*DPROJ*DM;
        dl = winl + (size_t)z*DPROJ*DM;
    } else {
        const int i = z - 20, layer = i >> 1, s = i & 1;
        src = (s ? woutG : woutS) + (size_t)layer*DIN*DM;
        K = DIN; N = DM;
        dh = wouth + (size_t)i*DM*DIN;
        dl = woutl + (size_t)i*DM*DIN;
    }
    const int nt = blockIdx.x*64, kt = blockIdx.y*64;
    if (nt >= N || kt >= K) return;
    __shared__ float tile[64][65];
    const int tid = threadIdx.x;
    #pragma unroll
    for (int i=0;i<4;i++){
        const int kk = (tid>>4) + i*16;
        const int c4 = (tid&15)*4;
        const int n = nt + c4;
        float4 v = {0.f,0.f,0.f,0.f};
        if (n + 3 < N) v = *(const float4*)(src + (size_t)(kt+kk)*N + n);
        else {
            if (n   < N) v.x = src[(size_t)(kt+kk)*N + n];
            if (n+1 < N) v.y = src[(size_t)(kt+kk)*N + n+1];
            if (n+2 < N) v.z = src[(size_t)(kt+kk)*N + n+2];
            if (n+3 < N) v.w = src[(size_t)(kt+kk)*N + n+3];
        }
        tile[kk][c4]=v.x; tile[kk][c4+1]=v.y; tile[kk][c4+2]=v.z; tile[kk][c4+3]=v.w;
    }
    __syncthreads();
    #pragma unroll
    for (int i=0;i<2;i++){
        const int c = tid + i*256;
        const int n = c >> 3, k8 = (c & 7)*8;
        if (nt + n < N){
            short8 vh_, vl_;
            #pragma unroll
            for (int q=0;q<8;q++){
                const float f = tile[k8+q][n];
                const unsigned short h = f2bh(f);
                vh_[q] = (short)h;
                vl_[q] = (short)f2bh(f - bh2f(h));
            }
            *(short8*)(dh + (size_t)(nt+n)*K + kt + k8) = vh_;
            *(short8*)(dl + (size_t)(nt+n)*K + kt + k8) = vl_;
        }
    }
}

// ---------------- elementwise weight split (attn weights already [N][K]) ----------------
struct CvtE { const float* src; unsigned short* h; unsigned short* l; int n; };

__global__ __launch_bounds__(256) void convert_wE(CvtE j0, CvtE j1, CvtE j2, CvtE j3)
{
    CvtE j = (blockIdx.y==0)?j0 : (blockIdx.y==1)?j1 : (blockIdx.y==2)?j2 : j3;
    const int i4 = (blockIdx.x*256 + threadIdx.x)*4;
    if (i4 >= j.n) return;
    const float4 v = *(const float4*)(j.src + i4);
    const float f[4] = {v.x,v.y,v.z,v.w};
    short4_ h4, l4;
    #pragma unroll
    for (int q=0;q<4;q++){
        const unsigned short h = f2bh(f[q]);
        h4[q] = (short)h;
        l4[q] = (short)f2bh(f[q] - bh2f(h));
    }
    *(short4_*)(j.h + i4) = h4;
    *(short4_*)(j.l + i4) = l4;
}

// ---------------- split-K MFMA GEMM, pre-split bf16 operands ----------------
// part[split][M][N] = A[M][Kslice] @ W^T ; A,W given as hi/lo bf16 planes, [row][k].
// BM=BN=64, BK=32, 256 threads = 4 waves, double-buffered LDS, 1 barrier/K-step.
struct GemmJob {
    const unsigned short* Ah; const unsigned short* Al;
    const unsigned short* Wh; const unsigned short* Wl;
    float* part; int M;
};

template<int NSPLIT>
__global__ __launch_bounds__(256) void gemm_mfma(GemmJob j0, GemmJob j1, GemmJob j2, int N, int K)
{
    const int z = blockIdx.z;
    const int job = z / NSPLIT, split = z % NSPLIT;
    GemmJob jb = (job==0) ? j0 : (job==1 ? j1 : j2);
    const int bm = blockIdx.y*64, bn = blockIdx.x*64;
    const int M = jb.M;
    if (bm >= M) return;

    constexpr int SR = 40;
    __shared__ unsigned short AhS[2][64*SR], AlS[2][64*SR];
    __shared__ unsigned short BhS[2][64*SR], BlS[2][64*SR];

    const int tid = threadIdx.x;
    const int r0 = tid >> 2, k0off = (tid & 3)*8;
    const bool aok = (bm + r0 < M);
    const bool wok = (bn + r0 < N);
    const unsigned short* Aph = jb.Ah + (size_t)(bm+r0)*K;
    const unsigned short* Apl = jb.Al + (size_t)(bm+r0)*K;
    const unsigned short* Wph = jb.Wh + (size_t)(bn+r0)*K;
    const unsigned short* Wpl = jb.Wl + (size_t)(bn+r0)*K;

    const short8 z8 = {0,0,0,0,0,0,0,0};
    short8 ra_h = z8, ra_l = z8, rw_h = z8, rw_l = z8;

    auto loadT = [&](int k0){
        if (aok){
            ra_h = *(const short8*)(Aph + k0 + k0off);
            ra_l = *(const short8*)(Apl + k0 + k0off);
        } else { ra_h = z8; ra_l = z8; }
        if (wok){
            rw_h = *(const short8*)(Wph + k0 + k0off);
            rw_l = *(const short8*)(Wpl + k0 + k0off);
        } else { rw_h = z8; rw_l = z8; }
    };
    auto storeT = [&](int buf){
        *(short8*)&AhS[buf][r0*SR + k0off] = ra_h;
        *(short8*)&AlS[buf][r0*SR + k0off] = ra_l;
        *(short8*)&BhS[buf][r0*SR + k0off] = rw_h;
        *(short8*)&BlS[buf][r0*SR + k0off] = rw_l;
    };

    const int Kper = K / NSPLIT;
    const int koff = split * Kper;
    const int nk = Kper / 32;

    const int l = tid & 63, w = tid >> 6;
    const int fr = l & 15, kg = (l >> 4)*8;

    f32x4 acc0 = {0.f,0.f,0.f,0.f};
    f32x4 acc1 = {0.f,0.f,0.f,0.f};
    f32x4 acc2 = {0.f,0.f,0.f,0.f};
    f32x4 acc3 = {0.f,0.f,0.f,0.f};

    loadT(koff);
    storeT(0);
    __syncthreads();
    for (int t=0; t<nk; ++t){
        const int cur = t & 1;
        if (t+1 < nk) loadT(koff + (t+1)*32);

        const short8 ah = *(const short8*)&AhS[cur][(w*16+fr)*SR + kg];
        const short8 al = *(const short8*)&AlS[cur][(w*16+fr)*SR + kg];
        {
            const short8 bh = *(const short8*)&BhS[cur][(fr)*SR + kg];
            const short8 bl = *(const short8*)&BlS[cur][(fr)*SR + kg];
            acc0 = __builtin_amdgcn_mfma_f32_16x16x32_bf16(ah, bh, acc0, 0,0,0);
            acc0 = __builtin_amdgcn_mfma_f32_16x16x32_bf16(ah, bl, acc0, 0,0,0);
            acc0 = __builtin_amdgcn_mfma_f32_16x16x32_bf16(al, bh, acc0, 0,0,0);
        }
        {
            const short8 bh = *(const short8*)&BhS[cur][(16+fr)*SR + kg];
            const short8 bl = *(const short8*)&BlS[cur][(16+fr)*SR + kg];
            acc1 = __builtin_amdgcn_mfma_f32_16x16x32_bf16(ah, bh, acc1, 0,0,0);
            acc1 = __builtin_amdgcn_mfma_f32_16x16x32_bf16(ah, bl, acc1, 0,0,0);
            acc1 = __builtin_amdgcn_mfma_f32_16x16x32_bf16(al, bh, acc1, 0,0,0);
        }
        {
            const short8 bh = *(const short8*)&BhS[cur][(32+fr)*SR + kg];
            const short8 bl = *(const short8*)&BlS[cur][(32+fr)*SR + kg];
            acc2 = __builtin_amdgcn_mfma_f32_16x16x32_bf16(ah, bh, acc2, 0,0,0);
            acc2 = __builtin_amdgcn_mfma_f32_16x16x32_bf16(ah, bl, acc2, 0,0,0);
            acc2 = __builtin_amdgcn_mfma_f32_16x16x32_bf16(al, bh, acc2, 0,0,0);
        }
        {
            const short8 bh = *(const short8*)&BhS[cur][(48+fr)*SR + kg];
            const short8 bl = *(const short8*)&BlS[cur][(48+fr)*SR + kg];
            acc3 = __builtin_amdgcn_mfma_f32_16x16x32_bf16(ah, bh, acc3, 0,0,0);
            acc3 = __builtin_amdgcn_mfma_f32_16x16x32_bf16(ah, bl, acc3, 0,0,0);
            acc3 = __builtin_amdgcn_mfma_f32_16x16x32_bf16(al, bh, acc3, 0,0,0);
        }
        if (t+1 < nk) storeT(cur^1);
        __syncthreads();
    }

    // C/D layout (m89-verified): col = lane&15, row = (lane>>4)*4 + reg
    float* __restrict__ P = jb.part + (size_t)split*M*N;
    const int rbase = bm + w*16 + (l>>4)*4;
    #pragma unroll
    for (int nt=0; nt<4; ++nt){
        const f32x4 a = (nt==0)?acc0 : (nt==1)?acc1 : (nt==2)?acc2 : acc3;
        const int n = bn + nt*16 + fr;
        if (n < N){
            #pragma unroll
            for (int j=0;j<4;j++){
                const int m = rbase + j;
                if (m < M) P[(size_t)m*N + n] = a[j];
            }
        }
    }
}

// ---------------- reduce partials (+bias, +res, +optional bf16 planes) ----------------
struct RJob { const float* part; const float* bias; const float* res; float* C;
              unsigned short* ph; unsigned short* pl; int M; };

template<int NS>
__global__ __launch_bounds__(256) void reduce_k(RJob j0, RJob j1, int N)
{
    RJob j = blockIdx.y ? j1 : j0;
    const size_t total = (size_t)j.M*N;
    const size_t i4 = ((size_t)blockIdx.x*256 + threadIdx.x)*4;
    if (i4 >= total) return;
    float4 s = *(const float4*)(j.part + i4);
    #pragma unroll
    for (int t=1;t<NS;t++){
        const float4 v = *(const float4*)(j.part + (size_t)t*total + i4);
        s.x+=v.x; s.y+=v.y; s.z+=v.z; s.w+=v.w;
    }
    const int n = (int)(i4 % (size_t)N);
    if (j.bias){ s.x+=j.bias[n]; s.y+=j.bias[n+1]; s.z+=j.bias[n+2]; s.w+=j.bias[n+3]; }
    if (j.res){ const float4 r = *(const float4*)(j.res + i4); s.x+=r.x; s.y+=r.y; s.z+=r.z; s.w+=r.w; }
    if (j.C) *(float4*)(j.C + i4) = s;
    if (j.ph){
        const float f[4] = {s.x, s.y, s.z, s.w};
        short4_ h4, l4;
        #pragma unroll
        for (int q=0;q<4;q++){
            const unsigned short h = f2bh(f[q]);
            h4[q] = (short)h;
            l4[q] = (short)f2bh(f[q] - bh2f(h));
        }
        *(short4_*)(j.ph + i4) = h4;
        *(short4_*)(j.pl + i4) = l4;
    }
}

template<int NS>
__global__ __launch_bounds__(256) void reduce_k3(RJob j0, RJob j1, RJob j2, int N)
{
    RJob j = (blockIdx.y==0) ? j0 : (blockIdx.y==1 ? j1 : j2);
    const size_t total = (size_t)j.M*N;
    const size_t i4 = ((size_t)blockIdx.x*256 + threadIdx.x)*4;
    if (i4 >= total) return;
    float4 s = *(const float4*)(j.part + i4);
    #pragma unroll
    for (int t=1;t<NS;t++){
        const float4 v = *(const float4*)(j.part + (size_t)t*total + i4);
        s.x+=v.x; s.y+=v.y; s.z+=v.z; s.w+=v.w;
    }
    const int n = (int)(i4 % (size_t)N);
    if (j.bias){ s.x+=j.bias[n]; s.y+=j.bias[n+1]; s.z+=j.bias[n+2]; s.w+=j.bias[n+3]; }
    if (j.res){ const float4 r = *(const float4*)(j.res + i4); s.x+=r.x; s.y+=r.y; s.z+=r.z; s.w+=r.w; }
    *(float4*)(j.C + i4) = s;
}

// ---------------- mamba prep: reduce 2 partials + conv + silu + softplus ----------------
struct PrepJob {
    const float* part;     // [SP_IN][R][DPROJ]
    float* zsilu; float* xh; float* Bc; float* Cc; float* dtw;
    const float* cw; const float* cb; const float* dtb;
    int R, L;
};

__device__ __forceinline__ float4 psum2(const float* p, size_t pstr){
    float4 a = *(const float4*)p;
    const float4 b = *(const float4*)(p + pstr);
    a.x += b.x; a.y += b.y; a.z += b.z; a.w += b.w;
    return a;
}

__global__ __launch_bounds__(256) void mamba_prep(PrepJob js, PrepJob jg)
{
    PrepJob j = blockIdx.y ? jg : js;
    const int R = j.R, L = j.L;
    constexpr int QPR = 580;   // 256 (z) + 320 (conv) + 4 (dt) quads per row
    const int q = blockIdx.x*256 + threadIdx.x;
    if (q >= R*QPR) return;
    const int r = q / QPR, qi = q % QPR;
    const int l = r % L;
    const size_t pstr = (size_t)R*DPROJ;
    const float* base = j.part + (size_t)r*DPROJ;

    if (qi < 256) {                 // ---- z region -> silu(z)
        const int c = qi*4;
        float4 s = psum2(base + c, pstr);
        s.x = siluf(s.x); s.y = siluf(s.y); s.z = siluf(s.z); s.w = siluf(s.w);
        *(float4*)(j.zsilu + (size_t)r*1024 + c) = s;
    } else if (qi < 576) {          // ---- conv region
        const int cc = (qi-256)*4;  // 0..1276
        float tk[4][4];
        #pragma unroll
        for (int k=0;k<4;k++){
            const int lr = l - 3 + k;
            if (lr >= 0){
                float4 v = psum2(j.part + (size_t)(r-3+k)*DPROJ + 1024 + cc, pstr);
                tk[k][0]=v.x; tk[k][1]=v.y; tk[k][2]=v.z; tk[k][3]=v.w;
            } else {
                tk[k][0]=0.f; tk[k][1]=0.f; tk[k][2]=0.f; tk[k][3]=0.f;
            }
        }
        const float4 cb4 = *(const float4*)(j.cb + cc);
        const float cba[4] = {cb4.x, cb4.y, cb4.z, cb4.w};
        float out[4];
        #pragma unroll
        for (int jj=0;jj<4;jj++){
            const float4 wv = *(const float4*)(j.cw + (size_t)(cc+jj)*4);
            float v = cba[jj] + wv.x*tk[0][jj] + wv.y*tk[1][jj]
                              + wv.z*tk[2][jj] + wv.w*tk[3][jj];
            out[jj] = siluf(v);
        }
        float4 o4; o4.x=out[0]; o4.y=out[1]; o4.z=out[2]; o4.w=out[3];
        if (cc < 1024)       *(float4*)(j.xh + (size_t)r*1024 + cc)        = o4;
        else if (cc < 1152)  *(float4*)(j.Bc + (size_t)r*128 + (cc-1024))  = o4;
        else                 *(float4*)(j.Cc + (size_t)r*128 + (cc-1152))  = o4;
    } else {                        // ---- dt region
        const int hd = (qi-576)*4;  // 0,4,8,12
        float4 s = psum2(base + 2304 + hd, pstr);
        const float4 b4 = *(const float4*)(j.dtb + hd);
        float raw[4] = {s.x+b4.x, s.y+b4.y, s.z+b4.z, s.w+b4.w};
        float4 o4;
        float* op = &o4.x;
        #pragma unroll
        for (int jj=0;jj<4;jj++)
            op[jj] = (raw[jj] > 20.f) ? raw[jj] : log1pf(expf(raw[jj]));
        *(float4*)(j.dtw + (size_t)r*16 + hd) = o4;
    }
}

// ---------------- CBT = C @ B^T per (batch, stack) — head-independent ----------------
__global__ __launch_bounds__(256) void mamba_cbt(
    const float* __restrict__ Bc_s, const float* __restrict__ Cc_s, float* __restrict__ cbt_s,
    const float* __restrict__ Bc_g, const float* __restrict__ Cc_g, float* __restrict__ cbt_g)
{
    const int b = blockIdx.x, st = blockIdx.y;
    const float* Bc = st ? Bc_g : Bc_s;
    const float* Cc = st ? Cc_g : Cc_s;
    float* cbt = st ? cbt_g : cbt_s;
    const int L = st ? LG : LS;
    constexpr int SB = 132;
    __shared__ float Bm[64*SB], Cm[64*SB];
    const int t = threadIdx.x;
    for (int idx = t; idx < L*32; idx += 256){
        const int l = idx >> 5, c4 = (idx & 31)*4;
        *(float4*)&Bm[l*SB + c4] = *(const float4*)(Bc + (size_t)(b*L+l)*128 + c4);
        *(float4*)&Cm[l*SB + c4] = *(const float4*)(Cc + (size_t)(b*L+l)*128 + c4);
    }
    __syncthreads();
    const int ti = t >> 4, tj = t & 15;
    float acc[4][4] = {};
    for (int k0=0;k0<128;k0+=4){
        float4 cr[4], br[4];
        #pragma unroll
        for (int a=0;a<4;a++) cr[a] = *(const float4*)&Cm[(ti+16*a)*SB + k0];
        #pragma unroll
        for (int qq=0;qq<4;qq++) br[qq] = *(const float4*)&Bm[(tj+16*qq)*SB + k0];
        #pragma unroll
        for (int a=0;a<4;a++)
            #pragma unroll
            for (int qq=0;qq<4;qq++)
                acc[a][qq] += cr[a].x*br[qq].x + cr[a].y*br[qq].y
                            + cr[a].z*br[qq].z + cr[a].w*br[qq].w;
    }
    #pragma unroll
    for (int a=0;a<4;a++){
        const int i = ti + 16*a;
        if (i < L){
            #pragma unroll
            for (int qq=0;qq<4;qq++){
                const int jj = tj + 16*qq;
                if (jj < L) cbt[(size_t)b*3840 + i*60 + jj] = acc[a][qq];
            }
        }
    }
}

// ---------------- Y = (decay .* CBT) @ X + D*X per (head, batch, stack) ----------------
__global__ __launch_bounds__(256) void mamba_y(
    const float* __restrict__ cbt_s, const float* __restrict__ xh_s, const float* __restrict__ dtw_s,
    const float* __restrict__ al_s, const float* __restrict__ Dw_s, float* __restrict__ y_s,
    const float* __restrict__ cbt_g, const float* __restrict__ xh_g, const float* __restrict__ dtw_g,
    const float* __restrict__ al_g, const float* __restrict__ Dw_g, float* __restrict__ y_g)
{
    const int h = blockIdx.x, b = blockIdx.y, st = blockIdx.z;
    const float* cbt = st ? cbt_g : cbt_s;
    const float* xh  = st ? xh_g  : xh_s;
    const float* dtw = st ? dtw_g : dtw_s;
    const float* al  = st ? al_g  : al_s;
    const float* Dw  = st ? Dw_g  : Dw_s;
    float* y = st ? y_g : y_s;
    const int L = st ? LG : LS;

    const int t = threadIdx.x;
    constexpr int SG = 60, SX = 68;
    __shared__ float Gm[64*SG], Xm[64*SX];
    __shared__ float dts[64], sps[64];

    const float Ah = -expf(al[h]);
    const float Dh = Dw[h];

    if (t < 64){
        float dtv = (t < L) ? dtw[(size_t)(b*L+t)*16 + h] : 0.f;
        float s = dtv;
        #pragma unroll
        for (int d=1; d<64; d<<=1){
            float o = __shfl_up(s, d, 64);
            if (t >= d) s += o;
        }
        dts[t] = dtv; sps[t] = s;
    }
    for (int idx = t; idx < L*16; idx += 256){
        const int l = idx >> 4, c4 = (idx & 15)*4;
        *(float4*)&Xm[l*SX + c4] = *(const float4*)(xh + (size_t)(b*L+l)*1024 + h*64 + c4);
    }
    __syncthreads();

    for (int idx = t; idx < L*15; idx += 256){
        const int i = idx/15, j4 = (idx%15)*4;
        const float4 v = *(const float4*)(cbt + (size_t)b*3840 + i*60 + j4);
        const float va[4] = {v.x, v.y, v.z, v.w};
        float g[4];
        const float si = sps[i];
        #pragma unroll
        for (int jj=0;jj<4;jj++){
            const int jc = j4 + jj;
            float gg = 0.f;
            if (jc <= i && jc < L)
                gg = expf(Ah*(si - sps[jc])) * dts[jc] * va[jj];
            g[jj] = gg;
        }
        float4 g4; g4.x=g[0]; g4.y=g[1]; g4.z=g[2]; g4.w=g[3];
        *(float4*)&Gm[i*SG + j4] = g4;
    }
    __syncthreads();

    const int ti = t >> 4, tj = t & 15;
    int la[4];
    #pragma unroll
    for (int a=0;a<4;a++) la[a] = ti + 16*a;
    float accY[4][4] = {};
    for (int m=0; m<L; ++m){
        float xr[4], gr[4];
        #pragma unroll
        for (int qq=0;qq<4;qq++) xr[qq] = Xm[m*SX + tj + 16*qq];
        #pragma unroll
        for (int a=0;a<4;a++) gr[a] = (la[a] < L) ? Gm[la[a]*SG + m] : 0.f;
        #pragma unroll
        for (int a=0;a<4;a++)
            #pragma unroll
            for (int qq=0;qq<4;qq++) accY[a][qq] = fmaf(gr[a], xr[qq], accY[a][qq]);
    }
    #pragma unroll
    for (int a=0;a<4;a++){
        if (la[a] < L){
            float* yrow = y + (size_t)(b*L + la[a])*DIN + h*HD;
            #pragma unroll
            for (int qq=0;qq<4;qq++){
                const int col = tj + 16*qq;
                yrow[col] = accY[a][qq] + Dh * Xm[la[a]*SX + col];
            }
        }
    }
}

// ---------------- gated RMSNorm -> bf16 planes only ----------------
__global__ __launch_bounds__(256) void gated_rmsnorm(
    const float* __restrict__ y_s, const float* __restrict__ zs_s, const float* __restrict__ nw_s,
    unsigned short* __restrict__ oh_s, unsigned short* __restrict__ ol_s,
    const float* __restrict__ y_g, const float* __restrict__ zs_g, const float* __restrict__ nw_g,
    unsigned short* __restrict__ oh_g, unsigned short* __restrict__ ol_g)
{
    int r = blockIdx.x, t = threadIdx.x;
    int st = (r >= RS);
    int row = st ? r - RS : r;
    const float* y  = (st ? y_g  : y_s) + (size_t)row*DIN;
    const float* zs = (st ? zs_g : zs_s) + (size_t)row*DIN;
    const float* nw = st ? nw_g : nw_s;
    unsigned short* oh = (st ? oh_g : oh_s) + (size_t)row*DIN;
    unsigned short* ol = (st ? ol_g : ol_s) + (size_t)row*DIN;

    float g[4]; float s2 = 0.f;
    #pragma unroll
    for (int i=0;i<4;i++){
        int idx = t + i*256;
        float gv = y[idx] * zs[idx];
        g[i] = gv; s2 += gv*gv;
    }
    #pragma unroll
    for (int o2=32;o2;o2>>=1) s2 += __shfl_xor(s2, o2, 64);
    __shared__ float red[4];
    if ((t & 63) == 0) red[t>>6] = s2;
    __syncthreads();
    float S2 = red[0]+red[1]+red[2]+red[3];
    float scale = rsqrtf(S2*(1.f/DIN) + 1e-5f);
    #pragma unroll
    for (int i=0;i<4;i++){
        int idx = t + i*256;
        const float val = g[i]*scale*nw[idx];
        const unsigned short h = f2bh(val);
        oh[idx] = h;
        ol[idx] = f2bh(val - bh2f(h));
    }
}

// ---------------- LayerNorm rows -> bf16 planes ----------------
__global__ __launch_bounds__(256) void ln_rows(
    const float* __restrict__ x, const float* __restrict__ w, const float* __restrict__ b,
    unsigned short* __restrict__ outh, unsigned short* __restrict__ outl, int D)
{
    int r = blockIdx.x, t = threadIdx.x;
    const float* xr = x + (size_t)r*D;
    float s = 0.f, s2 = 0.f;
    for (int i=t;i<D;i+=256){ float v = xr[i]; s += v; s2 += v*v; }
    #pragma unroll
    for (int o=32;o;o>>=1){ s += __shfl_xor(s,o,64); s2 += __shfl_xor(s2,o,64); }
    __shared__ float red[8];
    if ((t & 63) == 0){ red[t>>6] = s; red[4+(t>>6)] = s2; }
    __syncthreads();
    float S  = red[0]+red[1]+red[2]+red[3];
    float S2 = red[4]+red[5]+red[6]+red[7];
    float mean = S/D;
    float var  = S2/D - mean*mean;
    float inv  = rsqrtf(var + 1e-5f);
    for (int i=t;i<D;i+=256){
        const float val = (xr[i]-mean)*inv*w[i] + b[i];
        const unsigned short h = f2bh(val);
        outh[(size_t)r*D + i] = h;
        outl[(size_t)r*D + i] = f2bh(val - bh2f(h));
    }
}

// ---------------- cross-attention core: dense Q/K/V f32 in, bf16 planes out ----------------
template<int LQ, int LKV>
__global__ __launch_bounds__(256) void mha_attn2(
    const float* __restrict__ qh, const float* __restrict__ kh,
    const float* __restrict__ vh,
    unsigned short* __restrict__ outh, unsigned short* __restrict__ outl)
{
    const int hh = blockIdx.x, b = blockIdx.y, t = threadIdx.x;
    constexpr int SD = 68;
    constexpr int SS = 60;
    constexpr int QT = (LQ +15)/16;
    constexpr int KT = (LKV+15)/16;
    __shared__ float Qs[LQ*SD];
    __shared__ float Ks[LKV*SD];
    __shared__ float Vs[LKV*SD];
    __shared__ float Ps[LQ*SS];

    for (int idx = t; idx < LQ*16; idx += 256){
        const int r = idx>>4, c4 = (idx&15)*4;
        *(float4*)&Qs[r*SD+c4] = *(const float4*)(qh + (size_t)(b*LQ+r)*DM + hh*64 + c4);
    }
    for (int idx = t; idx < LKV*16; idx += 256){
        const int r = idx>>4, c4 = (idx&15)*4;
        *(float4*)&Ks[r*SD+c4] = *(const float4*)(kh + (size_t)(b*LKV+r)*DM + hh*64 + c4);
        *(float4*)&Vs[r*SD+c4] = *(const float4*)(vh + (size_t)(b*LKV+r)*DM + hh*64 + c4);
    }
    __syncthreads();

    const int ti = t>>4, tj = t&15;

    {
        float acc[QT][KT];
        #pragma unroll
        for (int a=0;a<QT;a++)
            #pragma unroll
            for (int q=0;q<KT;q++) acc[a][q] = 0.f;
        for (int k0=0;k0<64;k0+=4){
            float4 qr[QT], kr[KT];
            #pragma unroll
            for (int a=0;a<QT;a++){
                int rr = ti+16*a; if (rr >= LQ) rr = LQ-1;
                qr[a] = *(const float4*)&Qs[rr*SD+k0];
            }
            #pragma unroll
            for (int q=0;q<KT;q++){
                int rr = tj+16*q; if (rr >= LKV) rr = LKV-1;
                kr[q] = *(const float4*)&Ks[rr*SD+k0];
            }
            #pragma unroll
            for (int a=0;a<QT;a++)
                #pragma unroll
                for (int q=0;q<KT;q++)
                    acc[a][q] += qr[a].x*kr[q].x + qr[a].y*kr[q].y
                               + qr[a].z*kr[q].z + qr[a].w*kr[q].w;
        }
        #pragma unroll
        for (int a=0;a<QT;a++){
            const int i = ti+16*a;
            if (i < LQ){
                #pragma unroll
                for (int q=0;q<KT;q++){
                    const int jj = tj+16*q;
                    if (jj < LKV) Ps[i*SS+jj] = acc[a][q]*0.125f;
                }
            }
        }
    }
    __syncthreads();

    if (t < LQ){
        float mx = -1e30f;
        for (int j=0;j<LKV;j++) mx = fmaxf(mx, Ps[t*SS+j]);
        float se = 0.f;
        for (int j=0;j<LKV;j++){ float e = expf(Ps[t*SS+j]-mx); Ps[t*SS+j] = e; se += e; }
        const float inv = 1.f/se;
        for (int j=0;j<LKV;j++) Ps[t*SS+j] *= inv;
    }
    __syncthreads();

    {
        float o[QT][4];
        #pragma unroll
        for (int a=0;a<QT;a++){ o[a][0]=0.f; o[a][1]=0.f; o[a][2]=0.f; o[a][3]=0.f; }
        for (int m=0;m<LKV;m++){
            const float4 vv = *(const float4*)&Vs[m*SD + tj*4];
            #pragma unroll
            for (int a=0;a<QT;a++){
                const int rr = ti+16*a;
                const float pv = (rr < LQ) ? Ps[rr*SS+m] : 0.f;
                o[a][0] = fmaf(pv, vv.x, o[a][0]);
                o[a][1] = fmaf(pv, vv.y, o[a][1]);
                o[a][2] = fmaf(pv, vv.z, o[a][2]);
                o[a][3] = fmaf(pv, vv.w, o[a][3]);
            }
        }
        #pragma unroll
        for (int a=0;a<QT;a++){
            const int rr = ti+16*a;
            if (rr < LQ){
                short4_ h4, l4;
                #pragma unroll
                for (int q=0;q<4;q++){
                    const unsigned short h = f2bh(o[a][q]);
                    h4[q] = (short)h;
                    l4[q] = (short)f2bh(o[a][q] - bh2f(h));
                }
                const size_t off = (size_t)(b*LQ+rr)*DM + hh*64 + tj*4;
                *(short4_*)(outh + off) = h4;
                *(short4_*)(outl + off) = l4;
            }
        }
    }
}

// ---------------- fused head: meanpool + LN + classifier ----------------
__global__ __launch_bounds__(512) void head_fused(
    const float* __restrict__ xs, const float* __restrict__ xg,
    const float* __restrict__ lw, const float* __restrict__ lb,
    const float* __restrict__ cw, const float* __restrict__ cb,
    float* __restrict__ out)
{
    const int b = blockIdx.x, t = threadIdx.x;
    __shared__ float fr[1024];
    __shared__ float red[16];
    __shared__ float pr[55*8];
    {
        float s = 0.f;
        for (int l=0;l<LS;l++) s += xs[(size_t)(b*LS+l)*DM + t];
        fr[t] = s*(1.f/LS);
        float g = 0.f;
        for (int l=0;l<LG;l++) g += xg[(size_t)(b*LG+l)*DM + t];
        fr[512+t] = g*(1.f/LG);
    }
    __syncthreads();
    float v0 = fr[t], v1 = fr[512+t];
    float sm = v0+v1, sq = v0*v0 + v1*v1;
    #pragma unroll
    for (int o=32;o;o>>=1){ sm += __shfl_xor(sm,o,64); sq += __shfl_xor(sq,o,64); }
    if ((t&63)==0){ red[t>>6] = sm; red[8+(t>>6)] = sq; }
    __syncthreads();
    float S=0.f, Q=0.f;
    #pragma unroll
    for (int i=0;i<8;i++){ S += red[i]; Q += red[8+i]; }
    const float mean = S*(1.f/1024.f);
    const float var  = Q*(1.f/1024.f) - mean*mean;
    const float inv  = rsqrtf(var + 1e-5f);
    fr[t]     = (v0-mean)*inv*lw[t]     + lb[t];
    fr[512+t] = (v1-mean)*inv*lw[512+t] + lb[512+t];
    __syncthreads();
    {
        const int c = t & 63, pp = t >> 6;
        if (c < 55){
            float a = 0.f;
            const float* wr = cw + (size_t)c*1024 + pp*128;
            const float* xr = fr + pp*128;
            #pragma unroll 4
            for (int k=0;k<128;k++) a = fmaf(xr[k], wr[k], a);
            pr[c*8+pp] = a;
        }
    }
    __syncthreads();
    if (t < 55){
        float a = cb[t];
        #pragma unroll
        for (int p2=0;p2<8;p2++) a += pr[t*8+p2];
        out[b*55 + t] = a;
    }
}

// ---------------- launch ----------------
extern "C" void kernel_launch(void* const* d_in, const int* in_sizes, int n_in,
                              void* d_out, int out_size, void* d_ws, size_t ws_size,
                              hipStream_t stream)
{
    (void)in_sizes; (void)n_in; (void)out_size; (void)ws_size;
    const float* x_spectra = (const float*)d_in[0];
    const float* x_gaia    = (const float*)d_in[1];
    const float* tok_w_s   = (const float*)d_in[2];
    const float* tok_b_s   = (const float*)d_in[3];
    const float* tok_w_g   = (const float*)d_in[4];
    const float* tok_b_g   = (const float*)d_in[5];
    const float* ms_Win    = (const float*)d_in[6];
    const float* ms_conv_w = (const float*)d_in[7];
    const float* ms_conv_b = (const float*)d_in[8];
    const float* ms_dtb    = (const float*)d_in[9];
    const float* ms_Alog   = (const float*)d_in[10];
    const float* ms_D      = (const float*)d_in[11];
    const float* ms_nw     = (const float*)d_in[12];
    const float* ms_Wout   = (const float*)d_in[13];
    const float* mg_Win    = (const float*)d_in[14];
    const float* mg_conv_w = (const float*)d_in[15];
    const float* mg_conv_b = (const float*)d_in[16];
    const float* mg_dtb    = (const float*)d_in[17];
    const float* mg_Alog   = (const float*)d_in[18];
    const float* mg_D      = (const float*)d_in[19];
    const float* mg_nw     = (const float*)d_in[20];
    const float* mg_Wout   = (const float*)d_in[21];
    const float* cas_ln_w  = (const float*)d_in[22];
    const float* cas_ln_b  = (const float*)d_in[23];
    const float* cas_in_w  = (const float*)d_in[24];
    const float* cas_in_b  = (const float*)d_in[25];
    const float* cas_out_w = (const float*)d_in[26];
    const float* cas_out_b = (const float*)d_in[27];
    const float* cag_ln_w  = (const float*)d_in[28];
    const float* cag_ln_b  = (const float*)d_in[29];
    const float* cag_in_w  = (const float*)d_in[30];
    const float* cag_in_b  = (const float*)d_in[31];
    const float* cag_out_w = (const float*)d_in[32];
    const float* cag_out_b = (const float*)d_in[33];
    const float* cls_ln_w  = (const float*)d_in[34];
    const float* cls_ln_b  = (const float*)d_in[35];
    const float* cls_w     = (const float*)d_in[36];
    const float* cls_b     = (const float*)d_in[37];

    float* p = (float*)d_ws;
    auto alloc = [&](size_t n){ float* r = p; p += n; return r; };
    float* xs       = alloc((size_t)RS*DM);
    float* xg       = alloc((size_t)RG*DM);
    float* y_s      = alloc((size_t)RS*DIN);
    float* y_g      = alloc((size_t)RG*DIN);
    float* qh       = alloc((size_t)RS*DM);
    float* kh       = alloc((size_t)RS*DM);
    float* vh       = alloc((size_t)RS*DM);
    float* part_inS  = alloc((size_t)SP_IN*RS*DPROJ);
    float* part_inG  = alloc((size_t)SP_IN*RG*DPROJ);
    float* part_outS = alloc((size_t)SP_OUT*RS*DM);
    float* part_outG = alloc((size_t)SP_OUT*RG*DM);
    float* part_q    = alloc((size_t)SP_ATT*RS*DM);
    float* part_k    = alloc((size_t)SP_ATT*RS*DM);
    float* part_v    = alloc((size_t)SP_ATT*RS*DM);
    float* zsilu_s = alloc((size_t)RS*1024);
    float* zsilu_g = alloc((size_t)RG*1024);
    float* xh_s    = alloc((size_t)RS*1024);
    float* xh_g    = alloc((size_t)RG*1024);
    float* Bc_s    = alloc((size_t)RS*128);
    float* Bc_g    = alloc((size_t)RG*128);
    float* Cc_s    = alloc((size_t)RS*128);
    float* Cc_g    = alloc((size_t)RG*128);
    float* dtw_s   = alloc((size_t)RS*16);
    float* dtw_g   = alloc((size_t)RG*16);
    float* cbt_s   = alloc((size_t)BB*3840);
    float* cbt_g   = alloc((size_t)BB*3840);

    unsigned short* up = (unsigned short*)p;
    auto ualloc = [&](size_t n){ unsigned short* r = up; up += n; return r; };
    unsigned short* xsh   = ualloc((size_t)RS*DM);
    unsigned short* xsl   = ualloc((size_t)RS*DM);
    unsigned short* xgh   = ualloc((size_t)RG*DM);
    unsigned short* xgl   = ualloc((size_t)RG*DM);
    unsigned short* ynh_s = ualloc((size_t)RS*DIN);
    unsigned short* ynl_s = ualloc((size_t)RS*DIN);
    unsigned short* ynh_g = ualloc((size_t)RG*DIN);
    unsigned short* ynl_g = ualloc((size_t)RG*DIN);
    unsigned short* lnh   = ualloc((size_t)RS*DM);
    unsigned short* lnl   = ualloc((size_t)RS*DM);
    unsigned short* aoh   = ualloc((size_t)RS*DM);
    unsigned short* aol   = ualloc((size_t)RS*DM);
    unsigned short* caih  = ualloc((size_t)1536*512);
    unsigned short* cail  = ualloc((size_t)1536*512);
    unsigned short* caoh  = ualloc((size_t)512*512);
    unsigned short* caol  = ualloc((size_t)512*512);
    unsigned short* cgih  = ualloc((size_t)1536*512);
    unsigned short* cgil  = ualloc((size_t)1536*512);
    unsigned short* cgoh  = ualloc((size_t)512*512);
    unsigned short* cgol  = ualloc((size_t)512*512);
    unsigned short* winh  = ualloc((size_t)20*DPROJ*DM);
    unsigned short* winl  = ualloc((size_t)20*DPROJ*DM);
    unsigned short* wouth = ualloc((size_t)20*DM*DIN);
    unsigned short* woutl = ualloc((size_t)20*DM*DIN);

    // one-time weight conversions
    CvtE e0{cas_in_w,  caih, cail, 1536*512};
    CvtE e1{cas_out_w, caoh, caol, 512*512};
    CvtE e2{cag_in_w,  cgih, cgil, 1536*512};
    CvtE e3{cag_out_w, cgoh, cgol, 512*512};
    convert_wE<<<dim3(768, 4), 256, 0, stream>>>(e0, e1, e2, e3);
    convert_all_w<<<dim3(37, 16, 40), 256, 0, stream>>>(
        ms_Win, mg_Win, ms_Wout, mg_Wout, winh, winl, wouth, woutl);

    // tokenize
    tokenize_k<<<dim3(LS,BB), 512, 0, stream>>>(x_spectra, tok_w_s, tok_b_s, xs, xsh, xsl, 3647, 64, LS);
    tokenize_k<<<dim3(LG,BB), 512, 0, stream>>>(x_gaia,    tok_w_g, tok_b_g, xg, xgh, xgl, 18,   2,  LG);

    const int rblkS = (RS*DM + 1023)/1024;   // 228
    const int prepBlk = (RS*580 + 255)/256;  // 1034

    // mamba stacks
    for (int i=0;i<NLAY;i++){
        const float* cw_s   = ms_conv_w + (size_t)i*1280*4;
        const float* cw_g   = mg_conv_w + (size_t)i*1280*4;
        const float* cbv_s  = ms_conv_b + (size_t)i*1280;
        const float* cbv_g  = mg_conv_b + (size_t)i*1280;
        const float* dtb_s  = ms_dtb  + (size_t)i*NH;
        const float* dtb_g  = mg_dtb  + (size_t)i*NH;
        const float* al_s   = ms_Alog + (size_t)i*NH;
        const float* al_g   = mg_Alog + (size_t)i*NH;
        const float* Dw_s   = ms_D    + (size_t)i*NH;
        const float* Dw_g   = mg_D    + (size_t)i*NH;
        const float* nw_s   = ms_nw   + (size_t)i*DIN;
        const float* nw_g   = mg_nw   + (size_t)i*DIN;

        const unsigned short* wih_s = winh + (size_t)(2*i+0)*DPROJ*DM;
        const unsigned short* wil_s = winl + (size_t)(2*i+0)*DPROJ*DM;
        const unsigned short* wih_g = winh + (size_t)(2*i+1)*DPROJ*DM;
        const unsigned short* wil_g = winl + (size_t)(2*i+1)*DPROJ*DM;
        const unsigned short* woh_s = wouth + (size_t)(2*i+0)*DM*DIN;
        const unsigned short* wol_s = woutl + (size_t)(2*i+0)*DM*DIN;
        const unsigned short* woh_g = wouth + (size_t)(2*i+1)*DM*DIN;
        const unsigned short* wol_g = woutl + (size_t)(2*i+1)*DM*DIN;

        GemmJob inS{xsh, xsl, wih_s, wil_s, part_inS, RS};
        GemmJob inG{xgh, xgl, wih_g, wil_g, part_inG, RG};
        gemm_mfma<SP_IN><<<dim3(37, 8, 2*SP_IN), 256, 0, stream>>>(inS, inG, inG, DPROJ, DM);

        PrepJob pjS{part_inS, zsilu_s, xh_s, Bc_s, Cc_s, dtw_s, cw_s, cbv_s, dtb_s, RS, LS};
        PrepJob pjG{part_inG, zsilu_g, xh_g, Bc_g, Cc_g, dtw_g, cw_g, cbv_g, dtb_g, RG, LG};
        mamba_prep<<<dim3(prepBlk, 2), 256, 0, stream>>>(pjS, pjG);

        mamba_cbt<<<dim3(BB, 2), 256, 0, stream>>>(Bc_s, Cc_s, cbt_s, Bc_g, Cc_g, cbt_g);

        mamba_y<<<dim3(NH, BB, 2), 256, 0, stream>>>(
            cbt_s, xh_s, dtw_s, al_s, Dw_s, y_s,
            cbt_g, xh_g, dtw_g, al_g, Dw_g, y_g);

        gated_rmsnorm<<<dim3(RS+RG), 256, 0, stream>>>(
            y_s, zsilu_s, nw_s, ynh_s, ynl_s,  y_g, zsilu_g, nw_g, ynh_g, ynl_g);

        GemmJob outS{ynh_s, ynl_s, woh_s, wol_s, part_outS, RS};
        GemmJob outG{ynh_g, ynl_g, woh_g, wol_g, part_outG, RG};
        gemm_mfma<SP_OUT><<<dim3(8, 8, 2*SP_OUT), 256, 0, stream>>>(outS, outG, outG, DM, DIN);

        RJob roS{part_outS, nullptr, nullptr, xs, xsh, xsl, RS};
        RJob roG{part_outG, nullptr, nullptr, xg, xgh, xgl, RG};
        reduce_k<SP_OUT><<<dim3(rblkS, 2), 256, 0, stream>>>(roS, roG, DM);
    }

    // cross-attention: xs = xs + MHA(LN(xs), xg)
    {
        ln_rows<<<dim3(RS), 256, 0, stream>>>(xs, cas_ln_w, cas_ln_b, lnh, lnl, DM);
        GemmJob jq{lnh, lnl, caih,            cail,            part_q, RS};
        GemmJob jk{xgh, xgl, caih +  512*512, cail +  512*512, part_k, RG};
        GemmJob jv{xgh, xgl, caih + 1024*512, cail + 1024*512, part_v, RG};
        gemm_mfma<SP_ATT><<<dim3(8, 8, 3*SP_ATT), 256, 0, stream>>>(jq, jk, jv, DM, DM);
        RJob rq{part_q, cas_in_b,      nullptr, qh, nullptr, nullptr, RS};
        RJob rk{part_k, cas_in_b+512,  nullptr, kh, nullptr, nullptr, RG};
        RJob rv{part_v, cas_in_b+1024, nullptr, vh, nullptr, nullptr, RG};
        reduce_k3<SP_ATT><<<dim3(rblkS, 3), 256, 0, stream>>>(rq, rk, rv, DM);
        mha_attn2<LS,LG><<<dim3(8,BB), 256, 0, stream>>>(qh, kh, vh, aoh, aol);
        GemmJob jo{aoh, aol, caoh, caol, part_outS, RS};
        gemm_mfma<SP_ATT><<<dim3(8, 8, SP_ATT), 256, 0, stream>>>(jo, jo, jo, DM, DM);
        RJob ro{part_outS, cas_out_b, xs, xs, xsh, xsl, RS};
        reduce_k<SP_ATT><<<dim3(rblkS, 1), 256, 0, stream>>>(ro, ro, DM);
    }

    // cross-attention: xg = xg + MHA(LN(xg), xs_updated)
    {
        ln_rows<<<dim3(RG), 256, 0, stream>>>(xg, cag_ln_w, cag_ln_b, lnh, lnl, DM);
        GemmJob jq{lnh, lnl, cgih,            cgil,            part_q, RG};
        GemmJob jk{xsh, xsl, cgih +  512*512, cgil +  512*512, part_k, RS};
        GemmJob jv{xsh, xsl, cgih + 1024*512, cgil + 1024*512, part_v, RS};
        gemm_mfma<SP_ATT><<<dim3(8, 8, 3*SP_ATT), 256, 0, stream>>>(jq, jk, jv, DM, DM);
        RJob rq{part_q, cag_in_b,      nullptr, qh, nullptr, nullptr, RG};
        RJob rk{part_k, cag_in_b+512,  nullptr, kh, nullptr, nullptr, RS};
        RJob rv{part_v, cag_in_b+1024, nullptr, vh, nullptr, nullptr, RS};
        reduce_k3<SP_ATT><<<dim3(rblkS, 3), 256, 0, stream>>>(rq, rk, rv, DM);
        mha_attn2<LG,LS><<<dim3(8,BB), 256, 0, stream>>>(qh, kh, vh, aoh, aol);
        GemmJob jo{aoh, aol, cgoh, cgol, part_outS, RG};
        gemm_mfma<SP_ATT><<<dim3(8, 2, SP_ATT), 256, 0, stream>>>(jo, jo, jo, DM, DM);
        RJob ro{part_outS, cag_out_b, xg, xg, nullptr, nullptr, RG};
        reduce_k<SP_ATT><<<dim3((RG*DM+1023)/1024, 1), 256, 0, stream>>>(ro, ro, DM);
    }

    // fused head
    head_fused<<<dim3(BB), 512, 0, stream>>>(xs, xg, cls_ln_w, cls_ln_b, cls_w, cls_b, (float*)d_out);
}

// Round 10
// 749.701 us; speedup vs baseline: 1.8969x; 1.0208x over previous
//
#include <hip/hip_runtime.h>
#include <cmath>

// ---------------- constants ----------------
constexpr int BB    = 8;     // batch
constexpr int LS    = 57;    // spectra tokens
constexpr int LG    = 9;     // gaia tokens
constexpr int RS    = BB*LS; // 456
constexpr int RG    = BB*LG; // 72
constexpr int DM    = 512;   // d_model
constexpr int DPROJ = 2320;
constexpr int DIN   = 1024;
constexpr int NH    = 16;    // mamba heads
constexpr int HD    = 64;    // mamba headdim
constexpr int NLAY  = 10;

constexpr int SP_IN  = 2;    // split-K for in-proj  (K=512  -> 256/split)
constexpr int SP_OUT = 8;    // split-K for out-proj (K=1024 -> 128/split)
constexpr int SP_ATT = 4;    // split-K for attention gemms (K=512 -> 128/split)

__device__ __forceinline__ float siluf(float x){ return x / (1.f + expf(-x)); }

// ---------------- bf16 split helpers ----------------
typedef short  short8  __attribute__((ext_vector_type(8)));
typedef short  short4_ __attribute__((ext_vector_type(4)));
typedef float  f32x4   __attribute__((ext_vector_type(4)));

__device__ __forceinline__ unsigned short f2bh(float f){
    unsigned int u = __float_as_uint(f);
    u = u + 0x7FFFu + ((u >> 16) & 1u);
    return (unsigned short)(u >> 16);
}
__device__ __forceinline__ float bh2f(unsigned short h){
    return __uint_as_float(((unsigned int)h) << 16);
}

// ---------------- tokenize both modalities (+bf16 planes) ----------------
__global__ __launch_bounds__(512) void tokenize2(
    const float* __restrict__ xS, const float* __restrict__ wS, const float* __restrict__ bS,
    float* __restrict__ oS, unsigned short* __restrict__ oSh, unsigned short* __restrict__ oSl,
    const float* __restrict__ xG, const float* __restrict__ wG, const float* __restrict__ bG,
    float* __restrict__ oG, unsigned short* __restrict__ oGh, unsigned short* __restrict__ oGl)
{
    const int st = blockIdx.z;
    const int tkt = blockIdx.x, b = blockIdx.y, d = threadIdx.x;
    const int ntok = st ? LG : LS;
    if (tkt >= ntok) return;
    const float* x = st ? xG : xS;
    const float* w = st ? wG : wS;
    const float* bias = st ? bG : bS;
    float* out = st ? oG : oS;
    unsigned short* oh = st ? oGh : oSh;
    unsigned short* ol = st ? oGl : oSl;
    const int in_dim = st ? 18 : 3647, tok_dim = st ? 2 : 64;

    __shared__ float xv[64];
    if (d < tok_dim) {
        int idx = tkt*tok_dim + d;
        xv[d] = (idx < in_dim) ? x[(size_t)b*in_dim + idx] : 0.f;
    }
    __syncthreads();
    float acc = bias[d];
    for (int k=0;k<tok_dim;k++) acc += xv[k]*w[(size_t)k*DM + d];
    const size_t o = (size_t)(b*ntok + tkt)*DM + d;
    out[o] = acc;
    const unsigned short h = f2bh(acc);
    oh[o] = h;
    ol[o] = f2bh(acc - bh2f(h));
}

// ---------------- one-time weight conversion, flat grid (no dead blocks) ----------------
// blocks [0,5920):   Win transpose tiles  (20 planes x 37 n-tiles x 8 k-tiles), K=512,N=2320
// blocks [5920,8480): Wout transpose tiles (20 planes x 8 n-tiles x 16 k-tiles), K=1024,N=512
// blocks [8480,10528): elementwise split of attention weights (already [N][K])
struct CvtE { const float* src; unsigned short* h; unsigned short* l; int nblk; };

__global__ __launch_bounds__(256) void convert_weights(
    const float* __restrict__ winS, const float* __restrict__ winG,
    const float* __restrict__ woutS, const float* __restrict__ woutG,
    unsigned short* __restrict__ winh, unsigned short* __restrict__ winl,
    unsigned short* __restrict__ wouth, unsigned short* __restrict__ woutl,
    CvtE e0, CvtE e1, CvtE e2, CvtE e3)
{
    __shared__ float tile[64][65];
    const int tid = threadIdx.x;
    const int bid = blockIdx.x;

    const float* src; unsigned short *dh, *dl; int K, N, nt, kt;
    if (bid < 5920){
        const int plane = bid / 296, rem = bid % 296;
        const int s = plane & 1, layer = plane >> 1;
        src = (s ? winG : winS) + (size_t)layer*DM*DPROJ;
        dh = winh + (size_t)plane*DPROJ*DM;
        dl = winl + (size_t)plane*DPROJ*DM;
        K = DM; N = DPROJ;
        nt = (rem % 37)*64; kt = (rem / 37)*64;
    } else if (bid < 8480){
        const int i = bid - 5920;
        const int plane = i / 128, rem = i % 128;
        const int s = plane & 1, layer = plane >> 1;
        src = (s ? woutG : woutS) + (size_t)layer*DIN*DM;
        dh = wouth + (size_t)plane*DM*DIN;
        dl = woutl + (size_t)plane*DM*DIN;
        K = DIN; N = DM;
        nt = (rem % 8)*64; kt = (rem / 8)*64;
    } else {
        int e = bid - 8480;
        CvtE j;
        if (e < e0.nblk){ j = e0; }
        else if (e < e0.nblk + e1.nblk){ j = e1; e -= e0.nblk; }
        else if (e < e0.nblk + e1.nblk + e2.nblk){ j = e2; e -= e0.nblk + e1.nblk; }
        else { j = e3; e -= e0.nblk + e1.nblk + e2.nblk; }
        const int i4 = (e*256 + tid)*4;
        const float4 v = *(const float4*)(j.src + i4);
        const float f[4] = {v.x,v.y,v.z,v.w};
        short4_ h4, l4;
        #pragma unroll
        for (int q=0;q<4;q++){
            const unsigned short h = f2bh(f[q]);
            h4[q] = (short)h;
            l4[q] = (short)f2bh(f[q] - bh2f(h));
        }
        *(short4_*)(j.h + i4) = h4;
        *(short4_*)(j.l + i4) = l4;
        return;
    }

    // transpose path: stage [K-tile][N-tile] f32 -> LDS, emit [N][K] bf16 hi/lo
    #pragma unroll
    for (int i=0;i<4;i++){
        const int kk = (tid>>4) + i*16;
        const int c4 = (tid&15)*4;
        const int n = nt + c4;
        float4 v = {0.f,0.f,0.f,0.f};
        if (n + 3 < N) v = *(const float4*)(src + (size_t)(kt+kk)*N + n);
        else {
            if (n   < N) v.x = src[(size_t)(kt+kk)*N + n];
            if (n+1 < N) v.y = src[(size_t)(kt+kk)*N + n+1];
            if (n+2 < N) v.z = src[(size_t)(kt+kk)*N + n+2];
            if (n+3 < N) v.w = src[(size_t)(kt+kk)*N + n+3];
        }
        tile[kk][c4]=v.x; tile[kk][c4+1]=v.y; tile[kk][c4+2]=v.z; tile[kk][c4+3]=v.w;
    }
    __syncthreads();
    #pragma unroll
    for (int i=0;i<2;i++){
        const int c = tid + i*256;
        const int n = c >> 3, k8 = (c & 7)*8;
        if (nt + n < N){
            short8 vh_, vl_;
            #pragma unroll
            for (int q=0;q<8;q++){
                const float f = tile[k8+q][n];
                const unsigned short h = f2bh(f);
                vh_[q] = (short)h;
                vl_[q] = (short)f2bh(f - bh2f(h));
            }
            *(short8*)(dh + (size_t)(nt+n)*K + kt + k8) = vh_;
            *(short8*)(dl + (size_t)(nt+n)*K + kt + k8) = vl_;
        }
    }
}

// ---------------- split-K MFMA GEMM, pre-split bf16 operands ----------------
struct GemmJob {
    const unsigned short* Ah; const unsigned short* Al;
    const unsigned short* Wh; const unsigned short* Wl;
    float* part; int M;
};

template<int NSPLIT>
__global__ __launch_bounds__(256) void gemm_mfma(GemmJob j0, GemmJob j1, GemmJob j2, int N, int K)
{
    const int z = blockIdx.z;
    const int job = z / NSPLIT, split = z % NSPLIT;
    GemmJob jb = (job==0) ? j0 : (job==1 ? j1 : j2);
    const int bm = blockIdx.y*64, bn = blockIdx.x*64;
    const int M = jb.M;
    if (bm >= M) return;

    constexpr int SR = 40;
    __shared__ unsigned short AhS[2][64*SR], AlS[2][64*SR];
    __shared__ unsigned short BhS[2][64*SR], BlS[2][64*SR];

    const int tid = threadIdx.x;
    const int r0 = tid >> 2, k0off = (tid & 3)*8;
    const bool aok = (bm + r0 < M);
    const bool wok = (bn + r0 < N);
    const unsigned short* Aph = jb.Ah + (size_t)(bm+r0)*K;
    const unsigned short* Apl = jb.Al + (size_t)(bm+r0)*K;
    const unsigned short* Wph = jb.Wh + (size_t)(bn+r0)*K;
    const unsigned short* Wpl = jb.Wl + (size_t)(bn+r0)*K;

    const short8 z8 = {0,0,0,0,0,0,0,0};
    short8 ra_h = z8, ra_l = z8, rw_h = z8, rw_l = z8;

    auto loadT = [&](int k0){
        if (aok){
            ra_h = *(const short8*)(Aph + k0 + k0off);
            ra_l = *(const short8*)(Apl + k0 + k0off);
        } else { ra_h = z8; ra_l = z8; }
        if (wok){
            rw_h = *(const short8*)(Wph + k0 + k0off);
            rw_l = *(const short8*)(Wpl + k0 + k0off);
        } else { rw_h = z8; rw_l = z8; }
    };
    auto storeT = [&](int buf){
        *(short8*)&AhS[buf][r0*SR + k0off] = ra_h;
        *(short8*)&AlS[buf][r0*SR + k0off] = ra_l;
        *(short8*)&BhS[buf][r0*SR + k0off] = rw_h;
        *(short8*)&BlS[buf][r0*SR + k0off] = rw_l;
    };

    const int Kper = K / NSPLIT;
    const int koff = split * Kper;
    const int nk = Kper / 32;

    const int l = tid & 63, w = tid >> 6;
    const int fr = l & 15, kg = (l >> 4)*8;

    f32x4 acc0 = {0.f,0.f,0.f,0.f};
    f32x4 acc1 = {0.f,0.f,0.f,0.f};
    f32x4 acc2 = {0.f,0.f,0.f,0.f};
    f32x4 acc3 = {0.f,0.f,0.f,0.f};

    loadT(koff);
    storeT(0);
    __syncthreads();
    for (int t=0; t<nk; ++t){
        const int cur = t & 1;
        if (t+1 < nk) loadT(koff + (t+1)*32);

        const short8 ah = *(const short8*)&AhS[cur][(w*16+fr)*SR + kg];
        const short8 al = *(const short8*)&AlS[cur][(w*16+fr)*SR + kg];
        {
            const short8 bh = *(const short8*)&BhS[cur][(fr)*SR + kg];
            const short8 bl = *(const short8*)&BlS[cur][(fr)*SR + kg];
            acc0 = __builtin_amdgcn_mfma_f32_16x16x32_bf16(ah, bh, acc0, 0,0,0);
            acc0 = __builtin_amdgcn_mfma_f32_16x16x32_bf16(ah, bl, acc0, 0,0,0);
            acc0 = __builtin_amdgcn_mfma_f32_16x16x32_bf16(al, bh, acc0, 0,0,0);
        }
        {
            const short8 bh = *(const short8*)&BhS[cur][(16+fr)*SR + kg];
            const short8 bl = *(const short8*)&BlS[cur][(16+fr)*SR + kg];
            acc1 = __builtin_amdgcn_mfma_f32_16x16x32_bf16(ah, bh, acc1, 0,0,0);
            acc1 = __builtin_amdgcn_mfma_f32_16x16x32_bf16(ah, bl, acc1, 0,0,0);
            acc1 = __builtin_amdgcn_mfma_f32_16x16x32_bf16(al, bh, acc1, 0,0,0);
        }
        {
            const short8 bh = *(const short8*)&BhS[cur][(32+fr)*SR + kg];
            const short8 bl = *(const short8*)&BlS[cur][(32+fr)*SR + kg];
            acc2 = __builtin_amdgcn_mfma_f32_16x16x32_bf16(ah, bh, acc2, 0,0,0);
            acc2 = __builtin_amdgcn_mfma_f32_16x16x32_bf16(ah, bl, acc2, 0,0,0);
            acc2 = __builtin_amdgcn_mfma_f32_16x16x32_bf16(al, bh, acc2, 0,0,0);
        }
        {
            const short8 bh = *(const short8*)&BhS[cur][(48+fr)*SR + kg];
            const short8 bl = *(const short8*)&BlS[cur][(48+fr)*SR + kg];
            acc3 = __builtin_amdgcn_mfma_f32_16x16x32_bf16(ah, bh, acc3, 0,0,0);
            acc3 = __builtin_amdgcn_mfma_f32_16x16x32_bf16(ah, bl, acc3, 0,0,0);
            acc3 = __builtin_amdgcn_mfma_f32_16x16x32_bf16(al, bh, acc3, 0,0,0);
        }
        if (t+1 < nk) storeT(cur^1);
        __syncthreads();
    }

    // C/D layout (m89-verified): col = lane&15, row = (lane>>4)*4 + reg
    float* __restrict__ P = jb.part + (size_t)split*M*N;
    const int rbase = bm + w*16 + (l>>4)*4;
    #pragma unroll
    for (int nt=0; nt<4; ++nt){
        const f32x4 a = (nt==0)?acc0 : (nt==1)?acc1 : (nt==2)?acc2 : acc3;
        const int n = bn + nt*16 + fr;
        if (n < N){
            #pragma unroll
            for (int j=0;j<4;j++){
                const int m = rbase + j;
                if (m < M) P[(size_t)m*N + n] = a[j];
            }
        }
    }
}

// ---------------- reduce partials (+bias, +res, +optional bf16 planes) ----------------
struct RJob { const float* part; const float* bias; const float* res; float* C;
              unsigned short* ph; unsigned short* pl; int M; };

template<int NS>
__global__ __launch_bounds__(256) void reduce_k(RJob j0, RJob j1, int N)
{
    RJob j = blockIdx.y ? j1 : j0;
    const size_t total = (size_t)j.M*N;
    const size_t i4 = ((size_t)blockIdx.x*256 + threadIdx.x)*4;
    if (i4 >= total) return;
    float4 s = *(const float4*)(j.part + i4);
    #pragma unroll
    for (int t=1;t<NS;t++){
        const float4 v = *(const float4*)(j.part + (size_t)t*total + i4);
        s.x+=v.x; s.y+=v.y; s.z+=v.z; s.w+=v.w;
    }
    const int n = (int)(i4 % (size_t)N);
    if (j.bias){ s.x+=j.bias[n]; s.y+=j.bias[n+1]; s.z+=j.bias[n+2]; s.w+=j.bias[n+3]; }
    if (j.res){ const float4 r = *(const float4*)(j.res + i4); s.x+=r.x; s.y+=r.y; s.z+=r.z; s.w+=r.w; }
    if (j.C) *(float4*)(j.C + i4) = s;
    if (j.ph){
        const float f[4] = {s.x, s.y, s.z, s.w};
        short4_ h4, l4;
        #pragma unroll
        for (int q=0;q<4;q++){
            const unsigned short h = f2bh(f[q]);
            h4[q] = (short)h;
            l4[q] = (short)f2bh(f[q] - bh2f(h));
        }
        *(short4_*)(j.ph + i4) = h4;
        *(short4_*)(j.pl + i4) = l4;
    }
}

// ---------------- mamba prep: reduce 2 partials + conv + silu + softplus ----------------
struct PrepJob {
    const float* part;     // [SP_IN][R][DPROJ]
    float* zsilu; float* xh; float* Bc; float* Cc; float* dtw;
    const float* cw; const float* cb; const float* dtb;
    int R, L;
};

__device__ __forceinline__ float4 psum2(const float* p, size_t pstr){
    float4 a = *(const float4*)p;
    const float4 b = *(const float4*)(p + pstr);
    a.x += b.x; a.y += b.y; a.z += b.z; a.w += b.w;
    return a;
}

__global__ __launch_bounds__(256) void mamba_prep(PrepJob js, PrepJob jg)
{
    PrepJob j = blockIdx.y ? jg : js;
    const int R = j.R, L = j.L;
    constexpr int QPR = 580;   // 256 (z) + 320 (conv) + 4 (dt) quads per row
    const int q = blockIdx.x*256 + threadIdx.x;
    if (q >= R*QPR) return;
    const int r = q / QPR, qi = q % QPR;
    const int l = r % L;
    const size_t pstr = (size_t)R*DPROJ;
    const float* base = j.part + (size_t)r*DPROJ;

    if (qi < 256) {                 // ---- z region -> silu(z)
        const int c = qi*4;
        float4 s = psum2(base + c, pstr);
        s.x = siluf(s.x); s.y = siluf(s.y); s.z = siluf(s.z); s.w = siluf(s.w);
        *(float4*)(j.zsilu + (size_t)r*1024 + c) = s;
    } else if (qi < 576) {          // ---- conv region
        const int cc = (qi-256)*4;  // 0..1276
        float tk[4][4];
        #pragma unroll
        for (int k=0;k<4;k++){
            const int lr = l - 3 + k;
            if (lr >= 0){
                float4 v = psum2(j.part + (size_t)(r-3+k)*DPROJ + 1024 + cc, pstr);
                tk[k][0]=v.x; tk[k][1]=v.y; tk[k][2]=v.z; tk[k][3]=v.w;
            } else {
                tk[k][0]=0.f; tk[k][1]=0.f; tk[k][2]=0.f; tk[k][3]=0.f;
            }
        }
        const float4 cb4 = *(const float4*)(j.cb + cc);
        const float cba[4] = {cb4.x, cb4.y, cb4.z, cb4.w};
        float out[4];
        #pragma unroll
        for (int jj=0;jj<4;jj++){
            const float4 wv = *(const float4*)(j.cw + (size_t)(cc+jj)*4);
            float v = cba[jj] + wv.x*tk[0][jj] + wv.y*tk[1][jj]
                              + wv.z*tk[2][jj] + wv.w*tk[3][jj];
            out[jj] = siluf(v);
        }
        float4 o4; o4.x=out[0]; o4.y=out[1]; o4.z=out[2]; o4.w=out[3];
        if (cc < 1024)       *(float4*)(j.xh + (size_t)r*1024 + cc)        = o4;
        else if (cc < 1152)  *(float4*)(j.Bc + (size_t)r*128 + (cc-1024))  = o4;
        else                 *(float4*)(j.Cc + (size_t)r*128 + (cc-1152))  = o4;
    } else {                        // ---- dt region
        const int hd = (qi-576)*4;  // 0,4,8,12
        float4 s = psum2(base + 2304 + hd, pstr);
        const float4 b4 = *(const float4*)(j.dtb + hd);
        float raw[4] = {s.x+b4.x, s.y+b4.y, s.z+b4.z, s.w+b4.w};
        float4 o4;
        float* op = &o4.x;
        #pragma unroll
        for (int jj=0;jj<4;jj++)
            op[jj] = (raw[jj] > 20.f) ? raw[jj] : log1pf(expf(raw[jj]));
        *(float4*)(j.dtw + (size_t)r*16 + hd) = o4;
    }
}

// ---------------- CBT = C @ B^T per (batch, stack) — head-independent ----------------
__global__ __launch_bounds__(256) void mamba_cbt(
    const float* __restrict__ Bc_s, const float* __restrict__ Cc_s, float* __restrict__ cbt_s,
    const float* __restrict__ Bc_g, const float* __restrict__ Cc_g, float* __restrict__ cbt_g)
{
    const int b = blockIdx.x, st = blockIdx.y;
    const float* Bc = st ? Bc_g : Bc_s;
    const float* Cc = st ? Cc_g : Cc_s;
    float* cbt = st ? cbt_g : cbt_s;
    const int L = st ? LG : LS;
    constexpr int SB = 132;
    __shared__ float Bm[64*SB], Cm[64*SB];
    const int t = threadIdx.x;
    for (int idx = t; idx < L*32; idx += 256){
        const int l = idx >> 5, c4 = (idx & 31)*4;
        *(float4*)&Bm[l*SB + c4] = *(const float4*)(Bc + (size_t)(b*L+l)*128 + c4);
        *(float4*)&Cm[l*SB + c4] = *(const float4*)(Cc + (size_t)(b*L+l)*128 + c4);
    }
    __syncthreads();
    const int ti = t >> 4, tj = t & 15;
    float acc[4][4] = {};
    for (int k0=0;k0<128;k0+=4){
        float4 cr[4], br[4];
        #pragma unroll
        for (int a=0;a<4;a++) cr[a] = *(const float4*)&Cm[(ti+16*a)*SB + k0];
        #pragma unroll
        for (int qq=0;qq<4;qq++) br[qq] = *(const float4*)&Bm[(tj+16*qq)*SB + k0];
        #pragma unroll
        for (int a=0;a<4;a++)
            #pragma unroll
            for (int qq=0;qq<4;qq++)
                acc[a][qq] += cr[a].x*br[qq].x + cr[a].y*br[qq].y
                            + cr[a].z*br[qq].z + cr[a].w*br[qq].w;
    }
    #pragma unroll
    for (int a=0;a<4;a++){
        const int i = ti + 16*a;
        if (i < L){
            #pragma unroll
            for (int qq=0;qq<4;qq++){
                const int jj = tj + 16*qq;
                if (jj < L) cbt[(size_t)b*3840 + i*60 + jj] = acc[a][qq];
            }
        }
    }
}

// ---------------- Y = (decay .* CBT) @ X + D*X per (head, batch, stack) ----------------
__global__ __launch_bounds__(256) void mamba_y(
    const float* __restrict__ cbt_s, const float* __restrict__ xh_s, const float* __restrict__ dtw_s,
    const float* __restrict__ al_s, const float* __restrict__ Dw_s, float* __restrict__ y_s,
    const float* __restrict__ cbt_g, const float* __restrict__ xh_g, const float* __restrict__ dtw_g,
    const float* __restrict__ al_g, const float* __restrict__ Dw_g, float* __restrict__ y_g)
{
    const int h = blockIdx.x, b = blockIdx.y, st = blockIdx.z;
    const float* cbt = st ? cbt_g : cbt_s;
    const float* xh  = st ? xh_g  : xh_s;
    const float* dtw = st ? dtw_g : dtw_s;
    const float* al  = st ? al_g  : al_s;
    const float* Dw  = st ? Dw_g  : Dw_s;
    float* y = st ? y_g : y_s;
    const int L = st ? LG : LS;

    const int t = threadIdx.x;
    constexpr int SG = 60, SX = 68;
    __shared__ float Gm[64*SG], Xm[64*SX];
    __shared__ float dts[64], sps[64];

    const float Ah = -expf(al[h]);
    const float Dh = Dw[h];

    if (t < 64){
        float dtv = (t < L) ? dtw[(size_t)(b*L+t)*16 + h] : 0.f;
        float s = dtv;
        #pragma unroll
        for (int d=1; d<64; d<<=1){
            float o = __shfl_up(s, d, 64);
            if (t >= d) s += o;
        }
        dts[t] = dtv; sps[t] = s;
    }
    for (int idx = t; idx < L*16; idx += 256){
        const int l = idx >> 4, c4 = (idx & 15)*4;
        *(float4*)&Xm[l*SX + c4] = *(const float4*)(xh + (size_t)(b*L+l)*1024 + h*64 + c4);
    }
    __syncthreads();

    for (int idx = t; idx < L*15; idx += 256){
        const int i = idx/15, j4 = (idx%15)*4;
        const float4 v = *(const float4*)(cbt + (size_t)b*3840 + i*60 + j4);
        const float va[4] = {v.x, v.y, v.z, v.w};
        float g[4];
        const float si = sps[i];
        #pragma unroll
        for (int jj=0;jj<4;jj++){
            const int jc = j4 + jj;
            float gg = 0.f;
            if (jc <= i && jc < L)
                gg = expf(Ah*(si - sps[jc])) * dts[jc] * va[jj];
            g[jj] = gg;
        }
        float4 g4; g4.x=g[0]; g4.y=g[1]; g4.z=g[2]; g4.w=g[3];
        *(float4*)&Gm[i*SG + j4] = g4;
    }
    __syncthreads();

    const int ti = t >> 4, tj = t & 15;
    int la[4];
    #pragma unroll
    for (int a=0;a<4;a++) la[a] = ti + 16*a;
    float accY[4][4] = {};
    for (int m=0; m<L; ++m){
        float xr[4], gr[4];
        #pragma unroll
        for (int qq=0;qq<4;qq++) xr[qq] = Xm[m*SX + tj + 16*qq];
        #pragma unroll
        for (int a=0;a<4;a++) gr[a] = (la[a] < L) ? Gm[la[a]*SG + m] : 0.f;
        #pragma unroll
        for (int a=0;a<4;a++)
            #pragma unroll
            for (int qq=0;qq<4;qq++) accY[a][qq] = fmaf(gr[a], xr[qq], accY[a][qq]);
    }
    #pragma unroll
    for (int a=0;a<4;a++){
        if (la[a] < L){
            float* yrow = y + (size_t)(b*L + la[a])*DIN + h*HD;
            #pragma unroll
            for (int qq=0;qq<4;qq++){
                const int col = tj + 16*qq;
                yrow[col] = accY[a][qq] + Dh * Xm[la[a]*SX + col];
            }
        }
    }
}

// ---------------- gated RMSNorm -> bf16 planes only ----------------
__global__ __launch_bounds__(256) void gated_rmsnorm(
    const float* __restrict__ y_s, const float* __restrict__ zs_s, const float* __restrict__ nw_s,
    unsigned short* __restrict__ oh_s, unsigned short* __restrict__ ol_s,
    const float* __restrict__ y_g, const float* __restrict__ zs_g, const float* __restrict__ nw_g,
    unsigned short* __restrict__ oh_g, unsigned short* __restrict__ ol_g)
{
    int r = blockIdx.x, t = threadIdx.x;
    int st = (r >= RS);
    int row = st ? r - RS : r;
    const float* y  = (st ? y_g  : y_s) + (size_t)row*DIN;
    const float* zs = (st ? zs_g : zs_s) + (size_t)row*DIN;
    const float* nw = st ? nw_g : nw_s;
    unsigned short* oh = (st ? oh_g : oh_s) + (size_t)row*DIN;
    unsigned short* ol = (st ? ol_g : ol_s) + (size_t)row*DIN;

    float g[4]; float s2 = 0.f;
    #pragma unroll
    for (int i=0;i<4;i++){
        int idx = t + i*256;
        float gv = y[idx] * zs[idx];
        g[i] = gv; s2 += gv*gv;
    }
    #pragma unroll
    for (int o2=32;o2;o2>>=1) s2 += __shfl_xor(s2, o2, 64);
    __shared__ float red[4];
    if ((t & 63) == 0) red[t>>6] = s2;
    __syncthreads();
    float S2 = red[0]+red[1]+red[2]+red[3];
    float scale = rsqrtf(S2*(1.f/DIN) + 1e-5f);
    #pragma unroll
    for (int i=0;i<4;i++){
        int idx = t + i*256;
        const float val = g[i]*scale*nw[idx];
        const unsigned short h = f2bh(val);
        oh[idx] = h;
        ol[idx] = f2bh(val - bh2f(h));
    }
}

// ---------------- LayerNorm rows -> bf16 planes ----------------
__global__ __launch_bounds__(256) void ln_rows(
    const float* __restrict__ x, const float* __restrict__ w, const float* __restrict__ b,
    unsigned short* __restrict__ outh, unsigned short* __restrict__ outl, int D)
{
    int r = blockIdx.x, t = threadIdx.x;
    const float* xr = x + (size_t)r*D;
    float s = 0.f, s2 = 0.f;
    for (int i=t;i<D;i+=256){ float v = xr[i]; s += v; s2 += v*v; }
    #pragma unroll
    for (int o=32;o;o>>=1){ s += __shfl_xor(s,o,64); s2 += __shfl_xor(s2,o,64); }
    __shared__ float red[8];
    if ((t & 63) == 0){ red[t>>6] = s; red[4+(t>>6)] = s2; }
    __syncthreads();
    float S  = red[0]+red[1]+red[2]+red[3];
    float S2 = red[4]+red[5]+red[6]+red[7];
    float mean = S/D;
    float var  = S2/D - mean*mean;
    float inv  = rsqrtf(var + 1e-5f);
    for (int i=t;i<D;i+=256){
        const float val = (xr[i]-mean)*inv*w[i] + b[i];
        const unsigned short h = f2bh(val);
        outh[(size_t)r*D + i] = h;
        outl[(size_t)r*D + i] = f2bh(val - bh2f(h));
    }
}

// ---------------- cross-attention core: split-K partials + bias in, bf16 planes out ----------------
template<int LQ, int LKV, int NS>
__global__ __launch_bounds__(256) void mha_attn2(
    const float* __restrict__ pq, const float* __restrict__ pk, const float* __restrict__ pv,
    const float* __restrict__ qb, const float* __restrict__ kb, const float* __restrict__ vb,
    int Mq, int Mkv,
    unsigned short* __restrict__ outh, unsigned short* __restrict__ outl)
{
    const int hh = blockIdx.x, b = blockIdx.y, t = threadIdx.x;
    const size_t strQ = (size_t)Mq*DM, strKV = (size_t)Mkv*DM;
    constexpr int SD = 68;
    constexpr int SS = 60;
    constexpr int QT = (LQ +15)/16;
    constexpr int KT = (LKV+15)/16;
    __shared__ float Qs[LQ*SD];
    __shared__ float Ks[LKV*SD];
    __shared__ float Vs[LKV*SD];
    __shared__ float Ps[LQ*SS];

    for (int idx = t; idx < LQ*16; idx += 256){
        const int r = idx>>4, c4 = (idx&15)*4;
        float4 v = *(const float4*)(qb + hh*64 + c4);
        const size_t off = (size_t)(b*LQ+r)*DM + hh*64 + c4;
        #pragma unroll
        for (int s=0;s<NS;s++){
            const float4 u = *(const float4*)(pq + s*strQ + off);
            v.x+=u.x; v.y+=u.y; v.z+=u.z; v.w+=u.w;
        }
        *(float4*)&Qs[r*SD+c4] = v;
    }
    for (int idx = t; idx < LKV*16; idx += 256){
        const int r = idx>>4, c4 = (idx&15)*4;
        float4 kv = *(const float4*)(kb + hh*64 + c4);
        float4 vv = *(const float4*)(vb + hh*64 + c4);
        const size_t off = (size_t)(b*LKV+r)*DM + hh*64 + c4;
        #pragma unroll
        for (int s=0;s<NS;s++){
            const float4 ku = *(const float4*)(pk + s*strKV + off);
            const float4 vu = *(const float4*)(pv + s*strKV + off);
            kv.x+=ku.x; kv.y+=ku.y; kv.z+=ku.z; kv.w+=ku.w;
            vv.x+=vu.x; vv.y+=vu.y; vv.z+=vu.z; vv.w+=vu.w;
        }
        *(float4*)&Ks[r*SD+c4] = kv;
        *(float4*)&Vs[r*SD+c4] = vv;
    }
    __syncthreads();

    const int ti = t>>4, tj = t&15;

    {
        float acc[QT][KT];
        #pragma unroll
        for (int a=0;a<QT;a++)
            #pragma unroll
            for (int q=0;q<KT;q++) acc[a][q] = 0.f;
        for (int k0=0;k0<64;k0+=4){
            float4 qr[QT], kr[KT];
            #pragma unroll
            for (int a=0;a<QT;a++){
                int rr = ti+16*a; if (rr >= LQ) rr = LQ-1;
                qr[a] = *(const float4*)&Qs[rr*SD+k0];
            }
            #pragma unroll
            for (int q=0;q<KT;q++){
                int rr = tj+16*q; if (rr >= LKV) rr = LKV-1;
                kr[q] = *(const float4*)&Ks[rr*SD+k0];
            }
            #pragma unroll
            for (int a=0;a<QT;a++)
                #pragma unroll
                for (int q=0;q<KT;q++)
                    acc[a][q] += qr[a].x*kr[q].x + qr[a].y*kr[q].y
                               + qr[a].z*kr[q].z + qr[a].w*kr[q].w;
        }
        #pragma unroll
        for (int a=0;a<QT;a++){
            const int i = ti+16*a;
            if (i < LQ){
                #pragma unroll
                for (int q=0;q<KT;q++){
                    const int jj = tj+16*q;
                    if (jj < LKV) Ps[i*SS+jj] = acc[a][q]*0.125f;
                }
            }
        }
    }
    __syncthreads();

    if (t < LQ){
        float mx = -1e30f;
        for (int j=0;j<LKV;j++) mx = fmaxf(mx, Ps[t*SS+j]);
        float se = 0.f;
        for (int j=0;j<LKV;j++){ float e = expf(Ps[t*SS+j]-mx); Ps[t*SS+j] = e; se += e; }
        const float inv = 1.f/se;
        for (int j=0;j<LKV;j++) Ps[t*SS+j] *= inv;
    }
    __syncthreads();

    {
        float o[QT][4];
        #pragma unroll
        for (int a=0;a<QT;a++){ o[a][0]=0.f; o[a][1]=0.f; o[a][2]=0.f; o[a][3]=0.f; }
        for (int m=0;m<LKV;m++){
            const float4 vv = *(const float4*)&Vs[m*SD + tj*4];
            #pragma unroll
            for (int a=0;a<QT;a++){
                const int rr = ti+16*a;
                const float pv2 = (rr < LQ) ? Ps[rr*SS+m] : 0.f;
                o[a][0] = fmaf(pv2, vv.x, o[a][0]);
                o[a][1] = fmaf(pv2, vv.y, o[a][1]);
                o[a][2] = fmaf(pv2, vv.z, o[a][2]);
                o[a][3] = fmaf(pv2, vv.w, o[a][3]);
            }
        }
        #pragma unroll
        for (int a=0;a<QT;a++){
            const int rr = ti+16*a;
            if (rr < LQ){
                short4_ h4, l4;
                #pragma unroll
                for (int q=0;q<4;q++){
                    const unsigned short h = f2bh(o[a][q]);
                    h4[q] = (short)h;
                    l4[q] = (short)f2bh(o[a][q] - bh2f(h));
                }
                const size_t off = (size_t)(b*LQ+rr)*DM + hh*64 + tj*4;
                *(short4_*)(outh + off) = h4;
                *(short4_*)(outl + off) = l4;
            }
        }
    }
}

// ---------------- fused head: meanpool + LN + classifier ----------------
__global__ __launch_bounds__(512) void head_fused(
    const float* __restrict__ xs, const float* __restrict__ xg,
    const float* __restrict__ lw, const float* __restrict__ lb,
    const float* __restrict__ cw, const float* __restrict__ cb,
    float* __restrict__ out)
{
    const int b = blockIdx.x, t = threadIdx.x;
    __shared__ float fr[1024];
    __shared__ float red[16];
    __shared__ float pr[55*8];
    {
        float s = 0.f;
        for (int l=0;l<LS;l++) s += xs[(size_t)(b*LS+l)*DM + t];
        fr[t] = s*(1.f/LS);
        float g = 0.f;
        for (int l=0;l<LG;l++) g += xg[(size_t)(b*LG+l)*DM + t];
        fr[512+t] = g*(1.f/LG);
    }
    __syncthreads();
    float v0 = fr[t], v1 = fr[512+t];
    float sm = v0+v1, sq = v0*v0 + v1*v1;
    #pragma unroll
    for (int o=32;o;o>>=1){ sm += __shfl_xor(sm,o,64); sq += __shfl_xor(sq,o,64); }
    if ((t&63)==0){ red[t>>6] = sm; red[8+(t>>6)] = sq; }
    __syncthreads();
    float S=0.f, Q=0.f;
    #pragma unroll
    for (int i=0;i<8;i++){ S += red[i]; Q += red[8+i]; }
    const float mean = S*(1.f/1024.f);
    const float var  = Q*(1.f/1024.f) - mean*mean;
    const float inv  = rsqrtf(var + 1e-5f);
    fr[t]     = (v0-mean)*inv*lw[t]     + lb[t];
    fr[512+t] = (v1-mean)*inv*lw[512+t] + lb[512+t];
    __syncthreads();
    {
        const int c = t & 63, pp = t >> 6;
        if (c < 55){
            float a = 0.f;
            const float* wr = cw + (size_t)c*1024 + pp*128;
            const float* xr = fr + pp*128;
            #pragma unroll 4
            for (int k=0;k<128;k++) a = fmaf(xr[k], wr[k], a);
            pr[c*8+pp] = a;
        }
    }
    __syncthreads();
    if (t < 55){
        float a = cb[t];
        #pragma unroll
        for (int p2=0;p2<8;p2++) a += pr[t*8+p2];
        out[b*55 + t] = a;
    }
}

// ---------------- launch ----------------
extern "C" void kernel_launch(void* const* d_in, const int* in_sizes, int n_in,
                              void* d_out, int out_size, void* d_ws, size_t ws_size,
                              hipStream_t stream)
{
    (void)in_sizes; (void)n_in; (void)out_size; (void)ws_size;
    const float* x_spectra = (const float*)d_in[0];
    const float* x_gaia    = (const float*)d_in[1];
    const float* tok_w_s   = (const float*)d_in[2];
    const float* tok_b_s   = (const float*)d_in[3];
    const float* tok_w_g   = (const float*)d_in[4];
    const float* tok_b_g   = (const float*)d_in[5];
    const float* ms_Win    = (const float*)d_in[6];
    const float* ms_conv_w = (const float*)d_in[7];
    const float* ms_conv_b = (const float*)d_in[8];
    const float* ms_dtb    = (const float*)d_in[9];
    const float* ms_Alog   = (const float*)d_in[10];
    const float* ms_D      = (const float*)d_in[11];
    const float* ms_nw     = (const float*)d_in[12];
    const float* ms_Wout   = (const float*)d_in[13];
    const float* mg_Win    = (const float*)d_in[14];
    const float* mg_conv_w = (const float*)d_in[15];
    const float* mg_conv_b = (const float*)d_in[16];
    const float* mg_dtb    = (const float*)d_in[17];
    const float* mg_Alog   = (const float*)d_in[18];
    const float* mg_D      = (const float*)d_in[19];
    const float* mg_nw     = (const float*)d_in[20];
    const float* mg_Wout   = (const float*)d_in[21];
    const float* cas_ln_w  = (const float*)d_in[22];
    const float* cas_ln_b  = (const float*)d_in[23];
    const float* cas_in_w  = (const float*)d_in[24];
    const float* cas_in_b  = (const float*)d_in[25];
    const float* cas_out_w = (const float*)d_in[26];
    const float* cas_out_b = (const float*)d_in[27];
    const float* cag_ln_w  = (const float*)d_in[28];
    const float* cag_ln_b  = (const float*)d_in[29];
    const float* cag_in_w  = (const float*)d_in[30];
    const float* cag_in_b  = (const float*)d_in[31];
    const float* cag_out_w = (const float*)d_in[32];
    const float* cag_out_b = (const float*)d_in[33];
    const float* cls_ln_w  = (const float*)d_in[34];
    const float* cls_ln_b  = (const float*)d_in[35];
    const float* cls_w     = (const float*)d_in[36];
    const float* cls_b     = (const float*)d_in[37];

    float* p = (float*)d_ws;
    auto alloc = [&](size_t n){ float* r = p; p += n; return r; };
    float* xs       = alloc((size_t)RS*DM);
    float* xg       = alloc((size_t)RG*DM);
    float* y_s      = alloc((size_t)RS*DIN);
    float* y_g      = alloc((size_t)RG*DIN);
    float* part_inS  = alloc((size_t)SP_IN*RS*DPROJ);
    float* part_inG  = alloc((size_t)SP_IN*RG*DPROJ);
    float* part_outS = alloc((size_t)SP_OUT*RS*DM);
    float* part_outG = alloc((size_t)SP_OUT*RG*DM);
    float* part_q    = alloc((size_t)SP_ATT*RS*DM);
    float* part_k    = alloc((size_t)SP_ATT*RS*DM);
    float* part_v    = alloc((size_t)SP_ATT*RS*DM);
    float* zsilu_s = alloc((size_t)RS*1024);
    float* zsilu_g = alloc((size_t)RG*1024);
    float* xh_s    = alloc((size_t)RS*1024);
    float* xh_g    = alloc((size_t)RG*1024);
    float* Bc_s    = alloc((size_t)RS*128);
    float* Bc_g    = alloc((size_t)RG*128);
    float* Cc_s    = alloc((size_t)RS*128);
    float* Cc_g    = alloc((size_t)RG*128);
    float* dtw_s   = alloc((size_t)RS*16);
    float* dtw_g   = alloc((size_t)RG*16);
    float* cbt_s   = alloc((size_t)BB*3840);
    float* cbt_g   = alloc((size_t)BB*3840);

    unsigned short* up = (unsigned short*)p;
    auto ualloc = [&](size_t n){ unsigned short* r = up; up += n; return r; };
    unsigned short* xsh   = ualloc((size_t)RS*DM);
    unsigned short* xsl   = ualloc((size_t)RS*DM);
    unsigned short* xgh   = ualloc((size_t)RG*DM);
    unsigned short* xgl   = ualloc((size_t)RG*DM);
    unsigned short* ynh_s = ualloc((size_t)RS*DIN);
    unsigned short* ynl_s = ualloc((size_t)RS*DIN);
    unsigned short* ynh_g = ualloc((size_t)RG*DIN);
    unsigned short* ynl_g = ualloc((size_t)RG*DIN);
    unsigned short* lnh   = ualloc((size_t)RS*DM);
    unsigned short* lnl   = ualloc((size_t)RS*DM);
    unsigned short* aoh   = ualloc((size_t)RS*DM);
    unsigned short* aol   = ualloc((size_t)RS*DM);
    unsigned short* caih  = ualloc((size_t)1536*512);
    unsigned short* cail  = ualloc((size_t)1536*512);
    unsigned short* caoh  = ualloc((size_t)512*512);
    unsigned short* caol  = ualloc((size_t)512*512);
    unsigned short* cgih  = ualloc((size_t)1536*512);
    unsigned short* cgil  = ualloc((size_t)1536*512);
    unsigned short* cgoh  = ualloc((size_t)512*512);
    unsigned short* cgol  = ualloc((size_t)512*512);
    unsigned short* winh  = ualloc((size_t)20*DPROJ*DM);
    unsigned short* winl  = ualloc((size_t)20*DPROJ*DM);
    unsigned short* wouth = ualloc((size_t)20*DM*DIN);
    unsigned short* woutl = ualloc((size_t)20*DM*DIN);

    // one-time weight conversions (single launch, no dead blocks)
    CvtE e0{cas_in_w,  caih, cail, 768};
    CvtE e1{cas_out_w, caoh, caol, 256};
    CvtE e2{cag_in_w,  cgih, cgil, 768};
    CvtE e3{cag_out_w, cgoh, cgol, 256};
    convert_weights<<<dim3(10528), 256, 0, stream>>>(
        ms_Win, mg_Win, ms_Wout, mg_Wout, winh, winl, wouth, woutl, e0, e1, e2, e3);

    // tokenize (both modalities)
    tokenize2<<<dim3(LS, BB, 2), 512, 0, stream>>>(
        x_spectra, tok_w_s, tok_b_s, xs, xsh, xsl,
        x_gaia,    tok_w_g, tok_b_g, xg, xgh, xgl);

    const int rblkS = (RS*DM + 1023)/1024;   // 228
    const int prepBlk = (RS*580 + 255)/256;  // 1034

    // mamba stacks
    for (int i=0;i<NLAY;i++){
        const float* cw_s   = ms_conv_w + (size_t)i*1280*4;
        const float* cw_g   = mg_conv_w + (size_t)i*1280*4;
        const float* cbv_s  = ms_conv_b + (size_t)i*1280;
        const float* cbv_g  = mg_conv_b + (size_t)i*1280;
        const float* dtb_s  = ms_dtb  + (size_t)i*NH;
        const float* dtb_g  = mg_dtb  + (size_t)i*NH;
        const float* al_s   = ms_Alog + (size_t)i*NH;
        const float* al_g   = mg_Alog + (size_t)i*NH;
        const float* Dw_s   = ms_D    + (size_t)i*NH;
        const float* Dw_g   = mg_D    + (size_t)i*NH;
        const float* nw_s   = ms_nw   + (size_t)i*DIN;
        const float* nw_g   = mg_nw   + (size_t)i*DIN;

        const unsigned short* wih_s = winh + (size_t)(2*i+0)*DPROJ*DM;
        const unsigned short* wil_s = winl + (size_t)(2*i+0)*DPROJ*DM;
        const unsigned short* wih_g = winh + (size_t)(2*i+1)*DPROJ*DM;
        const unsigned short* wil_g = winl + (size_t)(2*i+1)*DPROJ*DM;
        const unsigned short* woh_s = wouth + (size_t)(2*i+0)*DM*DIN;
        const unsigned short* wol_s = woutl + (size_t)(2*i+0)*DM*DIN;
        const unsigned short* woh_g = wouth + (size_t)(2*i+1)*DM*DIN;
        const unsigned short* wol_g = woutl + (size_t)(2*i+1)*DM*DIN;

        GemmJob inS{xsh, xsl, wih_s, wil_s, part_inS, RS};
        GemmJob inG{xgh, xgl, wih_g, wil_g, part_inG, RG};
        gemm_mfma<SP_IN><<<dim3(37, 8, 2*SP_IN), 256, 0, stream>>>(inS, inG, inG, DPROJ, DM);

        PrepJob pjS{part_inS, zsilu_s, xh_s, Bc_s, Cc_s, dtw_s, cw_s, cbv_s, dtb_s, RS, LS};
        PrepJob pjG{part_inG, zsilu_g, xh_g, Bc_g, Cc_g, dtw_g, cw_g, cbv_g, dtb_g, RG, LG};
        mamba_prep<<<dim3(prepBlk, 2), 256, 0, stream>>>(pjS, pjG);

        mamba_cbt<<<dim3(BB, 2), 256, 0, stream>>>(Bc_s, Cc_s, cbt_s, Bc_g, Cc_g, cbt_g);

        mamba_y<<<dim3(NH, BB, 2), 256, 0, stream>>>(
            cbt_s, xh_s, dtw_s, al_s, Dw_s, y_s,
            cbt_g, xh_g, dtw_g, al_g, Dw_g, y_g);

        gated_rmsnorm<<<dim3(RS+RG), 256, 0, stream>>>(
            y_s, zsilu_s, nw_s, ynh_s, ynl_s,  y_g, zsilu_g, nw_g, ynh_g, ynl_g);

        GemmJob outS{ynh_s, ynl_s, woh_s, wol_s, part_outS, RS};
        GemmJob outG{ynh_g, ynl_g, woh_g, wol_g, part_outG, RG};
        gemm_mfma<SP_OUT><<<dim3(8, 8, 2*SP_OUT), 256, 0, stream>>>(outS, outG, outG, DM, DIN);

        RJob roS{part_outS, nullptr, nullptr, xs, xsh, xsl, RS};
        RJob roG{part_outG, nullptr, nullptr, xg, xgh, xgl, RG};
        reduce_k<SP_OUT><<<dim3(rblkS, 2), 256, 0, stream>>>(roS, roG, DM);
    }

    // cross-attention: xs = xs + MHA(LN(xs), xg)
    {
        ln_rows<<<dim3(RS), 256, 0, stream>>>(xs, cas_ln_w, cas_ln_b, lnh, lnl, DM);
        GemmJob jq{lnh, lnl, caih,            cail,            part_q, RS};
        GemmJob jk{xgh, xgl, caih +  512*512, cail +  512*512, part_k, RG};
        GemmJob jv{xgh, xgl, caih + 1024*512, cail + 1024*512, part_v, RG};
        gemm_mfma<SP_ATT><<<dim3(8, 8, 3*SP_ATT), 256, 0, stream>>>(jq, jk, jv, DM, DM);
        mha_attn2<LS,LG,SP_ATT><<<dim3(8,BB), 256, 0, stream>>>(
            part_q, part_k, part_v, cas_in_b, cas_in_b+512, cas_in_b+1024, RS, RG, aoh, aol);
        GemmJob jo{aoh, aol, caoh, caol, part_outS, RS};
        gemm_mfma<SP_ATT><<<dim3(8, 8, SP_ATT), 256, 0, stream>>>(jo, jo, jo, DM, DM);
        RJob ro{part_outS, cas_out_b, xs, xs, xsh, xsl, RS};
        reduce_k<SP_ATT><<<dim3(rblkS, 1), 256, 0, stream>>>(ro, ro, DM);
    }

    // cross-attention: xg = xg + MHA(LN(xg), xs_updated)
    {
        ln_rows<<<dim3(RG), 256, 0, stream>>>(xg, cag_ln_w, cag_ln_b, lnh, lnl, DM);
        GemmJob jq{lnh, lnl, cgih,            cgil,            part_q, RG};
        GemmJob jk{xsh, xsl, cgih +  512*512, cgil +  512*512, part_k, RS};
        GemmJob jv{xsh, xsl, cgih + 1024*512, cgil + 1024*512, part_v, RS};
        gemm_mfma<SP_ATT><<<dim3(8, 8, 3*SP_ATT), 256, 0, stream>>>(jq, jk, jv, DM, DM);
        mha_attn2<LG,LS,SP_ATT><<<dim3(8,BB), 256, 0, stream>>>(
            part_q, part_k, part_v, cag_in_b, cag_in_b+512, cag_in_b+1024, RG, RS, aoh, aol);
        GemmJob jo{aoh, aol, cgoh, cgol, part_outS, RG};
        gemm_mfma<SP_ATT><<<dim3(8, 2, SP_ATT), 256, 0, stream>>>(jo, jo, jo, DM, DM);
        RJob ro{part_outS, cag_out_b, xg, xg, nullptr, nullptr, RG};
        reduce_k<SP_ATT><<<dim3((RG*DM+1023)/1024, 1), 256, 0, stream>>>(ro, ro, DM);
    }

    // fused head
    head_fused<<<dim3(BB), 512, 0, stream>>>(xs, xg, cls_ln_w, cls_ln_b, cls_w, cls_b, (float*)d_out);
}

// Round 11
// 733.010 us; speedup vs baseline: 1.9401x; 1.0228x over previous
//
#include <hip/hip_runtime.h>
#include <cmath>

// ---------------- constants ----------------
constexpr int BB    = 8;     // batch
constexpr int LS    = 57;    // spectra tokens
constexpr int LG    = 9;     // gaia tokens
constexpr int RS    = BB*LS; // 456
constexpr int RG    = BB*LG; // 72
constexpr int DM    = 512;   // d_model
constexpr int DPROJ = 2320;
constexpr int DIN   = 1024;
constexpr int NH    = 16;    // mamba heads
constexpr int HD    = 64;    // mamba headdim
constexpr int NLAY  = 10;

constexpr int SP_IN  = 2;    // split-K for in-proj  (K=512  -> 256/split)
constexpr int SP_OUT = 8;    // split-K for out-proj (K=1024 -> 128/split)
constexpr int SP_ATT = 4;    // split-K for attention gemms (K=512 -> 128/split)

// tiled weight geometry: [kt2][nt2][64 n][32 k], 2048 shorts (4KB) per tile
constexpr int NT_IN  = 37;   // in-proj n-tiles (2320 -> padded 2368)
constexpr int NT_OUT = 8;    // out-proj n-tiles (512)
constexpr int NT_ATT = 8;    // attention n-tiles (512)
constexpr size_t WIN_PLANE  = (size_t)16*NT_IN*2048;   // K=512 -> 16 k-tiles
constexpr size_t WOUT_PLANE = (size_t)32*NT_OUT*2048;  // K=1024 -> 32 k-tiles
constexpr size_t ATT_PLANE  = (size_t)16*NT_ATT*2048;  // 512x512

__device__ __forceinline__ float siluf(float x){ return x / (1.f + expf(-x)); }

// ---------------- bf16 split helpers ----------------
typedef short  short8  __attribute__((ext_vector_type(8)));
typedef short  short4_ __attribute__((ext_vector_type(4)));
typedef float  f32x4   __attribute__((ext_vector_type(4)));

__device__ __forceinline__ unsigned short f2bh(float f){
    unsigned int u = __float_as_uint(f);
    u = u + 0x7FFFu + ((u >> 16) & 1u);
    return (unsigned short)(u >> 16);
}
__device__ __forceinline__ float bh2f(unsigned short h){
    return __uint_as_float(((unsigned int)h) << 16);
}

// ---------------- tokenize both modalities (+bf16 planes) ----------------
__global__ __launch_bounds__(512) void tokenize2(
    const float* __restrict__ xS, const float* __restrict__ wS, const float* __restrict__ bS,
    float* __restrict__ oS, unsigned short* __restrict__ oSh, unsigned short* __restrict__ oSl,
    const float* __restrict__ xG, const float* __restrict__ wG, const float* __restrict__ bG,
    float* __restrict__ oG, unsigned short* __restrict__ oGh, unsigned short* __restrict__ oGl)
{
    const int st = blockIdx.z;
    const int tkt = blockIdx.x, b = blockIdx.y, d = threadIdx.x;
    const int ntok = st ? LG : LS;
    if (tkt >= ntok) return;
    const float* x = st ? xG : xS;
    const float* w = st ? wG : wS;
    const float* bias = st ? bG : bS;
    float* out = st ? oG : oS;
    unsigned short* oh = st ? oGh : oSh;
    unsigned short* ol = st ? oGl : oSl;
    const int in_dim = st ? 18 : 3647, tok_dim = st ? 2 : 64;

    __shared__ float xv[64];
    if (d < tok_dim) {
        int idx = tkt*tok_dim + d;
        xv[d] = (idx < in_dim) ? x[(size_t)b*in_dim + idx] : 0.f;
    }
    __syncthreads();
    float acc = bias[d];
    for (int k=0;k<tok_dim;k++) acc += xv[k]*w[(size_t)k*DM + d];
    const size_t o = (size_t)(b*ntok + tkt)*DM + d;
    out[o] = acc;
    const unsigned short h = f2bh(acc);
    oh[o] = h;
    ol[o] = f2bh(acc - bh2f(h));
}

// ---------------- weight conversion -> GEMM-native tiled bf16 hi/lo ----------------
// blocks [0,5920):    Win transpose (20 planes x 8 k64-groups x 37 n-tiles)
// blocks [5920,8480): Wout transpose (20 planes x 16 k64-groups x 8 n-tiles)
// blocks [8480,9504): attention tiled copy (8 planes x 128 tiles, src already [N][K])
__global__ __launch_bounds__(256) void convert_weights(
    const float* __restrict__ winS, const float* __restrict__ winG,
    const float* __restrict__ woutS, const float* __restrict__ woutG,
    const float* __restrict__ cai, const float* __restrict__ cao,
    const float* __restrict__ cgi, const float* __restrict__ cgo,
    unsigned short* __restrict__ winh, unsigned short* __restrict__ winl,
    unsigned short* __restrict__ wouth, unsigned short* __restrict__ woutl,
    unsigned short* __restrict__ atth, unsigned short* __restrict__ attl)
{
    const int tid = threadIdx.x;
    const int bid = blockIdx.x;

    if (bid >= 8480){
        // ---- attention tiled copy (no transpose; src f32 [512][512]) ----
        int e = bid - 8480;
        const int job = e >> 7, rem = e & 127;
        const int kt2 = rem >> 3, nt2 = rem & 7;
        const float* src =
            (job==3) ? cao : (job==7) ? cgo :
            (job< 3) ? cai + (size_t)job*512*512 : cgi + (size_t)(job-4)*512*512;
        const size_t tile = (size_t)job*ATT_PLANE + ((size_t)kt2*NT_ATT + nt2)*2048;
        const int n = tid >> 2, k8 = (tid & 3)*8;
        const float* sp = src + (size_t)(nt2*64 + n)*512 + kt2*32 + k8;
        const float4 v0 = *(const float4*)sp;
        const float4 v1 = *(const float4*)(sp+4);
        const float f[8] = {v0.x,v0.y,v0.z,v0.w,v1.x,v1.y,v1.z,v1.w};
        short8 h8, l8;
        #pragma unroll
        for (int q=0;q<8;q++){
            const unsigned short h = f2bh(f[q]);
            h8[q] = (short)h;
            l8[q] = (short)f2bh(f[q] - bh2f(h));
        }
        *(short8*)(atth + tile + tid*8) = h8;
        *(short8*)(attl + tile + tid*8) = l8;
        return;
    }

    // ---- transpose path ----
    const float* src; unsigned short *dh, *dl; int K, N, NT, nt, ktp;
    if (bid < 5920){
        const int plane = bid / 296, rem = bid % 296;
        const int s = plane & 1, layer = plane >> 1;
        src = (s ? winG : winS) + (size_t)layer*DM*DPROJ;
        dh = winh + (size_t)plane*WIN_PLANE;
        dl = winl + (size_t)plane*WIN_PLANE;
        K = DM; N = DPROJ; NT = NT_IN;
        nt = rem % 37; ktp = rem / 37;      // ktp in [0,8)
    } else {
        const int i = bid - 5920;
        const int plane = i / 128, rem = i % 128;
        const int s = plane & 1, layer = plane >> 1;
        src = (s ? woutG : woutS) + (size_t)layer*DIN*DM;
        dh = wouth + (size_t)plane*WOUT_PLANE;
        dl = woutl + (size_t)plane*WOUT_PLANE;
        K = DIN; N = DM; NT = NT_OUT;
        nt = rem % 8; ktp = rem / 8;        // ktp in [0,16)
    }

    __shared__ float tile[64][66];          // stride 66: 2-way-conflict gather
    #pragma unroll
    for (int i=0;i<4;i++){
        const int kk = (tid>>4) + i*16;
        const int c4 = (tid&15)*4;
        const int n = nt*64 + c4;
        float4 v = {0.f,0.f,0.f,0.f};
        const float* sp = src + (size_t)(ktp*64+kk)*N + n;
        if (n + 3 < N) v = *(const float4*)sp;
        else {
            if (n   < N) v.x = sp[0];
            if (n+1 < N) v.y = sp[1];
            if (n+2 < N) v.z = sp[2];
            if (n+3 < N) v.w = sp[3];
        }
        tile[kk][c4]=v.x; tile[kk][c4+1]=v.y; tile[kk][c4+2]=v.z; tile[kk][c4+3]=v.w;
    }
    __syncthreads();

    const int n_l = tid >> 2, k8 = (tid & 3)*8;
    #pragma unroll
    for (int i=0;i<2;i++){
        const int kt2 = ktp*2 + i;
        short8 h8, l8;
        #pragma unroll
        for (int q=0;q<8;q++){
            const float f = tile[i*32 + k8 + q][n_l];
            const unsigned short h = f2bh(f);
            h8[q] = (short)h;
            l8[q] = (short)f2bh(f - bh2f(h));
        }
        const size_t off = ((size_t)kt2*NT + nt)*2048 + tid*8;
        *(short8*)(dh + off) = h8;
        *(short8*)(dl + off) = l8;
    }
}

// ---------------- split-K MFMA GEMM, pre-split bf16; W in tiled layout ----------------
struct GemmJob {
    const unsigned short* Ah; const unsigned short* Al;   // activations [M][K]
    const unsigned short* Wh; const unsigned short* Wl;   // tiled planes
    float* part; int M;
};

template<int NSPLIT>
__global__ __launch_bounds__(256) void gemm_mfma(GemmJob j0, GemmJob j1, GemmJob j2,
                                                 int N, int K, int NT)
{
    const int z = blockIdx.z;
    const int job = z / NSPLIT, split = z % NSPLIT;
    GemmJob jb = (job==0) ? j0 : (job==1 ? j1 : j2);
    const int bm = blockIdx.y*64, bn64 = blockIdx.x;
    const int M = jb.M;
    if (bm >= M) return;

    constexpr int SR = 40;
    __shared__ unsigned short AhS[2][64*SR], AlS[2][64*SR];
    __shared__ unsigned short BhS[2][64*SR], BlS[2][64*SR];

    const int tid = threadIdx.x;
    const int r0 = tid >> 2, k0off = (tid & 3)*8;
    const bool aok = (bm + r0 < M);
    const unsigned short* Aph = jb.Ah + (size_t)(bm+r0)*K;
    const unsigned short* Apl = jb.Al + (size_t)(bm+r0)*K;

    const int Kper = K / NSPLIT;
    const int koff = split * Kper;
    const int nk = Kper / 32;

    const size_t wbase = ((size_t)(koff >> 5)*NT + bn64)*2048 + (size_t)tid*8;
    const size_t wstep = (size_t)NT*2048;

    const short8 z8 = {0,0,0,0,0,0,0,0};
    short8 ra_h = z8, ra_l = z8, rw_h = z8, rw_l = z8;

    auto loadT = [&](int k0, int tstep){
        if (aok){
            ra_h = *(const short8*)(Aph + k0 + k0off);
            ra_l = *(const short8*)(Apl + k0 + k0off);
        } else { ra_h = z8; ra_l = z8; }
        rw_h = *(const short8*)(jb.Wh + wbase + (size_t)tstep*wstep);
        rw_l = *(const short8*)(jb.Wl + wbase + (size_t)tstep*wstep);
    };
    auto storeT = [&](int buf){
        *(short8*)&AhS[buf][r0*SR + k0off] = ra_h;
        *(short8*)&AlS[buf][r0*SR + k0off] = ra_l;
        *(short8*)&BhS[buf][r0*SR + k0off] = rw_h;
        *(short8*)&BlS[buf][r0*SR + k0off] = rw_l;
    };

    const int l = tid & 63, w = tid >> 6;
    const int fr = l & 15, kg = (l >> 4)*8;

    f32x4 acc0 = {0.f,0.f,0.f,0.f};
    f32x4 acc1 = {0.f,0.f,0.f,0.f};
    f32x4 acc2 = {0.f,0.f,0.f,0.f};
    f32x4 acc3 = {0.f,0.f,0.f,0.f};

    loadT(koff, 0);
    storeT(0);
    __syncthreads();
    for (int t=0; t<nk; ++t){
        const int cur = t & 1;
        if (t+1 < nk) loadT(koff + (t+1)*32, t+1);

        const short8 ah = *(const short8*)&AhS[cur][(w*16+fr)*SR + kg];
        const short8 al = *(const short8*)&AlS[cur][(w*16+fr)*SR + kg];
        {
            const short8 bh = *(const short8*)&BhS[cur][(fr)*SR + kg];
            const short8 bl = *(const short8*)&BlS[cur][(fr)*SR + kg];
            acc0 = __builtin_amdgcn_mfma_f32_16x16x32_bf16(ah, bh, acc0, 0,0,0);
            acc0 = __builtin_amdgcn_mfma_f32_16x16x32_bf16(ah, bl, acc0, 0,0,0);
            acc0 = __builtin_amdgcn_mfma_f32_16x16x32_bf16(al, bh, acc0, 0,0,0);
        }
        {
            const short8 bh = *(const short8*)&BhS[cur][(16+fr)*SR + kg];
            const short8 bl = *(const short8*)&BlS[cur][(16+fr)*SR + kg];
            acc1 = __builtin_amdgcn_mfma_f32_16x16x32_bf16(ah, bh, acc1, 0,0,0);
            acc1 = __builtin_amdgcn_mfma_f32_16x16x32_bf16(ah, bl, acc1, 0,0,0);
            acc1 = __builtin_amdgcn_mfma_f32_16x16x32_bf16(al, bh, acc1, 0,0,0);
        }
        {
            const short8 bh = *(const short8*)&BhS[cur][(32+fr)*SR + kg];
            const short8 bl = *(const short8*)&BlS[cur][(32+fr)*SR + kg];
            acc2 = __builtin_amdgcn_mfma_f32_16x16x32_bf16(ah, bh, acc2, 0,0,0);
            acc2 = __builtin_amdgcn_mfma_f32_16x16x32_bf16(ah, bl, acc2, 0,0,0);
            acc2 = __builtin_amdgcn_mfma_f32_16x16x32_bf16(al, bh, acc2, 0,0,0);
        }
        {
            const short8 bh = *(const short8*)&BhS[cur][(48+fr)*SR + kg];
            const short8 bl = *(const short8*)&BlS[cur][(48+fr)*SR + kg];
            acc3 = __builtin_amdgcn_mfma_f32_16x16x32_bf16(ah, bh, acc3, 0,0,0);
            acc3 = __builtin_amdgcn_mfma_f32_16x16x32_bf16(ah, bl, acc3, 0,0,0);
            acc3 = __builtin_amdgcn_mfma_f32_16x16x32_bf16(al, bh, acc3, 0,0,0);
        }
        if (t+1 < nk) storeT(cur^1);
        __syncthreads();
    }

    // C/D layout (m89-verified): col = lane&15, row = (lane>>4)*4 + reg
    float* __restrict__ P = jb.part + (size_t)split*M*N;
    const int rbase = bm + w*16 + (l>>4)*4;
    const int bn = bn64*64;
    #pragma unroll
    for (int nt=0; nt<4; ++nt){
        const f32x4 a = (nt==0)?acc0 : (nt==1)?acc1 : (nt==2)?acc2 : acc3;
        const int n = bn + nt*16 + fr;
        if (n < N){
            #pragma unroll
            for (int j=0;j<4;j++){
                const int m = rbase + j;
                if (m < M) P[(size_t)m*N + n] = a[j];
            }
        }
    }
}

// ---------------- reduce partials (+bias, +res, +optional bf16 planes) ----------------
struct RJob { const float* part; const float* bias; const float* res; float* C;
              unsigned short* ph; unsigned short* pl; int M; };

template<int NS>
__global__ __launch_bounds__(256) void reduce_k(RJob j0, RJob j1, int N)
{
    RJob j = blockIdx.y ? j1 : j0;
    const size_t total = (size_t)j.M*N;
    const size_t i4 = ((size_t)blockIdx.x*256 + threadIdx.x)*4;
    if (i4 >= total) return;
    float4 s = *(const float4*)(j.part + i4);
    #pragma unroll
    for (int t=1;t<NS;t++){
        const float4 v = *(const float4*)(j.part + (size_t)t*total + i4);
        s.x+=v.x; s.y+=v.y; s.z+=v.z; s.w+=v.w;
    }
    const int n = (int)(i4 % (size_t)N);
    if (j.bias){ s.x+=j.bias[n]; s.y+=j.bias[n+1]; s.z+=j.bias[n+2]; s.w+=j.bias[n+3]; }
    if (j.res){ const float4 r = *(const float4*)(j.res + i4); s.x+=r.x; s.y+=r.y; s.z+=r.z; s.w+=r.w; }
    if (j.C) *(float4*)(j.C + i4) = s;
    if (j.ph){
        const float f[4] = {s.x, s.y, s.z, s.w};
        short4_ h4, l4;
        #pragma unroll
        for (int q=0;q<4;q++){
            const unsigned short h = f2bh(f[q]);
            h4[q] = (short)h;
            l4[q] = (short)f2bh(f[q] - bh2f(h));
        }
        *(short4_*)(j.ph + i4) = h4;
        *(short4_*)(j.pl + i4) = l4;
    }
}

// ---------------- mamba prep: reduce 2 partials + conv + silu + softplus ----------------
// (z region removed: gated_rmsnorm now reads partials directly)
struct PrepJob {
    const float* part;     // [SP_IN][R][DPROJ]
    float* xh; float* Bc; float* Cc; float* dtw;
    const float* cw; const float* cb; const float* dtb;
    int R, L;
};

__device__ __forceinline__ float4 psum2(const float* p, size_t pstr){
    float4 a = *(const float4*)p;
    const float4 b = *(const float4*)(p + pstr);
    a.x += b.x; a.y += b.y; a.z += b.z; a.w += b.w;
    return a;
}

__global__ __launch_bounds__(256) void mamba_prep(PrepJob js, PrepJob jg)
{
    PrepJob j = blockIdx.y ? jg : js;
    const int R = j.R, L = j.L;
    constexpr int QPR = 324;   // 320 (conv) + 4 (dt) quads per row
    const int q = blockIdx.x*256 + threadIdx.x;
    if (q >= R*QPR) return;
    const int r = q / QPR, qi = q % QPR;
    const int l = r % L;
    const size_t pstr = (size_t)R*DPROJ;
    const float* base = j.part + (size_t)r*DPROJ;

    if (qi < 320) {                 // ---- conv region
        const int cc = qi*4;        // 0..1276
        float tk[4][4];
        #pragma unroll
        for (int k=0;k<4;k++){
            const int lr = l - 3 + k;
            if (lr >= 0){
                float4 v = psum2(j.part + (size_t)(r-3+k)*DPROJ + 1024 + cc, pstr);
                tk[k][0]=v.x; tk[k][1]=v.y; tk[k][2]=v.z; tk[k][3]=v.w;
            } else {
                tk[k][0]=0.f; tk[k][1]=0.f; tk[k][2]=0.f; tk[k][3]=0.f;
            }
        }
        const float4 cb4 = *(const float4*)(j.cb + cc);
        const float cba[4] = {cb4.x, cb4.y, cb4.z, cb4.w};
        float out[4];
        #pragma unroll
        for (int jj=0;jj<4;jj++){
            const float4 wv = *(const float4*)(j.cw + (size_t)(cc+jj)*4);
            float v = cba[jj] + wv.x*tk[0][jj] + wv.y*tk[1][jj]
                              + wv.z*tk[2][jj] + wv.w*tk[3][jj];
            out[jj] = siluf(v);
        }
        float4 o4; o4.x=out[0]; o4.y=out[1]; o4.z=out[2]; o4.w=out[3];
        if (cc < 1024)       *(float4*)(j.xh + (size_t)r*1024 + cc)        = o4;
        else if (cc < 1152)  *(float4*)(j.Bc + (size_t)r*128 + (cc-1024))  = o4;
        else                 *(float4*)(j.Cc + (size_t)r*128 + (cc-1152))  = o4;
    } else {                        // ---- dt region
        const int hd = (qi-320)*4;  // 0,4,8,12
        float4 s = psum2(base + 2304 + hd, pstr);
        const float4 b4 = *(const float4*)(j.dtb + hd);
        float raw[4] = {s.x+b4.x, s.y+b4.y, s.z+b4.z, s.w+b4.w};
        float4 o4;
        float* op = &o4.x;
        #pragma unroll
        for (int jj=0;jj<4;jj++)
            op[jj] = (raw[jj] > 20.f) ? raw[jj] : log1pf(expf(raw[jj]));
        *(float4*)(j.dtw + (size_t)r*16 + hd) = o4;
    }
}

// ---------------- CBT = C @ B^T per (batch, stack) — head-independent ----------------
__global__ __launch_bounds__(256) void mamba_cbt(
    const float* __restrict__ Bc_s, const float* __restrict__ Cc_s, float* __restrict__ cbt_s,
    const float* __restrict__ Bc_g, const float* __restrict__ Cc_g, float* __restrict__ cbt_g)
{
    const int b = blockIdx.x, st = blockIdx.y;
    const float* Bc = st ? Bc_g : Bc_s;
    const float* Cc = st ? Cc_g : Cc_s;
    float* cbt = st ? cbt_g : cbt_s;
    const int L = st ? LG : LS;
    constexpr int SB = 132;
    __shared__ float Bm[64*SB], Cm[64*SB];
    const int t = threadIdx.x;
    for (int idx = t; idx < L*32; idx += 256){
        const int l = idx >> 5, c4 = (idx & 31)*4;
        *(float4*)&Bm[l*SB + c4] = *(const float4*)(Bc + (size_t)(b*L+l)*128 + c4);
        *(float4*)&Cm[l*SB + c4] = *(const float4*)(Cc + (size_t)(b*L+l)*128 + c4);
    }
    __syncthreads();
    const int ti = t >> 4, tj = t & 15;
    float acc[4][4] = {};
    for (int k0=0;k0<128;k0+=4){
        float4 cr[4], br[4];
        #pragma unroll
        for (int a=0;a<4;a++) cr[a] = *(const float4*)&Cm[(ti+16*a)*SB + k0];
        #pragma unroll
        for (int qq=0;qq<4;qq++) br[qq] = *(const float4*)&Bm[(tj+16*qq)*SB + k0];
        #pragma unroll
        for (int a=0;a<4;a++)
            #pragma unroll
            for (int qq=0;qq<4;qq++)
                acc[a][qq] += cr[a].x*br[qq].x + cr[a].y*br[qq].y
                            + cr[a].z*br[qq].z + cr[a].w*br[qq].w;
    }
    #pragma unroll
    for (int a=0;a<4;a++){
        const int i = ti + 16*a;
        if (i < L){
            #pragma unroll
            for (int qq=0;qq<4;qq++){
                const int jj = tj + 16*qq;
                if (jj < L) cbt[(size_t)b*3840 + i*60 + jj] = acc[a][qq];
            }
        }
    }
}

// ---------------- Y = (decay .* CBT) @ X + D*X per (head, batch, stack) ----------------
__global__ __launch_bounds__(256) void mamba_y(
    const float* __restrict__ cbt_s, const float* __restrict__ xh_s, const float* __restrict__ dtw_s,
    const float* __restrict__ al_s, const float* __restrict__ Dw_s, float* __restrict__ y_s,
    const float* __restrict__ cbt_g, const float* __restrict__ xh_g, const float* __restrict__ dtw_g,
    const float* __restrict__ al_g, const float* __restrict__ Dw_g, float* __restrict__ y_g)
{
    const int h = blockIdx.x, b = blockIdx.y, st = blockIdx.z;
    const float* cbt = st ? cbt_g : cbt_s;
    const float* xh  = st ? xh_g  : xh_s;
    const float* dtw = st ? dtw_g : dtw_s;
    const float* al  = st ? al_g  : al_s;
    const float* Dw  = st ? Dw_g  : Dw_s;
    float* y = st ? y_g : y_s;
    const int L = st ? LG : LS;

    const int t = threadIdx.x;
    constexpr int SG = 60, SX = 68;
    __shared__ float Gm[64*SG], Xm[64*SX];
    __shared__ float dts[64], sps[64];

    const float Ah = -expf(al[h]);
    const float Dh = Dw[h];

    if (t < 64){
        float dtv = (t < L) ? dtw[(size_t)(b*L+t)*16 + h] : 0.f;
        float s = dtv;
        #pragma unroll
        for (int d=1; d<64; d<<=1){
            float o = __shfl_up(s, d, 64);
            if (t >= d) s += o;
        }
        dts[t] = dtv; sps[t] = s;
    }
    for (int idx = t; idx < L*16; idx += 256){
        const int l = idx >> 4, c4 = (idx & 15)*4;
        *(float4*)&Xm[l*SX + c4] = *(const float4*)(xh + (size_t)(b*L+l)*1024 + h*64 + c4);
    }
    __syncthreads();

    for (int idx = t; idx < L*15; idx += 256){
        const int i = idx/15, j4 = (idx%15)*4;
        const float4 v = *(const float4*)(cbt + (size_t)b*3840 + i*60 + j4);
        const float va[4] = {v.x, v.y, v.z, v.w};
        float g[4];
        const float si = sps[i];
        #pragma unroll
        for (int jj=0;jj<4;jj++){
            const int jc = j4 + jj;
            float gg = 0.f;
            if (jc <= i && jc < L)
                gg = expf(Ah*(si - sps[jc])) * dts[jc] * va[jj];
            g[jj] = gg;
        }
        float4 g4; g4.x=g[0]; g4.y=g[1]; g4.z=g[2]; g4.w=g[3];
        *(float4*)&Gm[i*SG + j4] = g4;
    }
    __syncthreads();

    const int ti = t >> 4, tj = t & 15;
    int la[4];
    #pragma unroll
    for (int a=0;a<4;a++) la[a] = ti + 16*a;
    float accY[4][4] = {};
    for (int m=0; m<L; ++m){
        float xr[4], gr[4];
        #pragma unroll
        for (int qq=0;qq<4;qq++) xr[qq] = Xm[m*SX + tj + 16*qq];
        #pragma unroll
        for (int a=0;a<4;a++) gr[a] = (la[a] < L) ? Gm[la[a]*SG + m] : 0.f;
        #pragma unroll
        for (int a=0;a<4;a++)
            #pragma unroll
            for (int qq=0;qq<4;qq++) accY[a][qq] = fmaf(gr[a], xr[qq], accY[a][qq]);
    }
    #pragma unroll
    for (int a=0;a<4;a++){
        if (la[a] < L){
            float* yrow = y + (size_t)(b*L + la[a])*DIN + h*HD;
            #pragma unroll
            for (int qq=0;qq<4;qq++){
                const int col = tj + 16*qq;
                yrow[col] = accY[a][qq] + Dh * Xm[la[a]*SX + col];
            }
        }
    }
}

// ---------------- gated RMSNorm: silu(z) from in-proj partials, -> bf16 planes ----------------
__global__ __launch_bounds__(256) void gated_rmsnorm(
    const float* __restrict__ y_s, const float* __restrict__ part_s, const float* __restrict__ nw_s,
    unsigned short* __restrict__ oh_s, unsigned short* __restrict__ ol_s,
    const float* __restrict__ y_g, const float* __restrict__ part_g, const float* __restrict__ nw_g,
    unsigned short* __restrict__ oh_g, unsigned short* __restrict__ ol_g)
{
    int r = blockIdx.x, t = threadIdx.x;
    int st = (r >= RS);
    int row = st ? r - RS : r;
    const float* y  = (st ? y_g  : y_s) + (size_t)row*DIN;
    const float* zp = (st ? part_g : part_s) + (size_t)row*DPROJ;
    const size_t pstr = (size_t)(st ? RG : RS)*DPROJ;
    const float* nw = st ? nw_g : nw_s;
    unsigned short* oh = (st ? oh_g : oh_s) + (size_t)row*DIN;
    unsigned short* ol = (st ? ol_g : ol_s) + (size_t)row*DIN;

    float g[4]; float s2 = 0.f;
    #pragma unroll
    for (int i=0;i<4;i++){
        int idx = t + i*256;
        const float zv = zp[idx] + zp[pstr + idx];
        float gv = y[idx] * siluf(zv);
        g[i] = gv; s2 += gv*gv;
    }
    #pragma unroll
    for (int o2=32;o2;o2>>=1) s2 += __shfl_xor(s2, o2, 64);
    __shared__ float red[4];
    if ((t & 63) == 0) red[t>>6] = s2;
    __syncthreads();
    float S2 = red[0]+red[1]+red[2]+red[3];
    float scale = rsqrtf(S2*(1.f/DIN) + 1e-5f);
    #pragma unroll
    for (int i=0;i<4;i++){
        int idx = t + i*256;
        const float val = g[i]*scale*nw[idx];
        const unsigned short h = f2bh(val);
        oh[idx] = h;
        ol[idx] = f2bh(val - bh2f(h));
    }
}

// ---------------- LayerNorm rows -> bf16 planes ----------------
__global__ __launch_bounds__(256) void ln_rows(
    const float* __restrict__ x, const float* __restrict__ w, const float* __restrict__ b,
    unsigned short* __restrict__ outh, unsigned short* __restrict__ outl, int D)
{
    int r = blockIdx.x, t = threadIdx.x;
    const float* xr = x + (size_t)r*D;
    float s = 0.f, s2 = 0.f;
    for (int i=t;i<D;i+=256){ float v = xr[i]; s += v; s2 += v*v; }
    #pragma unroll
    for (int o=32;o;o>>=1){ s += __shfl_xor(s,o,64); s2 += __shfl_xor(s2,o,64); }
    __shared__ float red[8];
    if ((t & 63) == 0){ red[t>>6] = s; red[4+(t>>6)] = s2; }
    __syncthreads();
    float S  = red[0]+red[1]+red[2]+red[3];
    float S2 = red[4]+red[5]+red[6]+red[7];
    float mean = S/D;
    float var  = S2/D - mean*mean;
    float inv  = rsqrtf(var + 1e-5f);
    for (int i=t;i<D;i+=256){
        const float val = (xr[i]-mean)*inv*w[i] + b[i];
        const unsigned short h = f2bh(val);
        outh[(size_t)r*D + i] = h;
        outl[(size_t)r*D + i] = f2bh(val - bh2f(h));
    }
}

// ---------------- cross-attention core: split-K partials + bias in, bf16 planes out ----------------
template<int LQ, int LKV, int NS>
__global__ __launch_bounds__(256) void mha_attn2(
    const float* __restrict__ pq, const float* __restrict__ pk, const float* __restrict__ pv,
    const float* __restrict__ qb, const float* __restrict__ kb, const float* __restrict__ vb,
    int Mq, int Mkv,
    unsigned short* __restrict__ outh, unsigned short* __restrict__ outl)
{
    const int hh = blockIdx.x, b = blockIdx.y, t = threadIdx.x;
    const size_t strQ = (size_t)Mq*DM, strKV = (size_t)Mkv*DM;
    constexpr int SD = 68;
    constexpr int SS = 60;
    constexpr int QT = (LQ +15)/16;
    constexpr int KT = (LKV+15)/16;
    __shared__ float Qs[LQ*SD];
    __shared__ float Ks[LKV*SD];
    __shared__ float Vs[LKV*SD];
    __shared__ float Ps[LQ*SS];

    for (int idx = t; idx < LQ*16; idx += 256){
        const int r = idx>>4, c4 = (idx&15)*4;
        float4 v = *(const float4*)(qb + hh*64 + c4);
        const size_t off = (size_t)(b*LQ+r)*DM + hh*64 + c4;
        #pragma unroll
        for (int s=0;s<NS;s++){
            const float4 u = *(const float4*)(pq + s*strQ + off);
            v.x+=u.x; v.y+=u.y; v.z+=u.z; v.w+=u.w;
        }
        *(float4*)&Qs[r*SD+c4] = v;
    }
    for (int idx = t; idx < LKV*16; idx += 256){
        const int r = idx>>4, c4 = (idx&15)*4;
        float4 kv = *(const float4*)(kb + hh*64 + c4);
        float4 vv = *(const float4*)(vb + hh*64 + c4);
        const size_t off = (size_t)(b*LKV+r)*DM + hh*64 + c4;
        #pragma unroll
        for (int s=0;s<NS;s++){
            const float4 ku = *(const float4*)(pk + s*strKV + off);
            const float4 vu = *(const float4*)(pv + s*strKV + off);
            kv.x+=ku.x; kv.y+=ku.y; kv.z+=ku.z; kv.w+=ku.w;
            vv.x+=vu.x; vv.y+=vu.y; vv.z+=vu.z; vv.w+=vu.w;
        }
        *(float4*)&Ks[r*SD+c4] = kv;
        *(float4*)&Vs[r*SD+c4] = vv;
    }
    __syncthreads();

    const int ti = t>>4, tj = t&15;

    {
        float acc[QT][KT];
        #pragma unroll
        for (int a=0;a<QT;a++)
            #pragma unroll
            for (int q=0;q<KT;q++) acc[a][q] = 0.f;
        for (int k0=0;k0<64;k0+=4){
            float4 qr[QT], kr[KT];
            #pragma unroll
            for (int a=0;a<QT;a++){
                int rr = ti+16*a; if (rr >= LQ) rr = LQ-1;
                qr[a] = *(const float4*)&Qs[rr*SD+k0];
            }
            #pragma unroll
            for (int q=0;q<KT;q++){
                int rr = tj+16*q; if (rr >= LKV) rr = LKV-1;
                kr[q] = *(const float4*)&Ks[rr*SD+k0];
            }
            #pragma unroll
            for (int a=0;a<QT;a++)
                #pragma unroll
                for (int q=0;q<KT;q++)
                    acc[a][q] += qr[a].x*kr[q].x + qr[a].y*kr[q].y
                               + qr[a].z*kr[q].z + qr[a].w*kr[q].w;
        }
        #pragma unroll
        for (int a=0;a<QT;a++){
            const int i = ti+16*a;
            if (i < LQ){
                #pragma unroll
                for (int q=0;q<KT;q++){
                    const int jj = tj+16*q;
                    if (jj < LKV) Ps[i*SS+jj] = acc[a][q]*0.125f;
                }
            }
        }
    }
    __syncthreads();

    if (t < LQ){
        float mx = -1e30f;
        for (int j=0;j<LKV;j++) mx = fmaxf(mx, Ps[t*SS+j]);
        float se = 0.f;
        for (int j=0;j<LKV;j++){ float e = expf(Ps[t*SS+j]-mx); Ps[t*SS+j] = e; se += e; }
        const float inv = 1.f/se;
        for (int j=0;j<LKV;j++) Ps[t*SS+j] *= inv;
    }
    __syncthreads();

    {
        float o[QT][4];
        #pragma unroll
        for (int a=0;a<QT;a++){ o[a][0]=0.f; o[a][1]=0.f; o[a][2]=0.f; o[a][3]=0.f; }
        for (int m=0;m<LKV;m++){
            const float4 vv = *(const float4*)&Vs[m*SD + tj*4];
            #pragma unroll
            for (int a=0;a<QT;a++){
                const int rr = ti+16*a;
                const float pv2 = (rr < LQ) ? Ps[rr*SS+m] : 0.f;
                o[a][0] = fmaf(pv2, vv.x, o[a][0]);
                o[a][1] = fmaf(pv2, vv.y, o[a][1]);
                o[a][2] = fmaf(pv2, vv.z, o[a][2]);
                o[a][3] = fmaf(pv2, vv.w, o[a][3]);
            }
        }
        #pragma unroll
        for (int a=0;a<QT;a++){
            const int rr = ti+16*a;
            if (rr < LQ){
                short4_ h4, l4;
                #pragma unroll
                for (int q=0;q<4;q++){
                    const unsigned short h = f2bh(o[a][q]);
                    h4[q] = (short)h;
                    l4[q] = (short)f2bh(o[a][q] - bh2f(h));
                }
                const size_t off = (size_t)(b*LQ+rr)*DM + hh*64 + tj*4;
                *(short4_*)(outh + off) = h4;
                *(short4_*)(outl + off) = l4;
            }
        }
    }
}

// ---------------- fused head: meanpool + LN + classifier ----------------
__global__ __launch_bounds__(512) void head_fused(
    const float* __restrict__ xs, const float* __restrict__ xg,
    const float* __restrict__ lw, const float* __restrict__ lb,
    const float* __restrict__ cw, const float* __restrict__ cb,
    float* __restrict__ out)
{
    const int b = blockIdx.x, t = threadIdx.x;
    __shared__ float fr[1024];
    __shared__ float red[16];
    __shared__ float pr[55*8];
    {
        float s = 0.f;
        for (int l=0;l<LS;l++) s += xs[(size_t)(b*LS+l)*DM + t];
        fr[t] = s*(1.f/LS);
        float g = 0.f;
        for (int l=0;l<LG;l++) g += xg[(size_t)(b*LG+l)*DM + t];
        fr[512+t] = g*(1.f/LG);
    }
    __syncthreads();
    float v0 = fr[t], v1 = fr[512+t];
    float sm = v0+v1, sq = v0*v0 + v1*v1;
    #pragma unroll
    for (int o=32;o;o>>=1){ sm += __shfl_xor(sm,o,64); sq += __shfl_xor(sq,o,64); }
    if ((t&63)==0){ red[t>>6] = sm; red[8+(t>>6)] = sq; }
    __syncthreads();
    float S=0.f, Q=0.f;
    #pragma unroll
    for (int i=0;i<8;i++){ S += red[i]; Q += red[8+i]; }
    const float mean = S*(1.f/1024.f);
    const float var  = Q*(1.f/1024.f) - mean*mean;
    const float inv  = rsqrtf(var + 1e-5f);
    fr[t]     = (v0-mean)*inv*lw[t]     + lb[t];
    fr[512+t] = (v1-mean)*inv*lw[512+t] + lb[512+t];
    __syncthreads();
    {
        const int c = t & 63, pp = t >> 6;
        if (c < 55){
            float a = 0.f;
            const float* wr = cw + (size_t)c*1024 + pp*128;
            const float* xr = fr + pp*128;
            #pragma unroll 4
            for (int k=0;k<128;k++) a = fmaf(xr[k], wr[k], a);
            pr[c*8+pp] = a;
        }
    }
    __syncthreads();
    if (t < 55){
        float a = cb[t];
        #pragma unroll
        for (int p2=0;p2<8;p2++) a += pr[t*8+p2];
        out[b*55 + t] = a;
    }
}

// ---------------- launch ----------------
extern "C" void kernel_launch(void* const* d_in, const int* in_sizes, int n_in,
                              void* d_out, int out_size, void* d_ws, size_t ws_size,
                              hipStream_t stream)
{
    (void)in_sizes; (void)n_in; (void)out_size; (void)ws_size;
    const float* x_spectra = (const float*)d_in[0];
    const float* x_gaia    = (const float*)d_in[1];
    const float* tok_w_s   = (const float*)d_in[2];
    const float* tok_b_s   = (const float*)d_in[3];
    const float* tok_w_g   = (const float*)d_in[4];
    const float* tok_b_g   = (const float*)d_in[5];
    const float* ms_Win    = (const float*)d_in[6];
    const float* ms_conv_w = (const float*)d_in[7];
    const float* ms_conv_b = (const float*)d_in[8];
    const float* ms_dtb    = (const float*)d_in[9];
    const float* ms_Alog   = (const float*)d_in[10];
    const float* ms_D      = (const float*)d_in[11];
    const float* ms_nw     = (const float*)d_in[12];
    const float* ms_Wout   = (const float*)d_in[13];
    const float* mg_Win    = (const float*)d_in[14];
    const float* mg_conv_w = (const float*)d_in[15];
    const float* mg_conv_b = (const float*)d_in[16];
    const float* mg_dtb    = (const float*)d_in[17];
    const float* mg_Alog   = (const float*)d_in[18];
    const float* mg_D      = (const float*)d_in[19];
    const float* mg_nw     = (const float*)d_in[20];
    const float* mg_Wout   = (const float*)d_in[21];
    const float* cas_ln_w  = (const float*)d_in[22];
    const float* cas_ln_b  = (const float*)d_in[23];
    const float* cas_in_w  = (const float*)d_in[24];
    const float* cas_in_b  = (const float*)d_in[25];
    const float* cas_out_w = (const float*)d_in[26];
    const float* cas_out_b = (const float*)d_in[27];
    const float* cag_ln_w  = (const float*)d_in[28];
    const float* cag_ln_b  = (const float*)d_in[29];
    const float* cag_in_w  = (const float*)d_in[30];
    const float* cag_in_b  = (const float*)d_in[31];
    const float* cag_out_w = (const float*)d_in[32];
    const float* cag_out_b = (const float*)d_in[33];
    const float* cls_ln_w  = (const float*)d_in[34];
    const float* cls_ln_b  = (const float*)d_in[35];
    const float* cls_w     = (const float*)d_in[36];
    const float* cls_b     = (const float*)d_in[37];

    float* p = (float*)d_ws;
    auto alloc = [&](size_t n){ float* r = p; p += n; return r; };
    float* xs       = alloc((size_t)RS*DM);
    float* xg       = alloc((size_t)RG*DM);
    float* y_s      = alloc((size_t)RS*DIN);
    float* y_g      = alloc((size_t)RG*DIN);
    float* part_inS  = alloc((size_t)SP_IN*RS*DPROJ);
    float* part_inG  = alloc((size_t)SP_IN*RG*DPROJ);
    float* part_outS = alloc((size_t)SP_OUT*RS*DM);
    float* part_outG = alloc((size_t)SP_OUT*RG*DM);
    float* part_q    = alloc((size_t)SP_ATT*RS*DM);
    float* part_k    = alloc((size_t)SP_ATT*RS*DM);
    float* part_v    = alloc((size_t)SP_ATT*RS*DM);
    float* xh_s    = alloc((size_t)RS*1024);
    float* xh_g    = alloc((size_t)RG*1024);
    float* Bc_s    = alloc((size_t)RS*128);
    float* Bc_g    = alloc((size_t)RG*128);
    float* Cc_s    = alloc((size_t)RS*128);
    float* Cc_g    = alloc((size_t)RG*128);
    float* dtw_s   = alloc((size_t)RS*16);
    float* dtw_g   = alloc((size_t)RG*16);
    float* cbt_s   = alloc((size_t)BB*3840);
    float* cbt_g   = alloc((size_t)BB*3840);

    unsigned short* up = (unsigned short*)p;
    auto ualloc = [&](size_t n){ unsigned short* r = up; up += n; return r; };
    unsigned short* xsh   = ualloc((size_t)RS*DM);
    unsigned short* xsl   = ualloc((size_t)RS*DM);
    unsigned short* xgh   = ualloc((size_t)RG*DM);
    unsigned short* xgl   = ualloc((size_t)RG*DM);
    unsigned short* ynh_s = ualloc((size_t)RS*DIN);
    unsigned short* ynl_s = ualloc((size_t)RS*DIN);
    unsigned short* ynh_g = ualloc((size_t)RG*DIN);
    unsigned short* ynl_g = ualloc((size_t)RG*DIN);
    unsigned short* lnh   = ualloc((size_t)RS*DM);
    unsigned short* lnl   = ualloc((size_t)RS*DM);
    unsigned short* aoh   = ualloc((size_t)RS*DM);
    unsigned short* aol   = ualloc((size_t)RS*DM);
    unsigned short* atth  = ualloc((size_t)8*ATT_PLANE);
    unsigned short* attl  = ualloc((size_t)8*ATT_PLANE);
    unsigned short* winh  = ualloc((size_t)20*WIN_PLANE);
    unsigned short* winl  = ualloc((size_t)20*WIN_PLANE);
    unsigned short* wouth = ualloc((size_t)20*WOUT_PLANE);
    unsigned short* woutl = ualloc((size_t)20*WOUT_PLANE);

    // tiled attention plane bases: q,k,v,o for cas (0..3) and cag (4..7)
    unsigned short* casq_h = atth + 0*ATT_PLANE; unsigned short* casq_l = attl + 0*ATT_PLANE;
    unsigned short* cask_h = atth + 1*ATT_PLANE; unsigned short* cask_l = attl + 1*ATT_PLANE;
    unsigned short* casv_h = atth + 2*ATT_PLANE; unsigned short* casv_l = attl + 2*ATT_PLANE;
    unsigned short* caso_h = atth + 3*ATT_PLANE; unsigned short* caso_l = attl + 3*ATT_PLANE;
    unsigned short* cagq_h = atth + 4*ATT_PLANE; unsigned short* cagq_l = attl + 4*ATT_PLANE;
    unsigned short* cagk_h = atth + 5*ATT_PLANE; unsigned short* cagk_l = attl + 5*ATT_PLANE;
    unsigned short* cagv_h = atth + 6*ATT_PLANE; unsigned short* cagv_l = attl + 6*ATT_PLANE;
    unsigned short* cago_h = atth + 7*ATT_PLANE; unsigned short* cago_l = attl + 7*ATT_PLANE;

    // one-time weight conversion (tiled, coalesced)
    convert_weights<<<dim3(9504), 256, 0, stream>>>(
        ms_Win, mg_Win, ms_Wout, mg_Wout,
        cas_in_w, cas_out_w, cag_in_w, cag_out_w,
        winh, winl, wouth, woutl, atth, attl);

    // tokenize (both modalities)
    tokenize2<<<dim3(LS, BB, 2), 512, 0, stream>>>(
        x_spectra, tok_w_s, tok_b_s, xs, xsh, xsl,
        x_gaia,    tok_w_g, tok_b_g, xg, xgh, xgl);

    const int rblkS = (RS*DM + 1023)/1024;   // 228
    const int prepBlk = (RS*324 + 255)/256;  // 578

    // mamba stacks
    for (int i=0;i<NLAY;i++){
        const float* cw_s   = ms_conv_w + (size_t)i*1280*4;
        const float* cw_g   = mg_conv_w + (size_t)i*1280*4;
        const float* cbv_s  = ms_conv_b + (size_t)i*1280;
        const float* cbv_g  = mg_conv_b + (size_t)i*1280;
        const float* dtb_s  = ms_dtb  + (size_t)i*NH;
        const float* dtb_g  = mg_dtb  + (size_t)i*NH;
        const float* al_s   = ms_Alog + (size_t)i*NH;
        const float* al_g   = mg_Alog + (size_t)i*NH;
        const float* Dw_s   = ms_D    + (size_t)i*NH;
        const float* Dw_g   = mg_D    + (size_t)i*NH;
        const float* nw_s   = ms_nw   + (size_t)i*DIN;
        const float* nw_g   = mg_nw   + (size_t)i*DIN;

        const unsigned short* wih_s = winh + (size_t)(2*i+0)*WIN_PLANE;
        const unsigned short* wil_s = winl + (size_t)(2*i+0)*WIN_PLANE;
        const unsigned short* wih_g = winh + (size_t)(2*i+1)*WIN_PLANE;
        const unsigned short* wil_g = winl + (size_t)(2*i+1)*WIN_PLANE;
        const unsigned short* woh_s = wouth + (size_t)(2*i+0)*WOUT_PLANE;
        const unsigned short* wol_s = woutl + (size_t)(2*i+0)*WOUT_PLANE;
        const unsigned short* woh_g = wouth + (size_t)(2*i+1)*WOUT_PLANE;
        const unsigned short* wol_g = woutl + (size_t)(2*i+1)*WOUT_PLANE;

        GemmJob inS{xsh, xsl, wih_s, wil_s, part_inS, RS};
        GemmJob inG{xgh, xgl, wih_g, wil_g, part_inG, RG};
        gemm_mfma<SP_IN><<<dim3(NT_IN, 8, 2*SP_IN), 256, 0, stream>>>(
            inS, inG, inG, DPROJ, DM, NT_IN);

        PrepJob pjS{part_inS, xh_s, Bc_s, Cc_s, dtw_s, cw_s, cbv_s, dtb_s, RS, LS};
        PrepJob pjG{part_inG, xh_g, Bc_g, Cc_g, dtw_g, cw_g, cbv_g, dtb_g, RG, LG};
        mamba_prep<<<dim3(prepBlk, 2), 256, 0, stream>>>(pjS, pjG);

        mamba_cbt<<<dim3(BB, 2), 256, 0, stream>>>(Bc_s, Cc_s, cbt_s, Bc_g, Cc_g, cbt_g);

        mamba_y<<<dim3(NH, BB, 2), 256, 0, stream>>>(
            cbt_s, xh_s, dtw_s, al_s, Dw_s, y_s,
            cbt_g, xh_g, dtw_g, al_g, Dw_g, y_g);

        gated_rmsnorm<<<dim3(RS+RG), 256, 0, stream>>>(
            y_s, part_inS, nw_s, ynh_s, ynl_s,  y_g, part_inG, nw_g, ynh_g, ynl_g);

        GemmJob outS{ynh_s, ynl_s, woh_s, wol_s, part_outS, RS};
        GemmJob outG{ynh_g, ynl_g, woh_g, wol_g, part_outG, RG};
        gemm_mfma<SP_OUT><<<dim3(NT_OUT, 8, 2*SP_OUT), 256, 0, stream>>>(
            outS, outG, outG, DM, DIN, NT_OUT);

        RJob roS{part_outS, nullptr, nullptr, xs, xsh, xsl, RS};
        RJob roG{part_outG, nullptr, nullptr, xg, xgh, xgl, RG};
        reduce_k<SP_OUT><<<dim3(rblkS, 2), 256, 0, stream>>>(roS, roG, DM);
    }

    // cross-attention: xs = xs + MHA(LN(xs), xg)
    {
        ln_rows<<<dim3(RS), 256, 0, stream>>>(xs, cas_ln_w, cas_ln_b, lnh, lnl, DM);
        GemmJob jq{lnh, lnl, casq_h, casq_l, part_q, RS};
        GemmJob jk{xgh, xgl, cask_h, cask_l, part_k, RG};
        GemmJob jv{xgh, xgl, casv_h, casv_l, part_v, RG};
        gemm_mfma<SP_ATT><<<dim3(NT_ATT, 8, 3*SP_ATT), 256, 0, stream>>>(jq, jk, jv, DM, DM, NT_ATT);
        mha_attn2<LS,LG,SP_ATT><<<dim3(8,BB), 256, 0, stream>>>(
            part_q, part_k, part_v, cas_in_b, cas_in_b+512, cas_in_b+1024, RS, RG, aoh, aol);
        GemmJob jo{aoh, aol, caso_h, caso_l, part_outS, RS};
        gemm_mfma<SP_ATT><<<dim3(NT_ATT, 8, SP_ATT), 256, 0, stream>>>(jo, jo, jo, DM, DM, NT_ATT);
        RJob ro{part_outS, cas_out_b, xs, xs, xsh, xsl, RS};
        reduce_k<SP_ATT><<<dim3(rblkS, 1), 256, 0, stream>>>(ro, ro, DM);
    }

    // cross-attention: xg = xg + MHA(LN(xg), xs_updated)
    {
        ln_rows<<<dim3(RG), 256, 0, stream>>>(xg, cag_ln_w, cag_ln_b, lnh, lnl, DM);
        GemmJob jq{lnh, lnl, cagq_h, cagq_l, part_q, RG};
        GemmJob jk{xsh, xsl, cagk_h, cagk_l, part_k, RS};
        GemmJob jv{xsh, xsl, cagv_h, cagv_l, part_v, RS};
        gemm_mfma<SP_ATT><<<dim3(NT_ATT, 8, 3*SP_ATT), 256, 0, stream>>>(jq, jk, jv, DM, DM, NT_ATT);
        mha_attn2<LG,LS,SP_ATT><<<dim3(8,BB), 256, 0, stream>>>(
            part_q, part_k, part_v, cag_in_b, cag_in_b+512, cag_in_b+1024, RG, RS, aoh, aol);
        GemmJob jo{aoh, aol, cago_h, cago_l, part_outS, RG};
        gemm_mfma<SP_ATT><<<dim3(NT_ATT, 2, SP_ATT), 256, 0, stream>>>(jo, jo, jo, DM, DM, NT_ATT);
        RJob ro{part_outS, cag_out_b, xg, xg, nullptr, nullptr, RG};
        reduce_k<SP_ATT><<<dim3((RG*DM+1023)/1024, 1), 256, 0, stream>>>(ro, ro, DM);
    }

    // fused head
    head_fused<<<dim3(BB), 512, 0, stream>>>(xs, xg, cls_ln_w, cls_ln_b, cls_w, cls_b, (float*)d_out);
}

// Round 13
// 702.256 us; speedup vs baseline: 2.0250x; 1.0438x over previous
//
#include <hip/hip_runtime.h>
#include <cmath>

// ---------------- constants ----------------
constexpr int BB    = 8;     // batch
constexpr int LS    = 57;    // spectra tokens
constexpr int LG    = 9;     // gaia tokens
constexpr int RS    = BB*LS; // 456
constexpr int RG    = BB*LG; // 72
constexpr int DM    = 512;   // d_model
constexpr int DPROJ = 2320;
constexpr int DIN   = 1024;
constexpr int NH    = 16;    // mamba heads
constexpr int HD    = 64;    // mamba headdim
constexpr int NLAY  = 10;

constexpr int SP_IN  = 2;    // split-K for in-proj  (K=512  -> 256/split)
constexpr int SP_OUT = 4;    // split-K for out-proj (K=1024 -> 256/split)
constexpr int SP_ATT = 4;    // split-K for attention gemms (K=512 -> 128/split)

// tiled weight geometry: [kt2][nt2][64 n][32 k], 2048 shorts (4KB) per tile
constexpr int NT_IN  = 37;   // in-proj n-tiles (2320 -> padded 2368)
constexpr int NT_OUT = 8;    // out-proj n-tiles (512)
constexpr int NT_ATT = 8;    // attention n-tiles (512)
constexpr size_t WIN_PLANE  = (size_t)16*NT_IN*2048;   // K=512 -> 16 k-tiles
constexpr size_t WOUT_PLANE = (size_t)32*NT_OUT*2048;  // K=1024 -> 32 k-tiles
constexpr size_t ATT_PLANE  = (size_t)16*NT_ATT*2048;  // 512x512

__device__ __forceinline__ float siluf(float x){ return x / (1.f + expf(-x)); }

// ---------------- bf16 split helpers ----------------
typedef short  short8  __attribute__((ext_vector_type(8)));
typedef short  short4_ __attribute__((ext_vector_type(4)));
typedef float  f32x4   __attribute__((ext_vector_type(4)));

__device__ __forceinline__ unsigned short f2bh(float f){
    unsigned int u = __float_as_uint(f);
    u = u + 0x7FFFu + ((u >> 16) & 1u);
    return (unsigned short)(u >> 16);
}
__device__ __forceinline__ float bh2f(unsigned short h){
    return __uint_as_float(((unsigned int)h) << 16);
}

// ---------------- tokenize both modalities (+bf16 planes) ----------------
__global__ __launch_bounds__(512) void tokenize2(
    const float* __restrict__ xS, const float* __restrict__ wS, const float* __restrict__ bS,
    float* __restrict__ oS, unsigned short* __restrict__ oSh, unsigned short* __restrict__ oSl,
    const float* __restrict__ xG, const float* __restrict__ wG, const float* __restrict__ bG,
    float* __restrict__ oG, unsigned short* __restrict__ oGh, unsigned short* __restrict__ oGl)
{
    const int st = blockIdx.z;
    const int tkt = blockIdx.x, b = blockIdx.y, d = threadIdx.x;
    const int ntok = st ? LG : LS;
    if (tkt >= ntok) return;
    const float* x = st ? xG : xS;
    const float* w = st ? wG : wS;
    const float* bias = st ? bG : bS;
    float* out = st ? oG : oS;
    unsigned short* oh = st ? oGh : oSh;
    unsigned short* ol = st ? oGl : oSl;
    const int in_dim = st ? 18 : 3647, tok_dim = st ? 2 : 64;

    __shared__ float xv[64];
    if (d < tok_dim) {
        int idx = tkt*tok_dim + d;
        xv[d] = (idx < in_dim) ? x[(size_t)b*in_dim + idx] : 0.f;
    }
    __syncthreads();
    float acc = bias[d];
    for (int k=0;k<tok_dim;k++) acc += xv[k]*w[(size_t)k*DM + d];
    const size_t o = (size_t)(b*ntok + tkt)*DM + d;
    out[o] = acc;
    const unsigned short h = f2bh(acc);
    oh[o] = h;
    ol[o] = f2bh(acc - bh2f(h));
}

// ---------------- weight conversion -> GEMM-native tiled bf16 hi/lo ----------------
// Non-temporal loads (source read once) and stores (planes not reused soon).
__global__ __launch_bounds__(256) void convert_weights(
    const float* __restrict__ winS, const float* __restrict__ winG,
    const float* __restrict__ woutS, const float* __restrict__ woutG,
    const float* __restrict__ cai, const float* __restrict__ cao,
    const float* __restrict__ cgi, const float* __restrict__ cgo,
    unsigned short* __restrict__ winh, unsigned short* __restrict__ winl,
    unsigned short* __restrict__ wouth, unsigned short* __restrict__ woutl,
    unsigned short* __restrict__ atth, unsigned short* __restrict__ attl)
{
    const int tid = threadIdx.x;
    const int bid = blockIdx.x;

    if (bid >= 8480){
        // ---- attention tiled copy (no transpose; src f32 [512][512]) ----
        int e = bid - 8480;
        const int job = e >> 7, rem = e & 127;
        const int kt2 = rem >> 3, nt2 = rem & 7;
        const float* src =
            (job==3) ? cao : (job==7) ? cgo :
            (job< 3) ? cai + (size_t)job*512*512 : cgi + (size_t)(job-4)*512*512;
        const size_t tile = (size_t)job*ATT_PLANE + ((size_t)kt2*NT_ATT + nt2)*2048;
        const int n = tid >> 2, k8 = (tid & 3)*8;
        const float* sp = src + (size_t)(nt2*64 + n)*512 + kt2*32 + k8;
        const f32x4 v0 = __builtin_nontemporal_load((const f32x4*)sp);
        const f32x4 v1 = __builtin_nontemporal_load((const f32x4*)(sp+4));
        const float f[8] = {v0[0],v0[1],v0[2],v0[3],v1[0],v1[1],v1[2],v1[3]};
        short8 h8, l8;
        #pragma unroll
        for (int q=0;q<8;q++){
            const unsigned short h = f2bh(f[q]);
            h8[q] = (short)h;
            l8[q] = (short)f2bh(f[q] - bh2f(h));
        }
        __builtin_nontemporal_store(h8, (short8*)(atth + tile + tid*8));
        __builtin_nontemporal_store(l8, (short8*)(attl + tile + tid*8));
        return;
    }

    // ---- transpose path ----
    const float* src; unsigned short *dh, *dl; int K, N, NT, nt, ktp;
    if (bid < 5920){
        const int plane = bid / 296, rem = bid % 296;
        const int s = plane & 1, layer = plane >> 1;
        src = (s ? winG : winS) + (size_t)layer*DM*DPROJ;
        dh = winh + (size_t)plane*WIN_PLANE;
        dl = winl + (size_t)plane*WIN_PLANE;
        K = DM; N = DPROJ; NT = NT_IN;
        nt = rem % 37; ktp = rem / 37;      // ktp in [0,8)
    } else {
        const int i = bid - 5920;
        const int plane = i / 128, rem = i % 128;
        const int s = plane & 1, layer = plane >> 1;
        src = (s ? woutG : woutS) + (size_t)layer*DIN*DM;
        dh = wouth + (size_t)plane*WOUT_PLANE;
        dl = woutl + (size_t)plane*WOUT_PLANE;
        K = DIN; N = DM; NT = NT_OUT;
        nt = rem % 8; ktp = rem / 8;        // ktp in [0,16)
    }

    __shared__ float tile[64][66];
    #pragma unroll
    for (int i=0;i<4;i++){
        const int kk = (tid>>4) + i*16;
        const int c4 = (tid&15)*4;
        const int n = nt*64 + c4;
        f32x4 v = {0.f,0.f,0.f,0.f};
        const float* sp = src + (size_t)(ktp*64+kk)*N + n;
        if (n + 3 < N) v = __builtin_nontemporal_load((const f32x4*)sp);
        else {
            if (n   < N) v[0] = sp[0];
            if (n+1 < N) v[1] = sp[1];
            if (n+2 < N) v[2] = sp[2];
            if (n+3 < N) v[3] = sp[3];
        }
        tile[kk][c4]=v[0]; tile[kk][c4+1]=v[1]; tile[kk][c4+2]=v[2]; tile[kk][c4+3]=v[3];
    }
    __syncthreads();

    const int n_l = tid >> 2, k8 = (tid & 3)*8;
    #pragma unroll
    for (int i=0;i<2;i++){
        const int kt2 = ktp*2 + i;
        short8 h8, l8;
        #pragma unroll
        for (int q=0;q<8;q++){
            const float f = tile[i*32 + k8 + q][n_l];
            const unsigned short h = f2bh(f);
            h8[q] = (short)h;
            l8[q] = (short)f2bh(f - bh2f(h));
        }
        const size_t off = ((size_t)kt2*NT + nt)*2048 + tid*8;
        __builtin_nontemporal_store(h8, (short8*)(dh + off));
        __builtin_nontemporal_store(l8, (short8*)(dl + off));
    }
}

// ---------------- split-K MFMA GEMM, pre-split bf16; W in tiled layout ----------------
struct GemmJob {
    const unsigned short* Ah; const unsigned short* Al;   // activations [M][K]
    const unsigned short* Wh; const unsigned short* Wl;   // tiled planes
    float* part; int M;
};

template<int NSPLIT>
__global__ __launch_bounds__(256) void gemm_mfma(GemmJob j0, GemmJob j1, GemmJob j2,
                                                 int N, int K, int NT)
{
    const int z = blockIdx.z;
    const int job = z / NSPLIT, split = z % NSPLIT;
    GemmJob jb = (job==0) ? j0 : (job==1 ? j1 : j2);
    const int bm = blockIdx.y*64, bn64 = blockIdx.x;
    const int M = jb.M;
    if (bm >= M) return;

    constexpr int SR = 40;
    __shared__ unsigned short AhS[2][64*SR], AlS[2][64*SR];
    __shared__ unsigned short BhS[2][64*SR], BlS[2][64*SR];

    const int tid = threadIdx.x;
    const int r0 = tid >> 2, k0off = (tid & 3)*8;
    const bool aok = (bm + r0 < M);
    const unsigned short* Aph = jb.Ah + (size_t)(bm+r0)*K;
    const unsigned short* Apl = jb.Al + (size_t)(bm+r0)*K;

    const int Kper = K / NSPLIT;
    const int koff = split * Kper;
    const int nk = Kper / 32;

    const size_t wbase = ((size_t)(koff >> 5)*NT + bn64)*2048 + (size_t)tid*8;
    const size_t wstep = (size_t)NT*2048;

    const short8 z8 = {0,0,0,0,0,0,0,0};
    short8 ra_h = z8, ra_l = z8, rw_h = z8, rw_l = z8;

    auto loadT = [&](int k0, int tstep){
        if (aok){
            ra_h = *(const short8*)(Aph + k0 + k0off);
            ra_l = *(const short8*)(Apl + k0 + k0off);
        } else { ra_h = z8; ra_l = z8; }
        rw_h = *(const short8*)(jb.Wh + wbase + (size_t)tstep*wstep);
        rw_l = *(const short8*)(jb.Wl + wbase + (size_t)tstep*wstep);
    };
    auto storeT = [&](int buf){
        *(short8*)&AhS[buf][r0*SR + k0off] = ra_h;
        *(short8*)&AlS[buf][r0*SR + k0off] = ra_l;
        *(short8*)&BhS[buf][r0*SR + k0off] = rw_h;
        *(short8*)&BlS[buf][r0*SR + k0off] = rw_l;
    };

    const int l = tid & 63, w = tid >> 6;
    const int fr = l & 15, kg = (l >> 4)*8;

    f32x4 acc0 = {0.f,0.f,0.f,0.f};
    f32x4 acc1 = {0.f,0.f,0.f,0.f};
    f32x4 acc2 = {0.f,0.f,0.f,0.f};
    f32x4 acc3 = {0.f,0.f,0.f,0.f};

    loadT(koff, 0);
    storeT(0);
    __syncthreads();
    for (int t=0; t<nk; ++t){
        const int cur = t & 1;
        if (t+1 < nk) loadT(koff + (t+1)*32, t+1);

        const short8 ah = *(const short8*)&AhS[cur][(w*16+fr)*SR + kg];
        const short8 al = *(const short8*)&AlS[cur][(w*16+fr)*SR + kg];
        {
            const short8 bh = *(const short8*)&BhS[cur][(fr)*SR + kg];
            const short8 bl = *(const short8*)&BlS[cur][(fr)*SR + kg];
            acc0 = __builtin_amdgcn_mfma_f32_16x16x32_bf16(ah, bh, acc0, 0,0,0);
            acc0 = __builtin_amdgcn_mfma_f32_16x16x32_bf16(ah, bl, acc0, 0,0,0);
            acc0 = __builtin_amdgcn_mfma_f32_16x16x32_bf16(al, bh, acc0, 0,0,0);
        }
        {
            const short8 bh = *(const short8*)&BhS[cur][(16+fr)*SR + kg];
            const short8 bl = *(const short8*)&BlS[cur][(16+fr)*SR + kg];
            acc1 = __builtin_amdgcn_mfma_f32_16x16x32_bf16(ah, bh, acc1, 0,0,0);
            acc1 = __builtin_amdgcn_mfma_f32_16x16x32_bf16(ah, bl, acc1, 0,0,0);
            acc1 = __builtin_amdgcn_mfma_f32_16x16x32_bf16(al, bh, acc1, 0,0,0);
        }
        {
            const short8 bh = *(const short8*)&BhS[cur][(32+fr)*SR + kg];
            const short8 bl = *(const short8*)&BlS[cur][(32+fr)*SR + kg];
            acc2 = __builtin_amdgcn_mfma_f32_16x16x32_bf16(ah, bh, acc2, 0,0,0);
            acc2 = __builtin_amdgcn_mfma_f32_16x16x32_bf16(ah, bl, acc2, 0,0,0);
            acc2 = __builtin_amdgcn_mfma_f32_16x16x32_bf16(al, bh, acc2, 0,0,0);
        }
        {
            const short8 bh = *(const short8*)&BhS[cur][(48+fr)*SR + kg];
            const short8 bl = *(const short8*)&BlS[cur][(48+fr)*SR + kg];
            acc3 = __builtin_amdgcn_mfma_f32_16x16x32_bf16(ah, bh, acc3, 0,0,0);
            acc3 = __builtin_amdgcn_mfma_f32_16x16x32_bf16(ah, bl, acc3, 0,0,0);
            acc3 = __builtin_amdgcn_mfma_f32_16x16x32_bf16(al, bh, acc3, 0,0,0);
        }
        if (t+1 < nk) storeT(cur^1);
        __syncthreads();
    }

    // C/D layout (m89-verified): col = lane&15, row = (lane>>4)*4 + reg
    float* __restrict__ P = jb.part + (size_t)split*M*N;
    const int rbase = bm + w*16 + (l>>4)*4;
    const int bn = bn64*64;
    #pragma unroll
    for (int nt=0; nt<4; ++nt){
        const f32x4 a = (nt==0)?acc0 : (nt==1)?acc1 : (nt==2)?acc2 : acc3;
        const int n = bn + nt*16 + fr;
        if (n < N){
            #pragma unroll
            for (int j=0;j<4;j++){
                const int m = rbase + j;
                if (m < M) P[(size_t)m*N + n] = a[j];
            }
        }
    }
}

// ---------------- reduce partials (+bias, +res, +optional bf16 planes) ----------------
struct RJob { const float* part; const float* bias; const float* res; float* C;
              unsigned short* ph; unsigned short* pl; int M; };

template<int NS>
__global__ __launch_bounds__(256) void reduce_k(RJob j0, RJob j1, int N)
{
    RJob j = blockIdx.y ? j1 : j0;
    const size_t total = (size_t)j.M*N;
    const size_t i4 = ((size_t)blockIdx.x*256 + threadIdx.x)*4;
    if (i4 >= total) return;
    float4 s = *(const float4*)(j.part + i4);
    #pragma unroll
    for (int t=1;t<NS;t++){
        const float4 v = *(const float4*)(j.part + (size_t)t*total + i4);
        s.x+=v.x; s.y+=v.y; s.z+=v.z; s.w+=v.w;
    }
    const int n = (int)(i4 % (size_t)N);
    if (j.bias){ s.x+=j.bias[n]; s.y+=j.bias[n+1]; s.z+=j.bias[n+2]; s.w+=j.bias[n+3]; }
    if (j.res){ const float4 r = *(const float4*)(j.res + i4); s.x+=r.x; s.y+=r.y; s.z+=r.z; s.w+=r.w; }
    if (j.C) *(float4*)(j.C + i4) = s;
    if (j.ph){
        const float f[4] = {s.x, s.y, s.z, s.w};
        short4_ h4, l4;
        #pragma unroll
        for (int q=0;q<4;q++){
            const unsigned short h = f2bh(f[q]);
            h4[q] = (short)h;
            l4[q] = (short)f2bh(f[q] - bh2f(h));
        }
        *(short4_*)(j.ph + i4) = h4;
        *(short4_*)(j.pl + i4) = l4;
    }
}

// ---------------- mamba prep: reduce 2 partials + conv + silu + softplus ----------------
struct PrepJob {
    const float* part;     // [SP_IN][R][DPROJ]
    float* xh; float* Bc; float* Cc; float* dtw;
    const float* cw; const float* cb; const float* dtb;
    int R, L;
};

__device__ __forceinline__ float4 psum2(const float* p, size_t pstr){
    float4 a = *(const float4*)p;
    const float4 b = *(const float4*)(p + pstr);
    a.x += b.x; a.y += b.y; a.z += b.z; a.w += b.w;
    return a;
}

__global__ __launch_bounds__(256) void mamba_prep(PrepJob js, PrepJob jg)
{
    PrepJob j = blockIdx.y ? jg : js;
    const int R = j.R, L = j.L;
    constexpr int QPR = 324;   // 320 (conv) + 4 (dt) quads per row
    const int q = blockIdx.x*256 + threadIdx.x;
    if (q >= R*QPR) return;
    const int r = q / QPR, qi = q % QPR;
    const int l = r % L;
    const size_t pstr = (size_t)R*DPROJ;
    const float* base = j.part + (size_t)r*DPROJ;

    if (qi < 320) {                 // ---- conv region
        const int cc = qi*4;        // 0..1276
        float tk[4][4];
        #pragma unroll
        for (int k=0;k<4;k++){
            const int lr = l - 3 + k;
            if (lr >= 0){
                float4 v = psum2(j.part + (size_t)(r-3+k)*DPROJ + 1024 + cc, pstr);
                tk[k][0]=v.x; tk[k][1]=v.y; tk[k][2]=v.z; tk[k][3]=v.w;
            } else {
                tk[k][0]=0.f; tk[k][1]=0.f; tk[k][2]=0.f; tk[k][3]=0.f;
            }
        }
        const float4 cb4 = *(const float4*)(j.cb + cc);
        const float cba[4] = {cb4.x, cb4.y, cb4.z, cb4.w};
        float out[4];
        #pragma unroll
        for (int jj=0;jj<4;jj++){
            const float4 wv = *(const float4*)(j.cw + (size_t)(cc+jj)*4);
            float v = cba[jj] + wv.x*tk[0][jj] + wv.y*tk[1][jj]
                              + wv.z*tk[2][jj] + wv.w*tk[3][jj];
            out[jj] = siluf(v);
        }
        float4 o4; o4.x=out[0]; o4.y=out[1]; o4.z=out[2]; o4.w=out[3];
        if (cc < 1024)       *(float4*)(j.xh + (size_t)r*1024 + cc)        = o4;
        else if (cc < 1152)  *(float4*)(j.Bc + (size_t)r*128 + (cc-1024))  = o4;
        else                 *(float4*)(j.Cc + (size_t)r*128 + (cc-1152))  = o4;
    } else {                        // ---- dt region
        const int hd = (qi-320)*4;  // 0,4,8,12
        float4 s = psum2(base + 2304 + hd, pstr);
        const float4 b4 = *(const float4*)(j.dtb + hd);
        float raw[4] = {s.x+b4.x, s.y+b4.y, s.z+b4.z, s.w+b4.w};
        float4 o4;
        float* op = &o4.x;
        #pragma unroll
        for (int jj=0;jj<4;jj++)
            op[jj] = (raw[jj] > 20.f) ? raw[jj] : log1pf(expf(raw[jj]));
        *(float4*)(j.dtw + (size_t)r*16 + hd) = o4;
    }
}

// ---------------- fused: G = decay .* (C @ B^T); Y = G @ X + D*X per (head,batch,stack) ----------------
__global__ __launch_bounds__(256) void mamba_y(
    const float* __restrict__ Bc_s, const float* __restrict__ Cc_s,
    const float* __restrict__ xh_s, const float* __restrict__ dtw_s,
    const float* __restrict__ al_s, const float* __restrict__ Dw_s, float* __restrict__ y_s,
    const float* __restrict__ Bc_g, const float* __restrict__ Cc_g,
    const float* __restrict__ xh_g, const float* __restrict__ dtw_g,
    const float* __restrict__ al_g, const float* __restrict__ Dw_g, float* __restrict__ y_g)
{
    const int h = blockIdx.x, b = blockIdx.y, st = blockIdx.z;
    const float* Bc  = st ? Bc_g  : Bc_s;
    const float* Cc  = st ? Cc_g  : Cc_s;
    const float* xh  = st ? xh_g  : xh_s;
    const float* dtw = st ? dtw_g : dtw_s;
    const float* al  = st ? al_g  : al_s;
    const float* Dw  = st ? Dw_g  : Dw_s;
    float* y = st ? y_g : y_s;
    const int L = st ? LG : LS;

    const int t = threadIdx.x;
    constexpr int SB = 132, SG = 60, SX = 68;
    __shared__ float Bm[64*SB], Cm[64*SB];
    __shared__ float Gm[64*SG], Xm[64*SX];
    __shared__ float dts[64], sps[64];

    const float Ah = -expf(al[h]);
    const float Dh = Dw[h];

    // dt + prefix scan (wave 0)
    if (t < 64){
        float dtv = (t < L) ? dtw[(size_t)(b*L+t)*16 + h] : 0.f;
        float s = dtv;
        #pragma unroll
        for (int d=1; d<64; d<<=1){
            float o = __shfl_up(s, d, 64);
            if (t >= d) s += o;
        }
        dts[t] = dtv; sps[t] = s;
    }
    // stage B, C, X tiles
    for (int idx = t; idx < L*32; idx += 256){
        const int l = idx >> 5, c4 = (idx & 31)*4;
        *(float4*)&Bm[l*SB + c4] = *(const float4*)(Bc + (size_t)(b*L+l)*128 + c4);
        *(float4*)&Cm[l*SB + c4] = *(const float4*)(Cc + (size_t)(b*L+l)*128 + c4);
    }
    for (int idx = t; idx < L*16; idx += 256){
        const int l = idx >> 4, c4 = (idx & 15)*4;
        *(float4*)&Xm[l*SX + c4] = *(const float4*)(xh + (size_t)(b*L+l)*1024 + h*64 + c4);
    }
    __syncthreads();

    const int ti = t >> 4, tj = t & 15;

    // G = decay .* (C @ B^T), computed in-block
    {
        float acc[4][4] = {};
        for (int k0=0;k0<128;k0+=4){
            float4 cr[4], br[4];
            #pragma unroll
            for (int a=0;a<4;a++) cr[a] = *(const float4*)&Cm[(ti+16*a)*SB + k0];
            #pragma unroll
            for (int qq=0;qq<4;qq++) br[qq] = *(const float4*)&Bm[(tj+16*qq)*SB + k0];
            #pragma unroll
            for (int a=0;a<4;a++)
                #pragma unroll
                for (int qq=0;qq<4;qq++)
                    acc[a][qq] += cr[a].x*br[qq].x + cr[a].y*br[qq].y
                                + cr[a].z*br[qq].z + cr[a].w*br[qq].w;
        }
        #pragma unroll
        for (int a=0;a<4;a++){
            const int i = ti + 16*a;
            if (i < L){
                const float si = sps[i];
                #pragma unroll
                for (int qq=0;qq<4;qq++){
                    const int jj = tj + 16*qq;
                    if (jj < L){
                        float gg = 0.f;
                        if (jj <= i)
                            gg = expf(Ah*(si - sps[jj])) * dts[jj] * acc[a][qq];
                        Gm[i*SG + jj] = gg;
                    }
                }
            }
        }
    }
    __syncthreads();

    // Y = G @ X + D*X
    int la[4];
    #pragma unroll
    for (int a=0;a<4;a++) la[a] = ti + 16*a;
    float accY[4][4] = {};
    for (int m=0; m<L; ++m){
        float xr[4], gr[4];
        #pragma unroll
        for (int qq=0;qq<4;qq++) xr[qq] = Xm[m*SX + tj + 16*qq];
        #pragma unroll
        for (int a=0;a<4;a++) gr[a] = (la[a] < L) ? Gm[la[a]*SG + m] : 0.f;
        #pragma unroll
        for (int a=0;a<4;a++)
            #pragma unroll
            for (int qq=0;qq<4;qq++) accY[a][qq] = fmaf(gr[a], xr[qq], accY[a][qq]);
    }
    #pragma unroll
    for (int a=0;a<4;a++){
        if (la[a] < L){
            float* yrow = y + (size_t)(b*L + la[a])*DIN + h*HD;
            #pragma unroll
            for (int qq=0;qq<4;qq++){
                const int col = tj + 16*qq;
                yrow[col] = accY[a][qq] + Dh * Xm[la[a]*SX + col];
            }
        }
    }
}

// ---------------- gated RMSNorm: silu(z) from in-proj partials, -> bf16 planes ----------------
__global__ __launch_bounds__(256) void gated_rmsnorm(
    const float* __restrict__ y_s, const float* __restrict__ part_s, const float* __restrict__ nw_s,
    unsigned short* __restrict__ oh_s, unsigned short* __restrict__ ol_s,
    const float* __restrict__ y_g, const float* __restrict__ part_g, const float* __restrict__ nw_g,
    unsigned short* __restrict__ oh_g, unsigned short* __restrict__ ol_g)
{
    int r = blockIdx.x, t = threadIdx.x;
    int st = (r >= RS);
    int row = st ? r - RS : r;
    const float* y  = (st ? y_g  : y_s) + (size_t)row*DIN;
    const float* zp = (st ? part_g : part_s) + (size_t)row*DPROJ;
    const size_t pstr = (size_t)(st ? RG : RS)*DPROJ;
    const float* nw = st ? nw_g : nw_s;
    unsigned short* oh = (st ? oh_g : oh_s) + (size_t)row*DIN;
    unsigned short* ol = (st ? ol_g : ol_s) + (size_t)row*DIN;

    float g[4]; float s2 = 0.f;
    #pragma unroll
    for (int i=0;i<4;i++){
        int idx = t + i*256;
        const float zv = zp[idx] + zp[pstr + idx];
        float gv = y[idx] * siluf(zv);
        g[i] = gv; s2 += gv*gv;
    }
    #pragma unroll
    for (int o2=32;o2;o2>>=1) s2 += __shfl_xor(s2, o2, 64);
    __shared__ float red[4];
    if ((t & 63) == 0) red[t>>6] = s2;
    __syncthreads();
    float S2 = red[0]+red[1]+red[2]+red[3];
    float scale = rsqrtf(S2*(1.f/DIN) + 1e-5f);
    #pragma unroll
    for (int i=0;i<4;i++){
        int idx = t + i*256;
        const float val = g[i]*scale*nw[idx];
        const unsigned short h = f2bh(val);
        oh[idx] = h;
        ol[idx] = f2bh(val - bh2f(h));
    }
}

// ---------------- LayerNorm rows -> bf16 planes ----------------
__global__ __launch_bounds__(256) void ln_rows(
    const float* __restrict__ x, const float* __restrict__ w, const float* __restrict__ b,
    unsigned short* __restrict__ outh, unsigned short* __restrict__ outl, int D)
{
    int r = blockIdx.x, t = threadIdx.x;
    const float* xr = x + (size_t)r*D;
    float s = 0.f, s2 = 0.f;
    for (int i=t;i<D;i+=256){ float v = xr[i]; s += v; s2 += v*v; }
    #pragma unroll
    for (int o=32;o;o>>=1){ s += __shfl_xor(s,o,64); s2 += __shfl_xor(s2,o,64); }
    __shared__ float red[8];
    if ((t & 63) == 0){ red[t>>6] = s; red[4+(t>>6)] = s2; }
    __syncthreads();
    float S  = red[0]+red[1]+red[2]+red[3];
    float S2 = red[4]+red[5]+red[6]+red[7];
    float mean = S/D;
    float var  = S2/D - mean*mean;
    float inv  = rsqrtf(var + 1e-5f);
    for (int i=t;i<D;i+=256){
        const float val = (xr[i]-mean)*inv*w[i] + b[i];
        const unsigned short h = f2bh(val);
        outh[(size_t)r*D + i] = h;
        outl[(size_t)r*D + i] = f2bh(val - bh2f(h));
    }
}

// ---------------- cross-attention core: split-K partials + bias in, bf16 planes out ----------------
template<int LQ, int LKV, int NS>
__global__ __launch_bounds__(256) void mha_attn2(
    const float* __restrict__ pq, const float* __restrict__ pk, const float* __restrict__ pv,
    const float* __restrict__ qb, const float* __restrict__ kb, const float* __restrict__ vb,
    int Mq, int Mkv,
    unsigned short* __restrict__ outh, unsigned short* __restrict__ outl)
{
    const int hh = blockIdx.x, b = blockIdx.y, t = threadIdx.x;
    const size_t strQ = (size_t)Mq*DM, strKV = (size_t)Mkv*DM;
    constexpr int SD = 68;
    constexpr int SS = 60;
    constexpr int QT = (LQ +15)/16;
    constexpr int KT = (LKV+15)/16;
    __shared__ float Qs[LQ*SD];
    __shared__ float Ks[LKV*SD];
    __shared__ float Vs[LKV*SD];
    __shared__ float Ps[LQ*SS];

    for (int idx = t; idx < LQ*16; idx += 256){
        const int r = idx>>4, c4 = (idx&15)*4;
        float4 v = *(const float4*)(qb + hh*64 + c4);
        const size_t off = (size_t)(b*LQ+r)*DM + hh*64 + c4;
        #pragma unroll
        for (int s=0;s<NS;s++){
            const float4 u = *(const float4*)(pq + s*strQ + off);
            v.x+=u.x; v.y+=u.y; v.z+=u.z; v.w+=u.w;
        }
        *(float4*)&Qs[r*SD+c4] = v;
    }
    for (int idx = t; idx < LKV*16; idx += 256){
        const int r = idx>>4, c4 = (idx&15)*4;
        float4 kv = *(const float4*)(kb + hh*64 + c4);
        float4 vv = *(const float4*)(vb + hh*64 + c4);
        const size_t off = (size_t)(b*LKV+r)*DM + hh*64 + c4;
        #pragma unroll
        for (int s=0;s<NS;s++){
            const float4 ku = *(const float4*)(pk + s*strKV + off);
            const float4 vu = *(const float4*)(pv + s*strKV + off);
            kv.x+=ku.x; kv.y+=ku.y; kv.z+=ku.z; kv.w+=ku.w;
            vv.x+=vu.x; vv.y+=vu.y; vv.z+=vu.z; vv.w+=vu.w;
        }
        *(float4*)&Ks[r*SD+c4] = kv;
        *(float4*)&Vs[r*SD+c4] = vv;
    }
    __syncthreads();

    const int ti = t>>4, tj = t&15;

    {
        float acc[QT][KT];
        #pragma unroll
        for (int a=0;a<QT;a++)
            #pragma unroll
            for (int q=0;q<KT;q++) acc[a][q] = 0.f;
        for (int k0=0;k0<64;k0+=4){
            float4 qr[QT], kr[KT];
            #pragma unroll
            for (int a=0;a<QT;a++){
                int rr = ti+16*a; if (rr >= LQ) rr = LQ-1;
                qr[a] = *(const float4*)&Qs[rr*SD+k0];
            }
            #pragma unroll
            for (int q=0;q<KT;q++){
                int rr = tj+16*q; if (rr >= LKV) rr = LKV-1;
                kr[q] = *(const float4*)&Ks[rr*SD+k0];
            }
            #pragma unroll
            for (int a=0;a<QT;a++)
                #pragma unroll
                for (int q=0;q<KT;q++)
                    acc[a][q] += qr[a].x*kr[q].x + qr[a].y*kr[q].y
                               + qr[a].z*kr[q].z + qr[a].w*kr[q].w;
        }
        #pragma unroll
        for (int a=0;a<QT;a++){
            const int i = ti+16*a;
            if (i < LQ){
                #pragma unroll
                for (int q=0;q<KT;q++){
                    const int jj = tj+16*q;
                    if (jj < LKV) Ps[i*SS+jj] = acc[a][q]*0.125f;
                }
            }
        }
    }
    __syncthreads();

    if (t < LQ){
        float mx = -1e30f;
        for (int j=0;j<LKV;j++) mx = fmaxf(mx, Ps[t*SS+j]);
        float se = 0.f;
        for (int j=0;j<LKV;j++){ float e = expf(Ps[t*SS+j]-mx); Ps[t*SS+j] = e; se += e; }
        const float inv = 1.f/se;
        for (int j=0;j<LKV;j++) Ps[t*SS+j] *= inv;
    }
    __syncthreads();

    {
        float o[QT][4];
        #pragma unroll
        for (int a=0;a<QT;a++){ o[a][0]=0.f; o[a][1]=0.f; o[a][2]=0.f; o[a][3]=0.f; }
        for (int m=0;m<LKV;m++){
            const float4 vv = *(const float4*)&Vs[m*SD + tj*4];
            #pragma unroll
            for (int a=0;a<QT;a++){
                const int rr = ti+16*a;
                const float pv2 = (rr < LQ) ? Ps[rr*SS+m] : 0.f;
                o[a][0] = fmaf(pv2, vv.x, o[a][0]);
                o[a][1] = fmaf(pv2, vv.y, o[a][1]);
                o[a][2] = fmaf(pv2, vv.z, o[a][2]);
                o[a][3] = fmaf(pv2, vv.w, o[a][3]);
            }
        }
        #pragma unroll
        for (int a=0;a<QT;a++){
            const int rr = ti+16*a;
            if (rr < LQ){
                short4_ h4, l4;
                #pragma unroll
                for (int q=0;q<4;q++){
                    const unsigned short h = f2bh(o[a][q]);
                    h4[q] = (short)h;
                    l4[q] = (short)f2bh(o[a][q] - bh2f(h));
                }
                const size_t off = (size_t)(b*LQ+rr)*DM + hh*64 + tj*4;
                *(short4_*)(outh + off) = h4;
                *(short4_*)(outl + off) = l4;
            }
        }
    }
}

// ---------------- fused head: meanpool + LN + classifier ----------------
__global__ __launch_bounds__(512) void head_fused(
    const float* __restrict__ xs, const float* __restrict__ xg,
    const float* __restrict__ lw, const float* __restrict__ lb,
    const float* __restrict__ cw, const float* __restrict__ cb,
    float* __restrict__ out)
{
    const int b = blockIdx.x, t = threadIdx.x;
    __shared__ float fr[1024];
    __shared__ float red[16];
    __shared__ float pr[55*8];
    {
        float s = 0.f;
        for (int l=0;l<LS;l++) s += xs[(size_t)(b*LS+l)*DM + t];
        fr[t] = s*(1.f/LS);
        float g = 0.f;
        for (int l=0;l<LG;l++) g += xg[(size_t)(b*LG+l)*DM + t];
        fr[512+t] = g*(1.f/LG);
    }
    __syncthreads();
    float v0 = fr[t], v1 = fr[512+t];
    float sm = v0+v1, sq = v0*v0 + v1*v1;
    #pragma unroll
    for (int o=32;o;o>>=1){ sm += __shfl_xor(sm,o,64); sq += __shfl_xor(sq,o,64); }
    if ((t&63)==0){ red[t>>6] = sm; red[8+(t>>6)] = sq; }
    __syncthreads();
    float S=0.f, Q=0.f;
    #pragma unroll
    for (int i=0;i<8;i++){ S += red[i]; Q += red[8+i]; }
    const float mean = S*(1.f/1024.f);
    const float var  = Q*(1.f/1024.f) - mean*mean;
    const float inv  = rsqrtf(var + 1e-5f);
    fr[t]     = (v0-mean)*inv*lw[t]     + lb[t];
    fr[512+t] = (v1-mean)*inv*lw[512+t] + lb[512+t];
    __syncthreads();
    {
        const int c = t & 63, pp = t >> 6;
        if (c < 55){
            float a = 0.f;
            const float* wr = cw + (size_t)c*1024 + pp*128;
            const float* xr = fr + pp*128;
            #pragma unroll 4
            for (int k=0;k<128;k++) a = fmaf(xr[k], wr[k], a);
            pr[c*8+pp] = a;
        }
    }
    __syncthreads();
    if (t < 55){
        float a = cb[t];
        #pragma unroll
        for (int p2=0;p2<8;p2++) a += pr[t*8+p2];
        out[b*55 + t] = a;
    }
}

// ---------------- launch ----------------
extern "C" void kernel_launch(void* const* d_in, const int* in_sizes, int n_in,
                              void* d_out, int out_size, void* d_ws, size_t ws_size,
                              hipStream_t stream)
{
    (void)in_sizes; (void)n_in; (void)out_size; (void)ws_size;
    const float* x_spectra = (const float*)d_in[0];
    const float* x_gaia    = (const float*)d_in[1];
    const float* tok_w_s   = (const float*)d_in[2];
    const float* tok_b_s   = (const float*)d_in[3];
    const float* tok_w_g   = (const float*)d_in[4];
    const float* tok_b_g   = (const float*)d_in[5];
    const float* ms_Win    = (const float*)d_in[6];
    const float* ms_conv_w = (const float*)d_in[7];
    const float* ms_conv_b = (const float*)d_in[8];
    const float* ms_dtb    = (const float*)d_in[9];
    const float* ms_Alog   = (const float*)d_in[10];
    const float* ms_D      = (const float*)d_in[11];
    const float* ms_nw     = (const float*)d_in[12];
    const float* ms_Wout   = (const float*)d_in[13];
    const float* mg_Win    = (const float*)d_in[14];
    const float* mg_conv_w = (const float*)d_in[15];
    const float* mg_conv_b = (const float*)d_in[16];
    const float* mg_dtb    = (const float*)d_in[17];
    const float* mg_Alog   = (const float*)d_in[18];
    const float* mg_D      = (const float*)d_in[19];
    const float* mg_nw     = (const float*)d_in[20];
    const float* mg_Wout   = (const float*)d_in[21];
    const float* cas_ln_w  = (const float*)d_in[22];
    const float* cas_ln_b  = (const float*)d_in[23];
    const float* cas_in_w  = (const float*)d_in[24];
    const float* cas_in_b  = (const float*)d_in[25];
    const float* cas_out_w = (const float*)d_in[26];
    const float* cas_out_b = (const float*)d_in[27];
    const float* cag_ln_w  = (const float*)d_in[28];
    const float* cag_ln_b  = (const float*)d_in[29];
    const float* cag_in_w  = (const float*)d_in[30];
    const float* cag_in_b  = (const float*)d_in[31];
    const float* cag_out_w = (const float*)d_in[32];
    const float* cag_out_b = (const float*)d_in[33];
    const float* cls_ln_w  = (const float*)d_in[34];
    const float* cls_ln_b  = (const float*)d_in[35];
    const float* cls_w     = (const float*)d_in[36];
    const float* cls_b     = (const float*)d_in[37];

    float* p = (float*)d_ws;
    auto alloc = [&](size_t n){ float* r = p; p += n; return r; };
    float* xs       = alloc((size_t)RS*DM);
    float* xg       = alloc((size_t)RG*DM);
    float* y_s      = alloc((size_t)RS*DIN);
    float* y_g      = alloc((size_t)RG*DIN);
    float* part_inS  = alloc((size_t)SP_IN*RS*DPROJ);
    float* part_inG  = alloc((size_t)SP_IN*RG*DPROJ);
    float* part_outS = alloc((size_t)SP_OUT*RS*DM);
    float* part_outG = alloc((size_t)SP_OUT*RG*DM);
    float* part_q    = alloc((size_t)SP_ATT*RS*DM);
    float* part_k    = alloc((size_t)SP_ATT*RS*DM);
    float* part_v    = alloc((size_t)SP_ATT*RS*DM);
    float* xh_s    = alloc((size_t)RS*1024);
    float* xh_g    = alloc((size_t)RG*1024);
    float* Bc_s    = alloc((size_t)RS*128);
    float* Bc_g    = alloc((size_t)RG*128);
    float* Cc_s    = alloc((size_t)RS*128);
    float* Cc_g    = alloc((size_t)RG*128);
    float* dtw_s   = alloc((size_t)RS*16);
    float* dtw_g   = alloc((size_t)RG*16);

    unsigned short* up = (unsigned short*)p;
    auto ualloc = [&](size_t n){ unsigned short* r = up; up += n; return r; };
    unsigned short* xsh   = ualloc((size_t)RS*DM);
    unsigned short* xsl   = ualloc((size_t)RS*DM);
    unsigned short* xgh   = ualloc((size_t)RG*DM);
    unsigned short* xgl   = ualloc((size_t)RG*DM);
    unsigned short* ynh_s = ualloc((size_t)RS*DIN);
    unsigned short* ynl_s = ualloc((size_t)RS*DIN);
    unsigned short* ynh_g = ualloc((size_t)RG*DIN);
    unsigned short* ynl_g = ualloc((size_t)RG*DIN);
    unsigned short* lnh   = ualloc((size_t)RS*DM);
    unsigned short* lnl   = ualloc((size_t)RS*DM);
    unsigned short* aoh   = ualloc((size_t)RS*DM);
    unsigned short* aol   = ualloc((size_t)RS*DM);
    unsigned short* atth  = ualloc((size_t)8*ATT_PLANE);
    unsigned short* attl  = ualloc((size_t)8*ATT_PLANE);
    unsigned short* winh  = ualloc((size_t)20*WIN_PLANE);
    unsigned short* winl  = ualloc((size_t)20*WIN_PLANE);
    unsigned short* wouth = ualloc((size_t)20*WOUT_PLANE);
    unsigned short* woutl = ualloc((size_t)20*WOUT_PLANE);

    // tiled attention plane bases: q,k,v,o for cas (0..3) and cag (4..7)
    unsigned short* casq_h = atth + 0*ATT_PLANE; unsigned short* casq_l = attl + 0*ATT_PLANE;
    unsigned short* cask_h = atth + 1*ATT_PLANE; unsigned short* cask_l = attl + 1*ATT_PLANE;
    unsigned short* casv_h = atth + 2*ATT_PLANE; unsigned short* casv_l = attl + 2*ATT_PLANE;
    unsigned short* caso_h = atth + 3*ATT_PLANE; unsigned short* caso_l = attl + 3*ATT_PLANE;
    unsigned short* cagq_h = atth + 4*ATT_PLANE; unsigned short* cagq_l = attl + 4*ATT_PLANE;
    unsigned short* cagk_h = atth + 5*ATT_PLANE; unsigned short* cagk_l = attl + 5*ATT_PLANE;
    unsigned short* cagv_h = atth + 6*ATT_PLANE; unsigned short* cagv_l = attl + 6*ATT_PLANE;
    unsigned short* cago_h = atth + 7*ATT_PLANE; unsigned short* cago_l = attl + 7*ATT_PLANE;

    // one-time weight conversion (tiled, NT loads/stores)
    convert_weights<<<dim3(9504), 256, 0, stream>>>(
        ms_Win, mg_Win, ms_Wout, mg_Wout,
        cas_in_w, cas_out_w, cag_in_w, cag_out_w,
        winh, winl, wouth, woutl, atth, attl);

    // tokenize (both modalities)
    tokenize2<<<dim3(LS, BB, 2), 512, 0, stream>>>(
        x_spectra, tok_w_s, tok_b_s, xs, xsh, xsl,
        x_gaia,    tok_w_g, tok_b_g, xg, xgh, xgl);

    const int rblkS = (RS*DM + 1023)/1024;   // 228
    const int prepBlk = (RS*324 + 255)/256;  // 578

    // mamba stacks
    for (int i=0;i<NLAY;i++){
        const float* cw_s   = ms_conv_w + (size_t)i*1280*4;
        const float* cw_g   = mg_conv_w + (size_t)i*1280*4;
        const float* cbv_s  = ms_conv_b + (size_t)i*1280;
        const float* cbv_g  = mg_conv_b + (size_t)i*1280;
        const float* dtb_s  = ms_dtb  + (size_t)i*NH;
        const float* dtb_g  = mg_dtb  + (size_t)i*NH;
        const float* al_s   = ms_Alog + (size_t)i*NH;
        const float* al_g   = mg_Alog + (size_t)i*NH;
        const float* Dw_s   = ms_D    + (size_t)i*NH;
        const float* Dw_g   = mg_D    + (size_t)i*NH;
        const float* nw_s   = ms_nw   + (size_t)i*DIN;
        const float* nw_g   = mg_nw   + (size_t)i*DIN;

        const unsigned short* wih_s = winh + (size_t)(2*i+0)*WIN_PLANE;
        const unsigned short* wil_s = winl + (size_t)(2*i+0)*WIN_PLANE;
        const unsigned short* wih_g = winh + (size_t)(2*i+1)*WIN_PLANE;
        const unsigned short* wil_g = winl + (size_t)(2*i+1)*WIN_PLANE;
        const unsigned short* woh_s = wouth + (size_t)(2*i+0)*WOUT_PLANE;
        const unsigned short* wol_s = woutl + (size_t)(2*i+0)*WOUT_PLANE;
        const unsigned short* woh_g = wouth + (size_t)(2*i+1)*WOUT_PLANE;
        const unsigned short* wol_g = woutl + (size_t)(2*i+1)*WOUT_PLANE;

        GemmJob inS{xsh, xsl, wih_s, wil_s, part_inS, RS};
        GemmJob inG{xgh, xgl, wih_g, wil_g, part_inG, RG};
        gemm_mfma<SP_IN><<<dim3(NT_IN, 8, 2*SP_IN), 256, 0, stream>>>(
            inS, inG, inG, DPROJ, DM, NT_IN);

        PrepJob pjS{part_inS, xh_s, Bc_s, Cc_s, dtw_s, cw_s, cbv_s, dtb_s, RS, LS};
        PrepJob pjG{part_inG, xh_g, Bc_g, Cc_g, dtw_g, cw_g, cbv_g, dtb_g, RG, LG};
        mamba_prep<<<dim3(prepBlk, 2), 256, 0, stream>>>(pjS, pjG);

        mamba_y<<<dim3(NH, BB, 2), 256, 0, stream>>>(
            Bc_s, Cc_s, xh_s, dtw_s, al_s, Dw_s, y_s,
            Bc_g, Cc_g, xh_g, dtw_g, al_g, Dw_g, y_g);

        gated_rmsnorm<<<dim3(RS+RG), 256, 0, stream>>>(
            y_s, part_inS, nw_s, ynh_s, ynl_s,  y_g, part_inG, nw_g, ynh_g, ynl_g);

        GemmJob outS{ynh_s, ynl_s, woh_s, wol_s, part_outS, RS};
        GemmJob outG{ynh_g, ynl_g, woh_g, wol_g, part_outG, RG};
        gemm_mfma<SP_OUT><<<dim3(NT_OUT, 8, 2*SP_OUT), 256, 0, stream>>>(
            outS, outG, outG, DM, DIN, NT_OUT);

        RJob roS{part_outS, nullptr, nullptr, xs, xsh, xsl, RS};
        RJob roG{part_outG, nullptr, nullptr, xg, xgh, xgl, RG};
        reduce_k<SP_OUT><<<dim3(rblkS, 2), 256, 0, stream>>>(roS, roG, DM);
    }

    // cross-attention: xs = xs + MHA(LN(xs), xg)
    {
        ln_rows<<<dim3(RS), 256, 0, stream>>>(xs, cas_ln_w, cas_ln_b, lnh, lnl, DM);
        GemmJob jq{lnh, lnl, casq_h, casq_l, part_q, RS};
        GemmJob jk{xgh, xgl, cask_h, cask_l, part_k, RG};
        GemmJob jv{xgh, xgl, casv_h, casv_l, part_v, RG};
        gemm_mfma<SP_ATT><<<dim3(NT_ATT, 8, 3*SP_ATT), 256, 0, stream>>>(jq, jk, jv, DM, DM, NT_ATT);
        mha_attn2<LS,LG,SP_ATT><<<dim3(8,BB), 256, 0, stream>>>(
            part_q, part_k, part_v, cas_in_b, cas_in_b+512, cas_in_b+1024, RS, RG, aoh, aol);
        GemmJob jo{aoh, aol, caso_h, caso_l, part_outS, RS};
        gemm_mfma<SP_ATT><<<dim3(NT_ATT, 8, SP_ATT), 256, 0, stream>>>(jo, jo, jo, DM, DM, NT_ATT);
        RJob ro{part_outS, cas_out_b, xs, xs, xsh, xsl, RS};
        reduce_k<SP_ATT><<<dim3(rblkS, 1), 256, 0, stream>>>(ro, ro, DM);
    }

    // cross-attention: xg = xg + MHA(LN(xg), xs_updated)
    {
        ln_rows<<<dim3(RG), 256, 0, stream>>>(xg, cag_ln_w, cag_ln_b, lnh, lnl, DM);
        GemmJob jq{lnh, lnl, cagq_h, cagq_l, part_q, RG};
        GemmJob jk{xsh, xsl, cagk_h, cagk_l, part_k, RS};
        GemmJob jv{xsh, xsl, cagv_h, cagv_l, part_v, RS};
        gemm_mfma<SP_ATT><<<dim3(NT_ATT, 8, 3*SP_ATT), 256, 0, stream>>>(jq, jk, jv, DM, DM, NT_ATT);
        mha_attn2<LG,LS,SP_ATT><<<dim3(8,BB), 256, 0, stream>>>(
            part_q, part_k, part_v, cag_in_b, cag_in_b+512, cag_in_b+1024, RG, RS, aoh, aol);
        GemmJob jo{aoh, aol, cago_h, cago_l, part_outS, RG};
        gemm_mfma<SP_ATT><<<dim3(NT_ATT, 2, SP_ATT), 256, 0, stream>>>(jo, jo, jo, DM, DM, NT_ATT);
        RJob ro{part_outS, cag_out_b, xg, xg, nullptr, nullptr, RG};
        reduce_k<SP_ATT><<<dim3((RG*DM+1023)/1024, 1), 256, 0, stream>>>(ro, ro, DM);
    }

    // fused head
    head_fused<<<dim3(BB), 512, 0, stream>>>(xs, xg, cls_ln_w, cls_ln_b, cls_w, cls_b, (float*)d_out);
}